// Round 2
// baseline (1249.141 us; speedup 1.0000x reference)
//
#include <hip/hip_runtime.h>
#include <hip/hip_bf16.h>
#include <math.h>

#define BB 64
#define HH 128
#define WW 128
#define EE 256
#define HP (HH*EE)        // 32768
#define H2 64
#define W2 128
#define PL2 (H2*W2)       // 8192
#define H4 32
#define W4 64
#define PL4 (H4*W4)       // 2048

typedef __hip_bfloat16 bf;
__device__ __forceinline__ float tof(float v) { return v; }
__device__ __forceinline__ float tof(bf v)    { return __bfloat162float(v); }
__device__ __forceinline__ bf    tob(float v) { return __float2bfloat16(v); }

// ---------------------------------------------------------------------------
// K1: Gaussian Fourier projection + fc1 matmul.
// One block = 16 rows of (b,h); 512 blocks, 256 threads. xf stays fp32 (8 MB).
__global__ __launch_bounds__(256) void k_fourier_fc1(
    const float* __restrict__ x, const float* __restrict__ Wf,
    const float* __restrict__ fc1_w, const float* __restrict__ fc1_b,
    float* __restrict__ xf)
{
    __shared__ float xe[16*EE];
    __shared__ float wt[256*33];
    int t = threadIdx.x;
    int row0 = blockIdx.x * 16;           // global row index (b*H + h)
    for (int i = t; i < 16*WW; i += 256) {
        int r = i / WW, w = i % WW;
        int rg = row0 + r;
        int h = rg % HH;
        float p = x[rg*WW + w] * Wf[h*WW + w] * 6.2831853071795864769f;
        float s, c;
        sincosf(p, &s, &c);
        xe[r*EE + w]      = s;
        xe[r*EE + w + WW] = c;
    }
    float acc[16];
    #pragma unroll
    for (int r = 0; r < 16; ++r) acc[r] = 0.f;
    for (int w0 = 0; w0 < EE; w0 += 32) {
        __syncthreads();
        #pragma unroll
        for (int j = 0; j < 32; ++j) {
            int idx = j*256 + t;
            int o = idx >> 5;
            int wi = idx & 31;
            wt[o*33 + wi] = fc1_w[o*EE + w0 + wi];
        }
        __syncthreads();
        #pragma unroll
        for (int j = 0; j < 32; ++j) {
            float wv = wt[t*33 + j];
            #pragma unroll
            for (int r = 0; r < 16; ++r)
                acc[r] += xe[r*EE + w0 + j] * wv;
        }
    }
    float bias = fc1_b[t];
    #pragma unroll
    for (int r = 0; r < 16; ++r)
        xf[(size_t)(row0 + r)*EE + t] = acc[r] + bias;
}

// ---------------------------------------------------------------------------
// K2: conv1 3x3, 1->6 channels, SAME. Block = 64(w) x 4(h) tile. 8192 blocks.
__global__ __launch_bounds__(256) void k_conv1(
    const float* __restrict__ xf, const float* __restrict__ k,
    const float* __restrict__ bias, bf* __restrict__ c1)
{
    int t = threadIdx.x;
    int wb = blockIdx.x & 3;
    int hb = (blockIdx.x >> 2) & 31;
    int b  = blockIdx.x >> 7;
    int wloc = t & 63, hloc = t >> 6;
    int w = wb*64 + wloc;
    int h = hb*4 + hloc;
    const float* src = xf + (size_t)b*HP;
    float v[9];
    #pragma unroll
    for (int ky = 0; ky < 3; ++ky)
      #pragma unroll
      for (int kx = 0; kx < 3; ++kx) {
        int yy = h + ky - 1, xx = w + kx - 1;
        v[ky*3+kx] = (yy >= 0 && yy < HH && xx >= 0 && xx < EE) ? src[(size_t)yy*EE+xx] : 0.f;
      }
    #pragma unroll
    for (int o = 0; o < 6; ++o) {
        float acc = bias[o];
        #pragma unroll
        for (int i = 0; i < 9; ++i) acc += v[i]*k[o*9+i];
        c1[((size_t)(b*6+o)*HH + h)*EE + w] = tob(acc);
    }
}

// ---------------------------------------------------------------------------
// Generic GroupNorm stats over a (possibly concatenated) channel set.
// One block per (b, group). Writes per-channel scale/shift pairs (fp32).
template<typename T>
__global__ __launch_bounds__(256) void k_gn_stats(
    const T* __restrict__ src0, int c0n,
    const T* __restrict__ src1, int c1n,
    int plane, int cpg,
    const float* __restrict__ gamma, const float* __restrict__ beta,
    float* __restrict__ ss)
{
    int C = c0n + c1n;
    int ng = C / cpg;
    int g = blockIdx.x % ng;
    int b = blockIdx.x / ng;
    float s = 0.f, sq = 0.f;
    for (int cl = 0; cl < cpg; ++cl) {
        int gc = g*cpg + cl;
        const T* p = (gc < c0n) ? src0 + ((size_t)b*c0n + gc)*plane
                                : src1 + ((size_t)b*c1n + (gc - c0n))*plane;
        for (int i = threadIdx.x; i < plane; i += 256) {
            float v = tof(p[i]);
            s += v; sq += v*v;
        }
    }
    __shared__ float rs[256], rq[256];
    rs[threadIdx.x] = s; rq[threadIdx.x] = sq;
    __syncthreads();
    for (int k = 128; k > 0; k >>= 1) {
        if (threadIdx.x < k) {
            rs[threadIdx.x] += rs[threadIdx.x+k];
            rq[threadIdx.x] += rq[threadIdx.x+k];
        }
        __syncthreads();
    }
    if (threadIdx.x < cpg) {
        float inv_n = 1.0f / (float)(plane * cpg);
        float mean = rs[0] * inv_n;
        float var  = rq[0] * inv_n - mean*mean;
        float rstd = rsqrtf(var + 1e-5f);
        int gc = g*cpg + threadIdx.x;
        float sc = gamma[gc] * rstd;
        ss[((size_t)b*C + gc)*2]   = sc;
        ss[((size_t)b*C + gc)*2+1] = beta[gc] - mean*sc;
    }
}

// ---------------------------------------------------------------------------
// GN apply + ReLU + 2x2 maxpool (+ optional SiLU). Thread per output pixel.
// bf16 src, fp32 dst.
__global__ __launch_bounds__(256) void k_gn_relu_pool(
    const bf* __restrict__ src, const float* __restrict__ ss,
    float* __restrict__ dst, int C, int hi, int wi, int do_silu)
{
    int idx = blockIdx.x*256 + threadIdx.x;
    int ho = hi >> 1, wo = wi >> 1;
    int xo = idx % wo; int tmp = idx / wo;
    int yo = tmp % ho; tmp /= ho;
    int c = tmp % C; int b = tmp / C;
    const bf* p = src + ((size_t)(b*C + c)*hi + yo*2)*wi + xo*2;
    float sc = ss[(b*C+c)*2], sh = ss[(b*C+c)*2+1];
    float v0 = fmaxf(tof(p[0])*sc+sh, 0.f);
    float v1 = fmaxf(tof(p[1])*sc+sh, 0.f);
    float v2 = fmaxf(tof(p[wi])*sc+sh, 0.f);
    float v3 = fmaxf(tof(p[wi+1])*sc+sh, 0.f);
    float m = fmaxf(fmaxf(v0,v1), fmaxf(v2,v3));
    if (do_silu) m = m / (1.f + expf(-m));
    dst[idx] = m;
}

// ---------------------------------------------------------------------------
// K5: conv2 3x3, 6->24, SAME, on (64,128) planes. Tile in LDS. 2048 blocks.
__global__ __launch_bounds__(256) void k_conv2(
    const float* __restrict__ p1, const float* __restrict__ k,
    const float* __restrict__ bias, bf* __restrict__ c2)
{
    __shared__ float tile[6][6][66];
    int t = threadIdx.x;
    int wb = blockIdx.x & 1;
    int hb = (blockIdx.x >> 1) & 15;
    int b  = blockIdx.x >> 5;
    int w0 = wb*64, h0 = hb*4;
    for (int i = t; i < 6*6*66; i += 256) {
        int c = i / (6*66);
        int rem = i % (6*66);
        int ty = rem / 66, tx = rem % 66;
        int hh = h0 + ty - 1, ww = w0 + tx - 1;
        float v = 0.f;
        if (hh >= 0 && hh < H2 && ww >= 0 && ww < W2)
            v = p1[((size_t)(b*6 + c)*H2 + hh)*W2 + ww];
        tile[c][ty][tx] = v;
    }
    __syncthreads();
    int wl = t & 63, hl = t >> 6;
    float acc[24];
    #pragma unroll
    for (int o = 0; o < 24; ++o) acc[o] = bias[o];
    #pragma unroll
    for (int c = 0; c < 6; ++c)
      #pragma unroll
      for (int ky = 0; ky < 3; ++ky)
        #pragma unroll
        for (int kx = 0; kx < 3; ++kx) {
            float v = tile[c][hl+ky][wl+kx];
            const float* kp = k + (c*9 + ky*3 + kx);
            #pragma unroll
            for (int o = 0; o < 24; ++o)
                acc[o] += v * kp[o*54];
        }
    int h = h0 + hl, w = w0 + wl;
    #pragma unroll
    for (int o = 0; o < 24; ++o)
        c2[((size_t)(b*24+o)*H2 + h)*W2 + w] = tob(acc[o]);
}

// ---------------------------------------------------------------------------
// K8: tconv 2x2 stride 2, 24->24. Thread per output element of (64,24,64,128).
__global__ __launch_bounds__(256) void k_tconv3(
    const float* __restrict__ a, const float* __restrict__ k,
    const float* __restrict__ bias, bf* __restrict__ u3)
{
    int idx = blockIdx.x*256 + threadIdx.x;
    int x = idx & (W2-1); int tmp = idx >> 7;
    int y = tmp & (H2-1); tmp >>= 6;
    int o = tmp % 24; int b = tmp / 24;
    int h = y >> 1, d = y & 1, w = x >> 1, q = x & 1;
    const float* ap = a + (size_t)b*24*PL4 + h*W4 + w;
    float acc = bias[o];
    #pragma unroll
    for (int c = 0; c < 24; ++c)
        acc += ap[(size_t)c*PL4] * k[((c*24+o)*2+d)*2+q];
    u3[idx] = tob(acc);
}

// ---------------------------------------------------------------------------
// K10: gn3-affine fused tconv 2x2 stride 2, 48->12, over concat(c2,u3).
__global__ __launch_bounds__(256) void k_tconv4(
    const bf* __restrict__ c2, const bf* __restrict__ u3,
    const float* __restrict__ ss3, const float* __restrict__ k,
    const float* __restrict__ bias, bf* __restrict__ u4)
{
    int idx = blockIdx.x*256 + threadIdx.x;
    int x = idx & (EE-1); int tmp = idx >> 8;
    int y = tmp & (HH-1); tmp >>= 7;
    int o = tmp % 12; int b = tmp / 12;
    int h = y >> 1, d = y & 1, w = x >> 1, q = x & 1;
    const bf* c2p = c2 + (size_t)b*24*PL2 + h*W2 + w;
    const bf* u3p = u3 + (size_t)b*24*PL2 + h*W2 + w;
    const float* ssp = ss3 + (size_t)b*96;
    float acc = bias[o];
    #pragma unroll
    for (int c = 0; c < 48; ++c) {
        float v = (c < 24) ? tof(c2p[(size_t)c*PL2]) : tof(u3p[(size_t)(c-24)*PL2]);
        v = v * ssp[c*2] + ssp[c*2+1];
        acc += v * k[((c*12+o)*2+d)*2+q];
    }
    u4[idx] = tob(acc);
}

// ---------------------------------------------------------------------------
// K12: gn4-affine fused 1x1 conv, 18->6, over concat(c1,u4). u5 fp32.
__global__ __launch_bounds__(256) void k_conv1x1_u5(
    const bf* __restrict__ c1, const bf* __restrict__ u4,
    const float* __restrict__ ss4, const float* __restrict__ k,
    const float* __restrict__ bias, float* __restrict__ u5)
{
    int idx = blockIdx.x*256 + threadIdx.x;
    int pix = idx & (HP-1); int tmp = idx >> 15;
    int o = tmp % 6; int b = tmp / 6;
    const bf* c1p = c1 + (size_t)b*6*HP + pix;
    const bf* u4p = u4 + (size_t)b*12*HP + pix;
    const float* ssp = ss4 + (size_t)b*36;
    float acc = bias[o];
    #pragma unroll
    for (int c = 0; c < 18; ++c) {
        float v = (c < 6) ? tof(c1p[(size_t)c*HP]) : tof(u4p[(size_t)(c-6)*HP]);
        v = v * ssp[c*2] + ssp[c*2+1];
        acc += v * k[o*18 + c];
    }
    u5[idx] = acc;
}

// ---------------------------------------------------------------------------
// K14: gn5-affine fused final 1x1 conv (6->1) + divide by std(t).
__global__ __launch_bounds__(256) void k_final(
    const float* __restrict__ u5, const float* __restrict__ ss5,
    const float* __restrict__ k, const float* __restrict__ bias,
    const float* __restrict__ t, float* __restrict__ out)
{
    int idx = blockIdx.x*256 + threadIdx.x;
    int pix = idx & (HP-1); int b = idx >> 15;
    const float* up = u5 + (size_t)b*6*HP + pix;
    const float* ssp = ss5 + (size_t)b*12;
    float acc = bias[0];
    #pragma unroll
    for (int c = 0; c < 6; ++c)
        acc += (up[(size_t)c*HP]*ssp[c*2] + ssp[c*2+1]) * k[c];
    float tb = t[b];
    const float lns = 3.2188758248682007492f;      // ln 25
    float var = (expf(2.f*tb*lns) - 1.f) / (2.f*lns);
    out[idx] = acc * rsqrtf(var);
}

// ---------------------------------------------------------------------------
extern "C" void kernel_launch(void* const* d_in, const int* in_sizes, int n_in,
                              void* d_out, int out_size, void* d_ws, size_t ws_size,
                              hipStream_t stream)
{
    const float* x       = (const float*)d_in[0];
    const float* t       = (const float*)d_in[1];
    const float* Wf      = (const float*)d_in[2];
    const float* fc1_w   = (const float*)d_in[3];
    const float* fc1_b   = (const float*)d_in[4];
    const float* conv1_k = (const float*)d_in[5];
    const float* conv1_b = (const float*)d_in[6];
    const float* gn1_g   = (const float*)d_in[7];
    const float* gn1_b   = (const float*)d_in[8];
    const float* conv2_k = (const float*)d_in[9];
    const float* conv2_b = (const float*)d_in[10];
    const float* gn2_g   = (const float*)d_in[11];
    const float* gn2_b   = (const float*)d_in[12];
    const float* t3_k    = (const float*)d_in[13];
    const float* t3_b    = (const float*)d_in[14];
    const float* gn3_g   = (const float*)d_in[15];
    const float* gn3_b   = (const float*)d_in[16];
    const float* t4_k    = (const float*)d_in[17];
    const float* t4_b    = (const float*)d_in[18];
    const float* gn4_g   = (const float*)d_in[19];
    const float* gn4_b   = (const float*)d_in[20];
    const float* t5_k    = (const float*)d_in[21];
    const float* t5_b    = (const float*)d_in[22];
    const float* gn5_g   = (const float*)d_in[23];
    const float* gn5_b   = (const float*)d_in[24];
    const float* fin_k   = (const float*)d_in[25];
    const float* fin_b   = (const float*)d_in[26];

    // Workspace layout in bf16-element units (byte = 2*el). Peak ~125.9 MB.
    bf* wsb = (bf*)d_ws;
    bf* c1 = wsb;                          // 12,582,912 el  live K2..K12
    bf* c2 = wsb + 12582912;               // 12,582,912 el  live K5..K10
    bf* u3 = wsb + 25165824;               // 12,582,912 el  live K8..K10
    bf* u4 = wsb + 37748736;               // 25,165,824 el  live K10..K12
    // fp32 temporaries inside u4's region (all dead before K10 writes u4):
    float* xf = (float*)(wsb + 37748736);  // 2,097,152 f    live K1..K2
    float* p1 = (float*)(wsb + 41943040);  // 3,145,728 f    live K4..K5
    float* a_ = (float*)(wsb + 48234496);  // 3,145,728 f    live K7..K8
    // u5 fp32 reuses c2+u3 region (dead after K10):
    float* u5 = (float*)(wsb + 12582912);  // 12,582,912 f   live K12..K14
    // stats (fp32) after the bf16 heap:
    float* s1 = (float*)(wsb + 62914560);  // 768
    float* s2 = s1 + 768;                  // 3072
    float* s3 = s2 + 3072;                 // 6144
    float* s4 = s3 + 6144;                 // 2304
    float* s5 = s4 + 2304;                 // 768

    k_fourier_fc1<<<512, 256, 0, stream>>>(x, Wf, fc1_w, fc1_b, xf);
    k_conv1<<<8192, 256, 0, stream>>>(xf, conv1_k, conv1_b, c1);
    k_gn_stats<bf><<<384, 256, 0, stream>>>(c1, 6, (const bf*)nullptr, 0, HP, 1, gn1_g, gn1_b, s1);
    k_gn_relu_pool<<<12288, 256, 0, stream>>>(c1, s1, p1, 6, HH, EE, 0);
    k_conv2<<<2048, 256, 0, stream>>>(p1, conv2_k, conv2_b, c2);
    k_gn_stats<bf><<<1536, 256, 0, stream>>>(c2, 24, (const bf*)nullptr, 0, PL2, 1, gn2_g, gn2_b, s2);
    k_gn_relu_pool<<<12288, 256, 0, stream>>>(c2, s2, a_, 24, H2, W2, 1);
    k_tconv3<<<49152, 256, 0, stream>>>(a_, t3_k, t3_b, u3);
    k_gn_stats<bf><<<384, 256, 0, stream>>>(c2, 24, u3, 24, PL2, 8, gn3_g, gn3_b, s3);
    k_tconv4<<<98304, 256, 0, stream>>>(c2, u3, s3, t4_k, t4_b, u4);
    k_gn_stats<bf><<<384, 256, 0, stream>>>(c1, 6, u4, 12, HP, 3, gn4_g, gn4_b, s4);
    k_conv1x1_u5<<<49152, 256, 0, stream>>>(c1, u4, s4, t5_k, t5_b, u5);
    k_gn_stats<float><<<384, 256, 0, stream>>>(u5, 6, (const float*)nullptr, 0, HP, 1, gn5_g, gn5_b, s5);
    k_final<<<8192, 256, 0, stream>>>(u5, s5, fin_k, fin_b, t, (float*)d_out);
}

// Round 3
// 460.277 us; speedup vs baseline: 2.7139x; 2.7139x over previous
//
#include <hip/hip_runtime.h>
#include <hip/hip_bf16.h>
#include <math.h>

#define BB 64
#define HH 128
#define WW 128
#define EE 256
#define HP (HH*EE)        // 32768
#define H2 64
#define W2 128
#define PL2 (H2*W2)       // 8192
#define H4 32
#define W4 64
#define PL4 (H4*W4)       // 2048

typedef __hip_bfloat16 bf;
typedef __hip_bfloat162 bf2;
__device__ __forceinline__ float tof(float v) { return v; }
__device__ __forceinline__ float tof(bf v)    { return __bfloat162float(v); }
__device__ __forceinline__ bf    tob(float v) { return __float2bfloat16(v); }

// ---------------------------------------------------------------------------
// K0: zero the atomic-sum scratch (graph-safe, runs every call).
__global__ __launch_bounds__(256) void k_zero(float* __restrict__ p, int n)
{
    for (int i = blockIdx.x*256 + threadIdx.x; i < n; i += gridDim.x*256) p[i] = 0.f;
}

// ---------------------------------------------------------------------------
// K1: Gaussian Fourier projection + fc1 matmul.
__global__ __launch_bounds__(256) void k_fourier_fc1(
    const float* __restrict__ x, const float* __restrict__ Wf,
    const float* __restrict__ fc1_w, const float* __restrict__ fc1_b,
    float* __restrict__ xf)
{
    __shared__ float xe[16*EE];
    __shared__ float wt[256*33];
    int t = threadIdx.x;
    int row0 = blockIdx.x * 16;
    for (int i = t; i < 16*WW; i += 256) {
        int r = i / WW, w = i % WW;
        int rg = row0 + r;
        int h = rg % HH;
        float p = x[rg*WW + w] * Wf[h*WW + w] * 6.2831853071795864769f;
        float s, c;
        sincosf(p, &s, &c);
        xe[r*EE + w]      = s;
        xe[r*EE + w + WW] = c;
    }
    float acc[16];
    #pragma unroll
    for (int r = 0; r < 16; ++r) acc[r] = 0.f;
    for (int w0 = 0; w0 < EE; w0 += 32) {
        __syncthreads();
        #pragma unroll
        for (int j = 0; j < 32; ++j) {
            int idx = j*256 + t;
            int o = idx >> 5;
            int wi = idx & 31;
            wt[o*33 + wi] = fc1_w[o*EE + w0 + wi];
        }
        __syncthreads();
        #pragma unroll
        for (int j = 0; j < 32; ++j) {
            float wv = wt[t*33 + j];
            #pragma unroll
            for (int r = 0; r < 16; ++r)
                acc[r] += xe[r*EE + w0 + j] * wv;
        }
    }
    float bias = fc1_b[t];
    #pragma unroll
    for (int r = 0; r < 16; ++r)
        xf[(size_t)(row0 + r)*EE + t] = acc[r] + bias;
}

// ---------------------------------------------------------------------------
// K2: conv1 3x3, 1->6 channels, SAME.
__global__ __launch_bounds__(256) void k_conv1(
    const float* __restrict__ xf, const float* __restrict__ k,
    const float* __restrict__ bias, bf* __restrict__ c1)
{
    int t = threadIdx.x;
    int wb = blockIdx.x & 3;
    int hb = (blockIdx.x >> 2) & 31;
    int b  = blockIdx.x >> 7;
    int wloc = t & 63, hloc = t >> 6;
    int w = wb*64 + wloc;
    int h = hb*4 + hloc;
    const float* src = xf + (size_t)b*HP;
    float v[9];
    #pragma unroll
    for (int ky = 0; ky < 3; ++ky)
      #pragma unroll
      for (int kx = 0; kx < 3; ++kx) {
        int yy = h + ky - 1, xx = w + kx - 1;
        v[ky*3+kx] = (yy >= 0 && yy < HH && xx >= 0 && xx < EE) ? src[(size_t)yy*EE+xx] : 0.f;
      }
    #pragma unroll
    for (int o = 0; o < 6; ++o) {
        float acc = bias[o];
        #pragma unroll
        for (int i = 0; i < 9; ++i) acc += v[i]*k[o*9+i];
        c1[((size_t)(b*6+o)*HH + h)*EE + w] = tob(acc);
    }
}

// ---------------------------------------------------------------------------
// GN stats phase A: per-(b,channel,chunk) partial sums, atomicAdd into sums.
// sums[(b*Ctot + c0off + c)*2 + {0,1}] accumulates {sum, sumsq}.
template<typename T>
__global__ __launch_bounds__(256) void k_stats_partial(
    const T* __restrict__ src, int C, int plane, int nchunk,
    int c0off, int Ctot, float* __restrict__ sums)
{
    int chunk = blockIdx.x % nchunk;
    int c = (blockIdx.x / nchunk) % C;
    int b = blockIdx.x / (nchunk * C);
    int clen = plane / nchunk;
    const T* p = src + ((size_t)b*C + c)*plane + chunk*clen;
    float s = 0.f, sq = 0.f;
    #pragma unroll 4
    for (int i = threadIdx.x; i < clen; i += 256) {
        float v = tof(p[i]);
        s += v; sq += v*v;
    }
    __shared__ float rs[256], rq[256];
    rs[threadIdx.x] = s; rq[threadIdx.x] = sq;
    __syncthreads();
    for (int k = 128; k > 0; k >>= 1) {
        if (threadIdx.x < k) {
            rs[threadIdx.x] += rs[threadIdx.x+k];
            rq[threadIdx.x] += rq[threadIdx.x+k];
        }
        __syncthreads();
    }
    if (threadIdx.x == 0) {
        float* dst = sums + ((size_t)b*Ctot + c0off + c)*2;
        atomicAdd(dst,   rs[0]);
        atomicAdd(dst+1, rq[0]);
    }
}

// GN stats phase B: combine channel sums per group -> per-channel scale/shift.
__global__ __launch_bounds__(256) void k_stats_final(
    const float* __restrict__ sums, const float* __restrict__ gamma,
    const float* __restrict__ beta, int C, int cpg, int n, float inv_n,
    float* __restrict__ ss)
{
    int idx = blockIdx.x*256 + threadIdx.x;
    if (idx >= n) return;
    int ng = C / cpg;
    int g = idx % ng;
    int b = idx / ng;
    float s = 0.f, q = 0.f;
    for (int cl = 0; cl < cpg; ++cl) {
        int gc = g*cpg + cl;
        s += sums[((size_t)b*C + gc)*2];
        q += sums[((size_t)b*C + gc)*2 + 1];
    }
    float mean = s * inv_n;
    float var  = q * inv_n - mean*mean;
    float rstd = rsqrtf(var + 1e-5f);
    for (int cl = 0; cl < cpg; ++cl) {
        int gc = g*cpg + cl;
        float sc = gamma[gc] * rstd;
        ss[((size_t)b*C + gc)*2]   = sc;
        ss[((size_t)b*C + gc)*2+1] = beta[gc] - mean*sc;
    }
}

// ---------------------------------------------------------------------------
// GN apply + ReLU + 2x2 maxpool (+ optional SiLU). Packed bf16x2 loads.
__global__ __launch_bounds__(256) void k_gn_relu_pool(
    const bf* __restrict__ src, const float* __restrict__ ss,
    float* __restrict__ dst, int C, int hi, int wi, int do_silu)
{
    int idx = blockIdx.x*256 + threadIdx.x;
    int ho = hi >> 1, wo = wi >> 1;
    int xo = idx % wo; int tmp = idx / wo;
    int yo = tmp % ho; tmp /= ho;
    int c = tmp % C; int b = tmp / C;
    const bf* p = src + ((size_t)(b*C + c)*hi + yo*2)*wi + xo*2;
    bf2 r0 = *(const bf2*)p;
    bf2 r1 = *(const bf2*)(p + wi);
    float sc = ss[(b*C+c)*2], sh = ss[(b*C+c)*2+1];
    float v0 = fmaxf(tof(r0.x)*sc+sh, 0.f);
    float v1 = fmaxf(tof(r0.y)*sc+sh, 0.f);
    float v2 = fmaxf(tof(r1.x)*sc+sh, 0.f);
    float v3 = fmaxf(tof(r1.y)*sc+sh, 0.f);
    float m = fmaxf(fmaxf(v0,v1), fmaxf(v2,v3));
    if (do_silu) m = m / (1.f + expf(-m));
    dst[idx] = m;
}

// ---------------------------------------------------------------------------
// K5: conv2 3x3, 6->24, SAME, on (64,128) planes.
__global__ __launch_bounds__(256) void k_conv2(
    const float* __restrict__ p1, const float* __restrict__ k,
    const float* __restrict__ bias, bf* __restrict__ c2)
{
    __shared__ float tile[6][6][66];
    int t = threadIdx.x;
    int wb = blockIdx.x & 1;
    int hb = (blockIdx.x >> 1) & 15;
    int b  = blockIdx.x >> 5;
    int w0 = wb*64, h0 = hb*4;
    for (int i = t; i < 6*6*66; i += 256) {
        int c = i / (6*66);
        int rem = i % (6*66);
        int ty = rem / 66, tx = rem % 66;
        int hh = h0 + ty - 1, ww = w0 + tx - 1;
        float v = 0.f;
        if (hh >= 0 && hh < H2 && ww >= 0 && ww < W2)
            v = p1[((size_t)(b*6 + c)*H2 + hh)*W2 + ww];
        tile[c][ty][tx] = v;
    }
    __syncthreads();
    int wl = t & 63, hl = t >> 6;
    float acc[24];
    #pragma unroll
    for (int o = 0; o < 24; ++o) acc[o] = bias[o];
    #pragma unroll
    for (int c = 0; c < 6; ++c)
      #pragma unroll
      for (int ky = 0; ky < 3; ++ky)
        #pragma unroll
        for (int kx = 0; kx < 3; ++kx) {
            float v = tile[c][hl+ky][wl+kx];
            const float* kp = k + (c*9 + ky*3 + kx);
            #pragma unroll
            for (int o = 0; o < 24; ++o)
                acc[o] += v * kp[o*54];
        }
    int h = h0 + hl, w = w0 + wl;
    #pragma unroll
    for (int o = 0; o < 24; ++o)
        c2[((size_t)(b*24+o)*H2 + h)*W2 + w] = tob(acc[o]);
}

// ---------------------------------------------------------------------------
// K8: tconv 2x2 stride 2, 24->24. Thread per INPUT pixel, all 24x2x2 outputs.
// 512 blocks (64 b x 8 pixel-groups).
__global__ __launch_bounds__(256) void k_tconv3(
    const float* __restrict__ a, const float* __restrict__ k,
    const float* __restrict__ bias, bf* __restrict__ u3)
{
    __shared__ float wt[24*24*4];   // [c][o][d*2+q] - linear copy of k
    __shared__ float sb[24];
    int t = threadIdx.x;
    int b  = blockIdx.x >> 3;
    int pg = blockIdx.x & 7;
    for (int i = t; i < 2304; i += 256) wt[i] = k[i];
    if (t < 24) sb[t] = bias[t];
    __syncthreads();
    int pix = pg*256 + t;                 // [0, 2048)
    int h = pix >> 6, w = pix & 63;
    const float* ap = a + ((size_t)b*24)*PL4 + pix;
    float acc[24][4];
    #pragma unroll
    for (int o = 0; o < 24; ++o) {
        float bv = sb[o];
        #pragma unroll
        for (int j = 0; j < 4; ++j) acc[o][j] = bv;
    }
    for (int c = 0; c < 24; ++c) {
        float v = ap[(size_t)c*PL4];
        const float* wr = wt + c*96;
        #pragma unroll
        for (int o = 0; o < 24; ++o) {
            acc[o][0] += v * wr[o*4+0];
            acc[o][1] += v * wr[o*4+1];
            acc[o][2] += v * wr[o*4+2];
            acc[o][3] += v * wr[o*4+3];
        }
    }
    #pragma unroll
    for (int o = 0; o < 24; ++o)
      #pragma unroll
      for (int d = 0; d < 2; ++d) {
        bf2 pk; pk.x = tob(acc[o][d*2+0]); pk.y = tob(acc[o][d*2+1]);
        *(bf2*)(u3 + (((size_t)(b*24+o)*H2 + 2*h+d)*W2 + 2*w)) = pk;
      }
}

// ---------------------------------------------------------------------------
// K10: gn3-affine fused tconv 2x2 stride 2, 48->12. Thread per INPUT pixel.
// 2048 blocks (64 b x 32 pixel-groups).
__global__ __launch_bounds__(256) void k_tconv4(
    const bf* __restrict__ c2, const bf* __restrict__ u3,
    const float* __restrict__ ss3, const float* __restrict__ k,
    const float* __restrict__ bias, bf* __restrict__ u4)
{
    __shared__ float wt[48*12*4];   // [c][o][d*2+q] - linear copy
    __shared__ float sb[12];
    __shared__ float ssl[96];
    int t = threadIdx.x;
    int b  = blockIdx.x >> 5;
    int pg = blockIdx.x & 31;
    for (int i = t; i < 2304; i += 256) wt[i] = k[i];
    if (t < 12) sb[t] = bias[t];
    if (t < 96) ssl[t] = ss3[b*96 + t];
    __syncthreads();
    int pix = pg*256 + t;                 // [0, 8192)
    int h = pix >> 7, w = pix & 127;
    const bf* c2p = c2 + ((size_t)b*24)*PL2 + pix;
    const bf* u3p = u3 + ((size_t)b*24)*PL2 + pix;
    float acc[12][4];
    #pragma unroll
    for (int o = 0; o < 12; ++o) {
        float bv = sb[o];
        #pragma unroll
        for (int j = 0; j < 4; ++j) acc[o][j] = bv;
    }
    for (int c = 0; c < 48; ++c) {
        float v = (c < 24) ? tof(c2p[(size_t)c*PL2]) : tof(u3p[(size_t)(c-24)*PL2]);
        v = v * ssl[2*c] + ssl[2*c+1];
        const float* wr = wt + c*48;
        #pragma unroll
        for (int o = 0; o < 12; ++o) {
            acc[o][0] += v * wr[o*4+0];
            acc[o][1] += v * wr[o*4+1];
            acc[o][2] += v * wr[o*4+2];
            acc[o][3] += v * wr[o*4+3];
        }
    }
    #pragma unroll
    for (int o = 0; o < 12; ++o)
      #pragma unroll
      for (int d = 0; d < 2; ++d) {
        bf2 pk; pk.x = tob(acc[o][d*2+0]); pk.y = tob(acc[o][d*2+1]);
        *(bf2*)(u4 + (((size_t)(b*12+o)*HH + 2*h+d)*EE + 2*w)) = pk;
      }
}

// ---------------------------------------------------------------------------
// K12: gn4-affine fused 1x1 conv, 18->6. Thread per pixel, all 6 outputs.
// 8192 blocks.
__global__ __launch_bounds__(256) void k_conv1x1_u5(
    const bf* __restrict__ c1, const bf* __restrict__ u4,
    const float* __restrict__ ss4, const float* __restrict__ k,
    const float* __restrict__ bias, bf* __restrict__ u5)
{
    __shared__ float wt[6*18];
    __shared__ float sb[6];
    __shared__ float ssl[36];
    int t = threadIdx.x;
    int b  = blockIdx.x >> 7;
    int pg = blockIdx.x & 127;
    if (t < 108) wt[t] = k[t];
    if (t < 6) sb[t] = bias[t];
    if (t < 36) ssl[t] = ss4[b*36 + t];
    __syncthreads();
    int pix = pg*256 + t;
    const bf* c1p = c1 + ((size_t)b*6)*HP + pix;
    const bf* u4p = u4 + ((size_t)b*12)*HP + pix;
    float acc[6];
    #pragma unroll
    for (int o = 0; o < 6; ++o) acc[o] = sb[o];
    #pragma unroll
    for (int c = 0; c < 18; ++c) {
        float v = (c < 6) ? tof(c1p[(size_t)c*HP]) : tof(u4p[(size_t)(c-6)*HP]);
        v = v * ssl[2*c] + ssl[2*c+1];
        #pragma unroll
        for (int o = 0; o < 6; ++o) acc[o] += v * wt[o*18 + c];
    }
    #pragma unroll
    for (int o = 0; o < 6; ++o)
        u5[((size_t)(b*6+o))*HP + pix] = tob(acc[o]);
}

// ---------------------------------------------------------------------------
// K14: gn5-affine fused final 1x1 conv (6->1) + divide by std(t).
__global__ __launch_bounds__(256) void k_final(
    const bf* __restrict__ u5, const float* __restrict__ ss5,
    const float* __restrict__ k, const float* __restrict__ bias,
    const float* __restrict__ t, float* __restrict__ out)
{
    int idx = blockIdx.x*256 + threadIdx.x;
    int pix = idx & (HP-1); int b = idx >> 15;
    const bf* up = u5 + (size_t)b*6*HP + pix;
    const float* ssp = ss5 + (size_t)b*12;
    float acc = bias[0];
    #pragma unroll
    for (int c = 0; c < 6; ++c)
        acc += (tof(up[(size_t)c*HP])*ssp[c*2] + ssp[c*2+1]) * k[c];
    float tb = t[b];
    const float lns = 3.2188758248682007492f;      // ln 25
    float var = (expf(2.f*tb*lns) - 1.f) / (2.f*lns);
    out[idx] = acc * rsqrtf(var);
}

// ---------------------------------------------------------------------------
extern "C" void kernel_launch(void* const* d_in, const int* in_sizes, int n_in,
                              void* d_out, int out_size, void* d_ws, size_t ws_size,
                              hipStream_t stream)
{
    const float* x       = (const float*)d_in[0];
    const float* t       = (const float*)d_in[1];
    const float* Wf      = (const float*)d_in[2];
    const float* fc1_w   = (const float*)d_in[3];
    const float* fc1_b   = (const float*)d_in[4];
    const float* conv1_k = (const float*)d_in[5];
    const float* conv1_b = (const float*)d_in[6];
    const float* gn1_g   = (const float*)d_in[7];
    const float* gn1_b   = (const float*)d_in[8];
    const float* conv2_k = (const float*)d_in[9];
    const float* conv2_b = (const float*)d_in[10];
    const float* gn2_g   = (const float*)d_in[11];
    const float* gn2_b   = (const float*)d_in[12];
    const float* t3_k    = (const float*)d_in[13];
    const float* t3_b    = (const float*)d_in[14];
    const float* gn3_g   = (const float*)d_in[15];
    const float* gn3_b   = (const float*)d_in[16];
    const float* t4_k    = (const float*)d_in[17];
    const float* t4_b    = (const float*)d_in[18];
    const float* gn4_g   = (const float*)d_in[19];
    const float* gn4_b   = (const float*)d_in[20];
    const float* t5_k    = (const float*)d_in[21];
    const float* t5_b    = (const float*)d_in[22];
    const float* gn5_g   = (const float*)d_in[23];
    const float* gn5_b   = (const float*)d_in[24];
    const float* fin_k   = (const float*)d_in[25];
    const float* fin_b   = (const float*)d_in[26];

    // Workspace layout in bf16-element units. Peak ~126 MB.
    bf* wsb = (bf*)d_ws;
    bf* c1 = wsb;                          // 12,582,912 el  live conv1..conv1x1
    bf* c2 = wsb + 12582912;               // 12,582,912 el  live conv2..tconv4
    bf* u3 = wsb + 25165824;               // 12,582,912 el  live tconv3..tconv4
    bf* u4 = wsb + 37748736;               // 25,165,824 el  live tconv4..conv1x1
    float* xf = (float*)(wsb + 37748736);  // in u4 region, live fc1..conv1
    float* p1 = (float*)(wsb + 41943040);  // in u4 region, live pool1..conv2
    float* a_ = (float*)(wsb + 48234496);  // in u4 region, live pool2..tconv3
    bf* u5 = wsb + 12582912;               // reuses c2 region, live conv1x1..final
    // stats area after bf16 heap: ss (13056 fl) then sums (13056 fl)
    float* st = (float*)(wsb + 62914560);
    float* s1 = st;            // 768
    float* s2 = st + 768;      // 3072
    float* s3 = st + 3840;     // 6144
    float* s4 = st + 9984;     // 2304
    float* s5 = st + 12288;    // 768
    float* sums = st + 13056;
    float* m1 = sums;          // 768
    float* m2 = sums + 768;    // 3072
    float* m3 = sums + 3840;   // 6144
    float* m4 = sums + 9984;   // 2304
    float* m5 = sums + 12288;  // 768

    k_zero<<<13, 256, 0, stream>>>(sums, 13056);
    k_fourier_fc1<<<512, 256, 0, stream>>>(x, Wf, fc1_w, fc1_b, xf);
    k_conv1<<<8192, 256, 0, stream>>>(xf, conv1_k, conv1_b, c1);
    // gn1: C=6, plane=HP, nchunk=4 -> 1536 blocks
    k_stats_partial<bf><<<1536, 256, 0, stream>>>(c1, 6, HP, 4, 0, 6, m1);
    k_stats_final<<<2, 256, 0, stream>>>(m1, gn1_g, gn1_b, 6, 1, 384, 1.f/HP, s1);
    k_gn_relu_pool<<<12288, 256, 0, stream>>>(c1, s1, p1, 6, HH, EE, 0);
    k_conv2<<<2048, 256, 0, stream>>>(p1, conv2_k, conv2_b, c2);
    // gn2: C=24, plane=PL2, nchunk=1 -> 1536 blocks
    k_stats_partial<bf><<<1536, 256, 0, stream>>>(c2, 24, PL2, 1, 0, 24, m2);
    k_stats_final<<<6, 256, 0, stream>>>(m2, gn2_g, gn2_b, 24, 1, 1536, 1.f/PL2, s2);
    k_gn_relu_pool<<<12288, 256, 0, stream>>>(c2, s2, a_, 24, H2, W2, 1);
    k_tconv3<<<512, 256, 0, stream>>>(a_, t3_k, t3_b, u3);
    // gn3: concat(c2,u3), Ctot=48, cpg=8
    k_stats_partial<bf><<<1536, 256, 0, stream>>>(c2, 24, PL2, 1, 0, 48, m3);
    k_stats_partial<bf><<<1536, 256, 0, stream>>>(u3, 24, PL2, 1, 24, 48, m3);
    k_stats_final<<<2, 256, 0, stream>>>(m3, gn3_g, gn3_b, 48, 8, 384, 1.f/(PL2*8), s3);
    k_tconv4<<<2048, 256, 0, stream>>>(c2, u3, s3, t4_k, t4_b, u4);
    // gn4: concat(c1,u4), Ctot=18, cpg=3
    k_stats_partial<bf><<<1536, 256, 0, stream>>>(c1, 6, HP, 4, 0, 18, m4);
    k_stats_partial<bf><<<1536, 256, 0, stream>>>(u4, 12, HP, 2, 6, 18, m4);
    k_stats_final<<<2, 256, 0, stream>>>(m4, gn4_g, gn4_b, 18, 3, 384, 1.f/(HP*3), s4);
    k_conv1x1_u5<<<8192, 256, 0, stream>>>(c1, u4, s4, t5_k, t5_b, u5);
    // gn5: C=6, plane=HP
    k_stats_partial<bf><<<1536, 256, 0, stream>>>(u5, 6, HP, 4, 0, 6, m5);
    k_stats_final<<<2, 256, 0, stream>>>(m5, gn5_g, gn5_b, 6, 1, 384, 1.f/HP, s5);
    k_final<<<8192, 256, 0, stream>>>(u5, s5, fin_k, fin_b, t, (float*)d_out);
}

// Round 4
// 413.142 us; speedup vs baseline: 3.0235x; 1.1141x over previous
//
#include <hip/hip_runtime.h>
#include <hip/hip_bf16.h>
#include <math.h>

#define BB 64
#define HH 128
#define WW 128
#define EE 256
#define HP (HH*EE)        // 32768
#define H2 64
#define W2 128
#define PL2 (H2*W2)       // 8192
#define H4 32
#define W4 64
#define PL4 (H4*W4)       // 2048

typedef __hip_bfloat16 bf;
typedef __hip_bfloat162 bf2;
typedef __attribute__((ext_vector_type(8))) __bf16 b8v;
typedef __attribute__((ext_vector_type(4))) float f4v;

__device__ __forceinline__ float tof(float v) { return v; }
__device__ __forceinline__ float tof(bf v)    { return __bfloat162float(v); }
__device__ __forceinline__ bf    tob(float v) { return __float2bfloat16(v); }
__device__ __forceinline__ unsigned short bfbits(float v) {
    return __builtin_bit_cast(unsigned short, __float2bfloat16(v));
}
__device__ __forceinline__ float b2f(unsigned int u16) {
    unsigned int x = u16 << 16;
    return __builtin_bit_cast(float, x);
}
// 64-lane butterfly reduction of (s, q)
__device__ __forceinline__ void wred2(float& s, float& q) {
    #pragma unroll
    for (int m = 32; m; m >>= 1) {
        s += __shfl_xor(s, m);
        q += __shfl_xor(q, m);
    }
}

// ---------------------------------------------------------------------------
// K0: zero the atomic-sum scratch (graph-safe, runs every call).
__global__ __launch_bounds__(256) void k_zero(float* __restrict__ p, int n)
{
    for (int i = blockIdx.x*256 + threadIdx.x; i < n; i += gridDim.x*256) p[i] = 0.f;
}

// ---------------------------------------------------------------------------
// K1a: Gaussian Fourier features -> xe bf16 [8192][256]. 2048 blocks.
__global__ __launch_bounds__(256) void k_fourier(
    const float* __restrict__ x, const float* __restrict__ Wf, bf* __restrict__ xe)
{
    int idx = blockIdx.x*256 + threadIdx.x;   // 524288 = 8192 rows * 64 w-pairs
    int row = idx >> 6, wp = idx & 63;
    float2 xv = *(const float2*)(x + (size_t)row*WW + wp*2);
    float2 wv = *(const float2*)(Wf + (size_t)(row & (HH-1))*WW + wp*2);
    const float TP = 6.2831853071795864769f;
    float s0, c0, s1, c1;
    sincosf(xv.x*wv.x*TP, &s0, &c0);
    sincosf(xv.y*wv.y*TP, &s1, &c1);
    bf* rp = xe + (size_t)row*EE + wp*2;
    bf2 sv; sv.x = tob(s0); sv.y = tob(s1); *(bf2*)rp = sv;
    bf2 cv; cv.x = tob(c0); cv.y = tob(c1); *(bf2*)(rp + WW) = cv;
}

// ---------------------------------------------------------------------------
// K1b: fc1 GEMM via MFMA: xf[row][o] = sum_k xe[row][k] * fc1_w[o][k] + b[o].
// Block = 64 rows x 64 cols, 4 waves (wave = 16 rows x 64 cols). 512 blocks.
__global__ __launch_bounds__(256) void k_gemm_fc1(
    const bf* __restrict__ xe, const float* __restrict__ fc1_w,
    const float* __restrict__ fc1_b, bf* __restrict__ xf)
{
    __shared__ unsigned short sA[64*264];   // rows x k, stride 264 (pad)
    __shared__ unsigned short sB[64*264];   // outs x k
    int tid = threadIdx.x;
    int rb = blockIdx.x >> 2, cb = blockIdx.x & 3;
    int row0 = rb*64, col0 = cb*64;
    #pragma unroll
    for (int it = 0; it < 8; ++it) {        // stage A (bf16 16B chunks)
        int i = it*256 + tid;
        int r = i >> 5, ch = i & 31;
        uint4 v = *(const uint4*)(xe + (size_t)(row0 + r)*EE + ch*8);
        *(uint4*)&sA[r*264 + ch*8] = v;
    }
    #pragma unroll
    for (int it = 0; it < 16; ++it) {       // stage B (fp32 -> bf16)
        int i = it*256 + tid;
        int o = i >> 6, c4 = i & 63;
        float4 w4 = *(const float4*)(fc1_w + (size_t)(col0 + o)*EE + c4*4);
        uint2 pk;
        pk.x = (unsigned)bfbits(w4.x) | ((unsigned)bfbits(w4.y) << 16);
        pk.y = (unsigned)bfbits(w4.z) | ((unsigned)bfbits(w4.w) << 16);
        *(uint2*)&sB[o*264 + c4*4] = pk;
    }
    __syncthreads();
    int lane = tid & 63, wid = tid >> 6;
    int m = lane & 15, kq = (lane >> 4) * 8;
    f4v acc[4] = {};
    const unsigned short* aBase = &sA[(wid*16 + m)*264 + kq];
    #pragma unroll
    for (int k0 = 0; k0 < 8; ++k0) {
        b8v av = *(const b8v*)(aBase + k0*32);
        #pragma unroll
        for (int t4 = 0; t4 < 4; ++t4) {
            b8v bv = *(const b8v*)&sB[(t4*16 + m)*264 + k0*32 + kq];
            acc[t4] = __builtin_amdgcn_mfma_f32_16x16x32_bf16(av, bv, acc[t4], 0, 0, 0);
        }
    }
    int rbase = row0 + wid*16 + (lane >> 4)*4;    // C/D: row=(lane>>4)*4+reg, col=lane&15
    #pragma unroll
    for (int t4 = 0; t4 < 4; ++t4) {
        int col = col0 + t4*16 + m;
        float bias = fc1_b[col];
        #pragma unroll
        for (int r = 0; r < 4; ++r)
            xf[(size_t)(rbase + r)*EE + col] = tob(acc[t4][r] + bias);
    }
}

// ---------------------------------------------------------------------------
// K2: conv1 3x3, 1->6, SAME, on bf16 xf. 2 px/thread. 4096 blocks.
// Fused gn1 channel statistics (raw c1 sums) -> mc1.
__global__ __launch_bounds__(256) void k_conv1(
    const bf* __restrict__ xf, const float* __restrict__ k,
    const float* __restrict__ bias, bf* __restrict__ c1, float* __restrict__ mc1)
{
    __shared__ float red[4][6][2];
    int t = threadIdx.x;
    int wt = blockIdx.x & 1;
    int ht = (blockIdx.x >> 1) & 31;
    int b  = blockIdx.x >> 6;
    int pr = t & 63, rw = t >> 6;
    int w = wt*128 + pr*2;
    int h = ht*4 + rw;
    int lane = t & 63, wid = t >> 6;
    const bf* src = xf + (size_t)b*HP;
    float v[3][4];
    #pragma unroll
    for (int ky = 0; ky < 3; ++ky) {
        int yy = h + ky - 1;
        #pragma unroll
        for (int kx = 0; kx < 4; ++kx) {
            int xx = w + kx - 1;
            v[ky][kx] = (yy >= 0 && yy < HH && xx >= 0 && xx < EE)
                        ? tof(src[(size_t)yy*EE + xx]) : 0.f;
        }
    }
    #pragma unroll
    for (int o = 0; o < 6; ++o) {
        float a0 = bias[o], a1 = a0;
        #pragma unroll
        for (int ky = 0; ky < 3; ++ky)
          #pragma unroll
          for (int kx = 0; kx < 3; ++kx) {
            float wv = k[o*9 + ky*3 + kx];
            a0 += v[ky][kx]   * wv;
            a1 += v[ky][kx+1] * wv;
          }
        bf2 pk; pk.x = tob(a0); pk.y = tob(a1);
        *(bf2*)(c1 + ((size_t)(b*6+o)*HH + h)*EE + w) = pk;
        float s = a0 + a1, q = a0*a0 + a1*a1;
        wred2(s, q);
        if (lane == 0) { red[wid][o][0] = s; red[wid][o][1] = q; }
    }
    __syncthreads();
    if (t < 6) {
        float S = 0.f, Q = 0.f;
        #pragma unroll
        for (int wv = 0; wv < 4; ++wv) { S += red[wv][t][0]; Q += red[wv][t][1]; }
        atomicAdd(&mc1[((size_t)b*6 + t)*2],     S);
        atomicAdd(&mc1[((size_t)b*6 + t)*2 + 1], Q);
    }
}

// ---------------------------------------------------------------------------
// GN finalize: combine per-channel sums (two sources) -> per-channel scale/shift.
__global__ __launch_bounds__(256) void k_stats_final(
    const float* __restrict__ A, int ca, const float* __restrict__ Bs, int cb,
    const float* __restrict__ gamma, const float* __restrict__ beta,
    int cpg, float inv_n, int n, float* __restrict__ ss)
{
    int idx = blockIdx.x*256 + threadIdx.x;
    if (idx >= n) return;
    int C = ca + cb;
    int ng = C / cpg;
    int g = idx % ng;
    int b = idx / ng;
    float s = 0.f, q = 0.f;
    for (int cl = 0; cl < cpg; ++cl) {
        int gc = g*cpg + cl;
        const float* p = (gc < ca) ? A + ((size_t)b*ca + gc)*2
                                   : Bs + ((size_t)b*cb + (gc - ca))*2;
        s += p[0]; q += p[1];
    }
    float mean = s * inv_n;
    float var  = q * inv_n - mean*mean;
    float rstd = rsqrtf(var + 1e-5f);
    for (int cl = 0; cl < cpg; ++cl) {
        int gc = g*cpg + cl;
        float sc = gamma[gc] * rstd;
        ss[((size_t)b*C + gc)*2]   = sc;
        ss[((size_t)b*C + gc)*2+1] = beta[gc] - mean*sc;
    }
}

// ---------------------------------------------------------------------------
// GN apply + ReLU + 2x2 maxpool (+ optional SiLU). 2 out-px/thread. 6144 blocks.
__global__ __launch_bounds__(256) void k_gn_relu_pool(
    const bf* __restrict__ src, const float* __restrict__ ss,
    float* __restrict__ dst, int C, int hi, int wi, int do_silu)
{
    int idx = blockIdx.x*256 + threadIdx.x;
    int wo2 = wi >> 2, ho = hi >> 1;
    int xp = idx % wo2; int tmp = idx / wo2;
    int yo = tmp % ho; tmp /= ho;
    int c = tmp % C; int b = tmp / C;
    const bf* p = src + ((size_t)(b*C + c)*hi + yo*2)*wi + xp*4;
    uint2 r0 = *(const uint2*)p;
    uint2 r1 = *(const uint2*)(p + wi);
    float sc = ss[(b*C+c)*2], sh = ss[(b*C+c)*2+1];
    float e0 = fmaxf(b2f(r0.x & 0xffff)*sc+sh, 0.f);
    float e1 = fmaxf(b2f(r0.x >> 16)   *sc+sh, 0.f);
    float e2 = fmaxf(b2f(r0.y & 0xffff)*sc+sh, 0.f);
    float e3 = fmaxf(b2f(r0.y >> 16)   *sc+sh, 0.f);
    float f0 = fmaxf(b2f(r1.x & 0xffff)*sc+sh, 0.f);
    float f1 = fmaxf(b2f(r1.x >> 16)   *sc+sh, 0.f);
    float f2 = fmaxf(b2f(r1.y & 0xffff)*sc+sh, 0.f);
    float f3 = fmaxf(b2f(r1.y >> 16)   *sc+sh, 0.f);
    float m0 = fmaxf(fmaxf(e0, e1), fmaxf(f0, f1));
    float m1 = fmaxf(fmaxf(e2, e3), fmaxf(f2, f3));
    if (do_silu) {
        m0 = m0 / (1.f + expf(-m0));
        m1 = m1 / (1.f + expf(-m1));
    }
    float2 ov; ov.x = m0; ov.y = m1;
    *(float2*)(dst + (size_t)idx*2) = ov;
}

// ---------------------------------------------------------------------------
// K5: conv2 3x3, 6->24, SAME on (64,128). LDS tile. Fused gn2 stats. 2048 blocks.
__global__ __launch_bounds__(256) void k_conv2(
    const float* __restrict__ p1, const float* __restrict__ k,
    const float* __restrict__ bias, bf* __restrict__ c2, float* __restrict__ mc2)
{
    __shared__ float tile[6][6][66];
    __shared__ float red[4][24][2];
    int t = threadIdx.x;
    int wb = blockIdx.x & 1;
    int hb = (blockIdx.x >> 1) & 15;
    int b  = blockIdx.x >> 5;
    int w0 = wb*64, h0 = hb*4;
    for (int i = t; i < 6*6*66; i += 256) {
        int c = i / (6*66);
        int rem = i % (6*66);
        int ty = rem / 66, tx = rem % 66;
        int hh = h0 + ty - 1, ww = w0 + tx - 1;
        float v = 0.f;
        if (hh >= 0 && hh < H2 && ww >= 0 && ww < W2)
            v = p1[((size_t)(b*6 + c)*H2 + hh)*W2 + ww];
        tile[c][ty][tx] = v;
    }
    __syncthreads();
    int wl = t & 63, hl = t >> 6;
    int lane = t & 63, wid = t >> 6;
    float acc[24];
    #pragma unroll
    for (int o = 0; o < 24; ++o) acc[o] = bias[o];
    #pragma unroll
    for (int c = 0; c < 6; ++c)
      #pragma unroll
      for (int ky = 0; ky < 3; ++ky)
        #pragma unroll
        for (int kx = 0; kx < 3; ++kx) {
            float v = tile[c][hl+ky][wl+kx];
            const float* kp = k + (c*9 + ky*3 + kx);
            #pragma unroll
            for (int o = 0; o < 24; ++o)
                acc[o] += v * kp[o*54];
        }
    int h = h0 + hl, w = w0 + wl;
    #pragma unroll
    for (int o = 0; o < 24; ++o) {
        c2[((size_t)(b*24+o)*H2 + h)*W2 + w] = tob(acc[o]);
        float s = acc[o], q = acc[o]*acc[o];
        wred2(s, q);
        if (lane == 0) { red[wid][o][0] = s; red[wid][o][1] = q; }
    }
    __syncthreads();
    if (t < 24) {
        float S = 0.f, Q = 0.f;
        #pragma unroll
        for (int wv = 0; wv < 4; ++wv) { S += red[wv][t][0]; Q += red[wv][t][1]; }
        atomicAdd(&mc2[((size_t)b*24 + t)*2],     S);
        atomicAdd(&mc2[((size_t)b*24 + t)*2 + 1], Q);
    }
}

// ---------------------------------------------------------------------------
// K8: tconv 2x2 s2, 24->24. Thread per INPUT pixel. Fused u3 stats. 512 blocks.
__global__ __launch_bounds__(256) void k_tconv3(
    const float* __restrict__ a, const float* __restrict__ k,
    const float* __restrict__ bias, bf* __restrict__ u3, float* __restrict__ mu3)
{
    __shared__ float wt[24*24*4];
    __shared__ float red[4][24][2];
    int t = threadIdx.x;
    int b  = blockIdx.x >> 3;
    int pg = blockIdx.x & 7;
    for (int i = t; i < 2304; i += 256) wt[i] = k[i];
    __syncthreads();
    int pix = pg*256 + t;
    int h = pix >> 6, w = pix & 63;
    int lane = t & 63, wid = t >> 6;
    const float* ap = a + ((size_t)b*24)*PL4 + pix;
    float acc[24][4];
    #pragma unroll
    for (int o = 0; o < 24; ++o) {
        float bv = bias[o];
        #pragma unroll
        for (int j = 0; j < 4; ++j) acc[o][j] = bv;
    }
    for (int c = 0; c < 24; ++c) {
        float v = ap[(size_t)c*PL4];
        const float* wr = wt + c*96;
        #pragma unroll
        for (int o = 0; o < 24; ++o) {
            acc[o][0] += v * wr[o*4+0];
            acc[o][1] += v * wr[o*4+1];
            acc[o][2] += v * wr[o*4+2];
            acc[o][3] += v * wr[o*4+3];
        }
    }
    #pragma unroll
    for (int o = 0; o < 24; ++o) {
        #pragma unroll
        for (int d = 0; d < 2; ++d) {
            bf2 pk; pk.x = tob(acc[o][d*2+0]); pk.y = tob(acc[o][d*2+1]);
            *(bf2*)(u3 + (((size_t)(b*24+o)*H2 + 2*h+d)*W2 + 2*w)) = pk;
        }
        float s = acc[o][0]+acc[o][1]+acc[o][2]+acc[o][3];
        float q = acc[o][0]*acc[o][0]+acc[o][1]*acc[o][1]
                + acc[o][2]*acc[o][2]+acc[o][3]*acc[o][3];
        wred2(s, q);
        if (lane == 0) { red[wid][o][0] = s; red[wid][o][1] = q; }
    }
    __syncthreads();
    if (t < 24) {
        float S = 0.f, Q = 0.f;
        #pragma unroll
        for (int wv = 0; wv < 4; ++wv) { S += red[wv][t][0]; Q += red[wv][t][1]; }
        atomicAdd(&mu3[((size_t)b*24 + t)*2],     S);
        atomicAdd(&mu3[((size_t)b*24 + t)*2 + 1], Q);
    }
}

// ---------------------------------------------------------------------------
// K10: gn3-fused tconv 2x2 s2, 48->12. Thread per INPUT pixel. Fused u4 stats.
// 2048 blocks.
__global__ __launch_bounds__(256) void k_tconv4(
    const bf* __restrict__ c2, const bf* __restrict__ u3,
    const float* __restrict__ ss3, const float* __restrict__ k,
    const float* __restrict__ bias, bf* __restrict__ u4, float* __restrict__ mu4)
{
    __shared__ float wt[48*12*4];
    __shared__ float red[4][12][2];
    int t = threadIdx.x;
    int b  = blockIdx.x >> 5;
    int pg = blockIdx.x & 31;
    for (int i = t; i < 2304; i += 256) wt[i] = k[i];
    __syncthreads();
    int pix = pg*256 + t;
    int h = pix >> 7, w = pix & 127;
    int lane = t & 63, wid = t >> 6;
    const bf* c2p = c2 + ((size_t)b*24)*PL2 + pix;
    const bf* u3p = u3 + ((size_t)b*24)*PL2 + pix;
    const float* ssp = ss3 + (size_t)b*96;
    float acc[12][4];
    #pragma unroll
    for (int o = 0; o < 12; ++o) {
        float bv = bias[o];
        #pragma unroll
        for (int j = 0; j < 4; ++j) acc[o][j] = bv;
    }
    for (int c = 0; c < 48; ++c) {
        float v = (c < 24) ? tof(c2p[(size_t)c*PL2]) : tof(u3p[(size_t)(c-24)*PL2]);
        v = v * ssp[2*c] + ssp[2*c+1];
        const float* wr = wt + c*48;
        #pragma unroll
        for (int o = 0; o < 12; ++o) {
            acc[o][0] += v * wr[o*4+0];
            acc[o][1] += v * wr[o*4+1];
            acc[o][2] += v * wr[o*4+2];
            acc[o][3] += v * wr[o*4+3];
        }
    }
    #pragma unroll
    for (int o = 0; o < 12; ++o) {
        #pragma unroll
        for (int d = 0; d < 2; ++d) {
            bf2 pk; pk.x = tob(acc[o][d*2+0]); pk.y = tob(acc[o][d*2+1]);
            *(bf2*)(u4 + (((size_t)(b*12+o)*HH + 2*h+d)*EE + 2*w)) = pk;
        }
        float s = acc[o][0]+acc[o][1]+acc[o][2]+acc[o][3];
        float q = acc[o][0]*acc[o][0]+acc[o][1]*acc[o][1]
                + acc[o][2]*acc[o][2]+acc[o][3]*acc[o][3];
        wred2(s, q);
        if (lane == 0) { red[wid][o][0] = s; red[wid][o][1] = q; }
    }
    __syncthreads();
    if (t < 12) {
        float S = 0.f, Q = 0.f;
        #pragma unroll
        for (int wv = 0; wv < 4; ++wv) { S += red[wv][t][0]; Q += red[wv][t][1]; }
        atomicAdd(&mu4[((size_t)b*12 + t)*2],     S);
        atomicAdd(&mu4[((size_t)b*12 + t)*2 + 1], Q);
    }
}

// ---------------------------------------------------------------------------
// K12: gn4-fused 1x1 conv 18->6. 4 px/thread. Fused u5 stats. 2048 blocks.
__global__ __launch_bounds__(256) void k_conv1x1_u5(
    const bf* __restrict__ c1, const bf* __restrict__ u4,
    const float* __restrict__ ss4, const float* __restrict__ k,
    const float* __restrict__ bias, bf* __restrict__ u5, float* __restrict__ mu5)
{
    __shared__ float red[4][6][2];
    int t = threadIdx.x;
    int b  = blockIdx.x >> 5;
    int pg = blockIdx.x & 31;
    int pix = pg*1024 + t*4;
    int lane = t & 63, wid = t >> 6;
    const bf* c1p = c1 + ((size_t)b*6)*HP + pix;
    const bf* u4p = u4 + ((size_t)b*12)*HP + pix;
    const float* ssp = ss4 + (size_t)b*36;
    float acc[6][4];
    #pragma unroll
    for (int o = 0; o < 6; ++o) {
        float bv = bias[o];
        #pragma unroll
        for (int j = 0; j < 4; ++j) acc[o][j] = bv;
    }
    #pragma unroll
    for (int c = 0; c < 18; ++c) {
        uint2 r = (c < 6) ? *(const uint2*)(c1p + (size_t)c*HP)
                          : *(const uint2*)(u4p + (size_t)(c-6)*HP);
        float sc = ssp[2*c], sh = ssp[2*c+1];
        float v0 = b2f(r.x & 0xffff)*sc + sh;
        float v1 = b2f(r.x >> 16)   *sc + sh;
        float v2 = b2f(r.y & 0xffff)*sc + sh;
        float v3 = b2f(r.y >> 16)   *sc + sh;
        #pragma unroll
        for (int o = 0; o < 6; ++o) {
            float wv = k[o*18 + c];
            acc[o][0] += v0*wv; acc[o][1] += v1*wv;
            acc[o][2] += v2*wv; acc[o][3] += v3*wv;
        }
    }
    #pragma unroll
    for (int o = 0; o < 6; ++o) {
        uint2 pk;
        pk.x = (unsigned)bfbits(acc[o][0]) | ((unsigned)bfbits(acc[o][1]) << 16);
        pk.y = (unsigned)bfbits(acc[o][2]) | ((unsigned)bfbits(acc[o][3]) << 16);
        *(uint2*)(u5 + ((size_t)(b*6+o))*HP + pix) = pk;
        float s = acc[o][0]+acc[o][1]+acc[o][2]+acc[o][3];
        float q = acc[o][0]*acc[o][0]+acc[o][1]*acc[o][1]
                + acc[o][2]*acc[o][2]+acc[o][3]*acc[o][3];
        wred2(s, q);
        if (lane == 0) { red[wid][o][0] = s; red[wid][o][1] = q; }
    }
    __syncthreads();
    if (t < 6) {
        float S = 0.f, Q = 0.f;
        #pragma unroll
        for (int wv = 0; wv < 4; ++wv) { S += red[wv][t][0]; Q += red[wv][t][1]; }
        atomicAdd(&mu5[((size_t)b*6 + t)*2],     S);
        atomicAdd(&mu5[((size_t)b*6 + t)*2 + 1], Q);
    }
}

// ---------------------------------------------------------------------------
// K14: gn5-fused final 1x1 conv (6->1) + divide by std(t). 4 px/thread.
__global__ __launch_bounds__(256) void k_final(
    const bf* __restrict__ u5, const float* __restrict__ ss5,
    const float* __restrict__ k, const float* __restrict__ bias,
    const float* __restrict__ t, float* __restrict__ out)
{
    int idx = blockIdx.x*256 + threadIdx.x;   // 524288 = 64 b * 8192 quads
    int b = idx >> 13;
    int pix = (idx & 8191)*4;
    const bf* up = u5 + (size_t)b*6*HP + pix;
    const float* ssp = ss5 + (size_t)b*12;
    float a0 = bias[0], a1 = a0, a2 = a0, a3 = a0;
    #pragma unroll
    for (int c = 0; c < 6; ++c) {
        uint2 r = *(const uint2*)(up + (size_t)c*HP);
        float sc = ssp[2*c], sh = ssp[2*c+1];
        float wv = k[c];
        a0 += (b2f(r.x & 0xffff)*sc + sh) * wv;
        a1 += (b2f(r.x >> 16)   *sc + sh) * wv;
        a2 += (b2f(r.y & 0xffff)*sc + sh) * wv;
        a3 += (b2f(r.y >> 16)   *sc + sh) * wv;
    }
    float tb = t[b];
    const float lns = 3.2188758248682007492f;      // ln 25
    float var = (expf(2.f*tb*lns) - 1.f) / (2.f*lns);
    float rs = rsqrtf(var);
    float4 ov; ov.x = a0*rs; ov.y = a1*rs; ov.z = a2*rs; ov.w = a3*rs;
    *(float4*)(out + (size_t)b*HP + pix) = ov;
}

// ---------------------------------------------------------------------------
extern "C" void kernel_launch(void* const* d_in, const int* in_sizes, int n_in,
                              void* d_out, int out_size, void* d_ws, size_t ws_size,
                              hipStream_t stream)
{
    const float* x       = (const float*)d_in[0];
    const float* t       = (const float*)d_in[1];
    const float* Wf      = (const float*)d_in[2];
    const float* fc1_w   = (const float*)d_in[3];
    const float* fc1_b   = (const float*)d_in[4];
    const float* conv1_k = (const float*)d_in[5];
    const float* conv1_b = (const float*)d_in[6];
    const float* gn1_g   = (const float*)d_in[7];
    const float* gn1_b   = (const float*)d_in[8];
    const float* conv2_k = (const float*)d_in[9];
    const float* conv2_b = (const float*)d_in[10];
    const float* gn2_g   = (const float*)d_in[11];
    const float* gn2_b   = (const float*)d_in[12];
    const float* t3_k    = (const float*)d_in[13];
    const float* t3_b    = (const float*)d_in[14];
    const float* gn3_g   = (const float*)d_in[15];
    const float* gn3_b   = (const float*)d_in[16];
    const float* t4_k    = (const float*)d_in[17];
    const float* t4_b    = (const float*)d_in[18];
    const float* gn4_g   = (const float*)d_in[19];
    const float* gn4_b   = (const float*)d_in[20];
    const float* t5_k    = (const float*)d_in[21];
    const float* t5_b    = (const float*)d_in[22];
    const float* gn5_g   = (const float*)d_in[23];
    const float* gn5_b   = (const float*)d_in[24];
    const float* fin_k   = (const float*)d_in[25];
    const float* fin_b   = (const float*)d_in[26];

    // Workspace (bf16-element units). Peak ~120.1 MiB.
    bf* wsb = (bf*)d_ws;
    bf* c1 = wsb;                          // 12,582,912 el  conv1..conv1x1
    bf* c2 = wsb + 12582912;               // 12,582,912 el  conv2..tconv4
    bf* u3 = wsb + 25165824;               // 12,582,912 el  tconv3..tconv4
    bf* u4 = wsb + 37748736;               // 25,165,824 el  tconv4..conv1x1
    // temporaries inside u4 region (dead before tconv4):
    bf*    xe = wsb + 37748736;            // 2,097,152 el   fourier..gemm
    bf*    xf = wsb + 39845888;            // 2,097,152 el   gemm..conv1
    float* p1 = (float*)(wsb + 41943040);  // 3,145,728 f    pool1..conv2
    float* a_ = (float*)(wsb + 48234496);  // 3,145,728 f    pool2..tconv3
    bf* u5 = wsb + 12582912;               // reuses c2, conv1x1..final
    // stats after bf16 heap
    float* st = (float*)(wsb + 62914560);
    float* s1 = st;             // 768
    float* s2 = st + 768;       // 3072
    float* s3 = st + 3840;      // 6144
    float* s4 = st + 9984;      // 2304
    float* s5 = st + 12288;     // 768
    float* mb = st + 13056;     // 9216 raw channel sums
    float* mc1 = mb;            // 768
    float* mc2 = mb + 768;      // 3072
    float* mu3 = mb + 3840;     // 3072
    float* mu4 = mb + 6912;     // 1536
    float* mu5 = mb + 8448;     // 768

    k_zero<<<9, 256, 0, stream>>>(mb, 9216);
    k_fourier<<<2048, 256, 0, stream>>>(x, Wf, xe);
    k_gemm_fc1<<<512, 256, 0, stream>>>(xe, fc1_w, fc1_b, xf);
    k_conv1<<<4096, 256, 0, stream>>>(xf, conv1_k, conv1_b, c1, mc1);
    k_stats_final<<<2, 256, 0, stream>>>(mc1, 6, (const float*)nullptr, 0,
                                         gn1_g, gn1_b, 1, 1.f/HP, 384, s1);
    k_gn_relu_pool<<<6144, 256, 0, stream>>>(c1, s1, p1, 6, HH, EE, 0);
    k_conv2<<<2048, 256, 0, stream>>>(p1, conv2_k, conv2_b, c2, mc2);
    k_stats_final<<<6, 256, 0, stream>>>(mc2, 24, (const float*)nullptr, 0,
                                         gn2_g, gn2_b, 1, 1.f/PL2, 1536, s2);
    k_gn_relu_pool<<<6144, 256, 0, stream>>>(c2, s2, a_, 24, H2, W2, 1);
    k_tconv3<<<512, 256, 0, stream>>>(a_, t3_k, t3_b, u3, mu3);
    k_stats_final<<<2, 256, 0, stream>>>(mc2, 24, mu3, 24,
                                         gn3_g, gn3_b, 8, 1.f/(PL2*8), 384, s3);
    k_tconv4<<<2048, 256, 0, stream>>>(c2, u3, s3, t4_k, t4_b, u4, mu4);
    k_stats_final<<<2, 256, 0, stream>>>(mc1, 6, mu4, 12,
                                         gn4_g, gn4_b, 3, 1.f/(HP*3), 384, s4);
    k_conv1x1_u5<<<2048, 256, 0, stream>>>(c1, u4, s4, t5_k, t5_b, u5, mu5);
    k_stats_final<<<2, 256, 0, stream>>>(mu5, 6, (const float*)nullptr, 0,
                                         gn5_g, gn5_b, 1, 1.f/HP, 384, s5);
    k_final<<<2048, 256, 0, stream>>>(u5, s5, fin_k, fin_b, t, (float*)d_out);
}

// Round 5
// 333.545 us; speedup vs baseline: 3.7451x; 1.2386x over previous
//
#include <hip/hip_runtime.h>
#include <hip/hip_bf16.h>
#include <math.h>

#define BB 64
#define HH 128
#define WW 128
#define EE 256
#define HP (HH*EE)        // 32768
#define H2 64
#define W2 128
#define PL2 (H2*W2)       // 8192
#define H4 32
#define W4 64
#define PL4 (H4*W4)       // 2048

typedef __hip_bfloat16 bf;
typedef __hip_bfloat162 bf2;
typedef unsigned short ushortt;
typedef __attribute__((ext_vector_type(8))) __bf16 b8v;
typedef __attribute__((ext_vector_type(4))) float f4v;

__device__ __forceinline__ float tof(float v) { return v; }
__device__ __forceinline__ float tof(bf v)    { return __bfloat162float(v); }
__device__ __forceinline__ bf    tob(float v) { return __float2bfloat16(v); }
__device__ __forceinline__ unsigned int bfbits(float v) {
    return (unsigned int)__builtin_bit_cast(unsigned short, __float2bfloat16(v));
}
__device__ __forceinline__ float b2f(unsigned int u16) {
    unsigned int x = u16 << 16;
    return __builtin_bit_cast(float, x);
}
// 64-lane butterfly reduction of (s, q)
__device__ __forceinline__ void wred2(float& s, float& q) {
    #pragma unroll
    for (int m = 32; m; m >>= 1) {
        s += __shfl_xor(s, m);
        q += __shfl_xor(q, m);
    }
}

// ---------------------------------------------------------------------------
// K0: zero the atomic-sum scratch (graph-safe, runs every call).
__global__ __launch_bounds__(256) void k_zero(float* __restrict__ p, int n)
{
    for (int i = blockIdx.x*256 + threadIdx.x; i < n; i += gridDim.x*256) p[i] = 0.f;
}

// ---------------------------------------------------------------------------
// K1a: Gaussian Fourier features -> xe bf16 [8192][256]. 2048 blocks.
__global__ __launch_bounds__(256) void k_fourier(
    const float* __restrict__ x, const float* __restrict__ Wf, bf* __restrict__ xe)
{
    int idx = blockIdx.x*256 + threadIdx.x;
    int row = idx >> 6, wp = idx & 63;
    float2 xv = *(const float2*)(x + (size_t)row*WW + wp*2);
    float2 wv = *(const float2*)(Wf + (size_t)(row & (HH-1))*WW + wp*2);
    const float TP = 6.2831853071795864769f;
    float s0, c0, s1, c1;
    sincosf(xv.x*wv.x*TP, &s0, &c0);
    sincosf(xv.y*wv.y*TP, &s1, &c1);
    bf* rp = xe + (size_t)row*EE + wp*2;
    bf2 sv; sv.x = tob(s0); sv.y = tob(s1); *(bf2*)rp = sv;
    bf2 cv; cv.x = tob(c0); cv.y = tob(c1); *(bf2*)(rp + WW) = cv;
}

// ---------------------------------------------------------------------------
// K1b: fc1 GEMM via MFMA. 512 blocks.
__global__ __launch_bounds__(256) void k_gemm_fc1(
    const bf* __restrict__ xe, const float* __restrict__ fc1_w,
    const float* __restrict__ fc1_b, bf* __restrict__ xf)
{
    __shared__ ushortt sA[64*264];
    __shared__ ushortt sB[64*264];
    int tid = threadIdx.x;
    int rb = blockIdx.x >> 2, cb = blockIdx.x & 3;
    int row0 = rb*64, col0 = cb*64;
    #pragma unroll
    for (int it = 0; it < 8; ++it) {
        int i = it*256 + tid;
        int r = i >> 5, ch = i & 31;
        uint4 v = *(const uint4*)(xe + (size_t)(row0 + r)*EE + ch*8);
        *(uint4*)&sA[r*264 + ch*8] = v;
    }
    #pragma unroll
    for (int it = 0; it < 16; ++it) {
        int i = it*256 + tid;
        int o = i >> 6, c4 = i & 63;
        float4 w4 = *(const float4*)(fc1_w + (size_t)(col0 + o)*EE + c4*4);
        uint2 pk;
        pk.x = bfbits(w4.x) | (bfbits(w4.y) << 16);
        pk.y = bfbits(w4.z) | (bfbits(w4.w) << 16);
        *(uint2*)&sB[o*264 + c4*4] = pk;
    }
    __syncthreads();
    int lane = tid & 63, wid = tid >> 6;
    int m = lane & 15, kq = (lane >> 4) * 8;
    f4v acc[4] = {};
    const ushortt* aBase = &sA[(wid*16 + m)*264 + kq];
    #pragma unroll
    for (int k0 = 0; k0 < 8; ++k0) {
        b8v av = *(const b8v*)(aBase + k0*32);
        #pragma unroll
        for (int t4 = 0; t4 < 4; ++t4) {
            b8v bv = *(const b8v*)&sB[(t4*16 + m)*264 + k0*32 + kq];
            acc[t4] = __builtin_amdgcn_mfma_f32_16x16x32_bf16(av, bv, acc[t4], 0, 0, 0);
        }
    }
    int rbase = row0 + wid*16 + (lane >> 4)*4;
    #pragma unroll
    for (int t4 = 0; t4 < 4; ++t4) {
        int col = col0 + t4*16 + m;
        float bias = fc1_b[col];
        #pragma unroll
        for (int r = 0; r < 4; ++r)
            xf[(size_t)(rbase + r)*EE + col] = tob(acc[t4][r] + bias);
    }
}

// ---------------------------------------------------------------------------
// K2: conv1 3x3, 1->6, SAME, on bf16 xf. 2 px/thread. 4096 blocks. Fused gn1 stats.
__global__ __launch_bounds__(256) void k_conv1(
    const bf* __restrict__ xf, const float* __restrict__ k,
    const float* __restrict__ bias, bf* __restrict__ c1, float* __restrict__ mc1)
{
    __shared__ float red[4][6][2];
    int t = threadIdx.x;
    int wt = blockIdx.x & 1;
    int ht = (blockIdx.x >> 1) & 31;
    int b  = blockIdx.x >> 6;
    int pr = t & 63, rw = t >> 6;
    int w = wt*128 + pr*2;
    int h = ht*4 + rw;
    int lane = t & 63, wid = t >> 6;
    const bf* src = xf + (size_t)b*HP;
    float v[3][4];
    #pragma unroll
    for (int ky = 0; ky < 3; ++ky) {
        int yy = h + ky - 1;
        #pragma unroll
        for (int kx = 0; kx < 4; ++kx) {
            int xx = w + kx - 1;
            v[ky][kx] = (yy >= 0 && yy < HH && xx >= 0 && xx < EE)
                        ? tof(src[(size_t)yy*EE + xx]) : 0.f;
        }
    }
    #pragma unroll
    for (int o = 0; o < 6; ++o) {
        float a0 = bias[o], a1 = a0;
        #pragma unroll
        for (int ky = 0; ky < 3; ++ky)
          #pragma unroll
          for (int kx = 0; kx < 3; ++kx) {
            float wv = k[o*9 + ky*3 + kx];
            a0 += v[ky][kx]   * wv;
            a1 += v[ky][kx+1] * wv;
          }
        bf2 pk; pk.x = tob(a0); pk.y = tob(a1);
        *(bf2*)(c1 + ((size_t)(b*6+o)*HH + h)*EE + w) = pk;
        float s = a0 + a1, q = a0*a0 + a1*a1;
        wred2(s, q);
        if (lane == 0) { red[wid][o][0] = s; red[wid][o][1] = q; }
    }
    __syncthreads();
    if (t < 6) {
        float S = 0.f, Q = 0.f;
        #pragma unroll
        for (int wv = 0; wv < 4; ++wv) { S += red[wv][t][0]; Q += red[wv][t][1]; }
        atomicAdd(&mc1[((size_t)b*6 + t)*2],     S);
        atomicAdd(&mc1[((size_t)b*6 + t)*2 + 1], Q);
    }
}

// ---------------------------------------------------------------------------
// GN finalize: combine per-channel sums (two sources) -> per-channel scale/shift.
__global__ __launch_bounds__(256) void k_stats_final(
    const float* __restrict__ A, int ca, const float* __restrict__ Bs, int cb,
    const float* __restrict__ gamma, const float* __restrict__ beta,
    int cpg, float inv_n, int n, float* __restrict__ ss)
{
    int idx = blockIdx.x*256 + threadIdx.x;
    if (idx >= n) return;
    int C = ca + cb;
    int ng = C / cpg;
    int g = idx % ng;
    int b = idx / ng;
    float s = 0.f, q = 0.f;
    for (int cl = 0; cl < cpg; ++cl) {
        int gc = g*cpg + cl;
        const float* p = (gc < ca) ? A + ((size_t)b*ca + gc)*2
                                   : Bs + ((size_t)b*cb + (gc - ca))*2;
        s += p[0]; q += p[1];
    }
    float mean = s * inv_n;
    float var  = q * inv_n - mean*mean;
    float rstd = rsqrtf(var + 1e-5f);
    for (int cl = 0; cl < cpg; ++cl) {
        int gc = g*cpg + cl;
        float sc = gamma[gc] * rstd;
        ss[((size_t)b*C + gc)*2]   = sc;
        ss[((size_t)b*C + gc)*2+1] = beta[gc] - mean*sc;
    }
}

// ---------------------------------------------------------------------------
// GN apply + ReLU + 2x2 maxpool (+ optional SiLU). 2 out-px/thread. 6144 blocks.
__global__ __launch_bounds__(256) void k_gn_relu_pool(
    const bf* __restrict__ src, const float* __restrict__ ss,
    float* __restrict__ dst, int C, int hi, int wi, int do_silu)
{
    int idx = blockIdx.x*256 + threadIdx.x;
    int wo2 = wi >> 2, ho = hi >> 1;
    int xp = idx % wo2; int tmp = idx / wo2;
    int yo = tmp % ho; tmp /= ho;
    int c = tmp % C; int b = tmp / C;
    const bf* p = src + ((size_t)(b*C + c)*hi + yo*2)*wi + xp*4;
    uint2 r0 = *(const uint2*)p;
    uint2 r1 = *(const uint2*)(p + wi);
    float sc = ss[(b*C+c)*2], sh = ss[(b*C+c)*2+1];
    float e0 = fmaxf(b2f(r0.x & 0xffff)*sc+sh, 0.f);
    float e1 = fmaxf(b2f(r0.x >> 16)   *sc+sh, 0.f);
    float e2 = fmaxf(b2f(r0.y & 0xffff)*sc+sh, 0.f);
    float e3 = fmaxf(b2f(r0.y >> 16)   *sc+sh, 0.f);
    float f0 = fmaxf(b2f(r1.x & 0xffff)*sc+sh, 0.f);
    float f1 = fmaxf(b2f(r1.x >> 16)   *sc+sh, 0.f);
    float f2 = fmaxf(b2f(r1.y & 0xffff)*sc+sh, 0.f);
    float f3 = fmaxf(b2f(r1.y >> 16)   *sc+sh, 0.f);
    float m0 = fmaxf(fmaxf(e0, e1), fmaxf(f0, f1));
    float m1 = fmaxf(fmaxf(e2, e3), fmaxf(f2, f3));
    if (do_silu) {
        m0 = m0 / (1.f + expf(-m0));
        m1 = m1 / (1.f + expf(-m1));
    }
    float2 ov; ov.x = m0; ov.y = m1;
    *(float2*)(dst + (size_t)idx*2) = ov;
}

// ---------------------------------------------------------------------------
// K5: conv2 3x3, 6->24. Register-resident activations, 4 px/thread; weights
// streamed per-o as uniform (scalar) loads. 512 blocks (64 b x 8 h-tiles).
// Fused gn2 stats.
__global__ __launch_bounds__(256) void k_conv2(
    const float* __restrict__ p1, const float* __restrict__ kw,
    const float* __restrict__ bias, bf* __restrict__ c2, float* __restrict__ mc2)
{
    __shared__ float tile[6][10][132];
    __shared__ float red[4][24][2];
    int t = threadIdx.x;
    int ht = blockIdx.x & 7, b = blockIdx.x >> 3;
    int h0 = ht*8;
    int lane = t & 63, wid = t >> 6;
    for (int i = t; i < 7920; i += 256) {
        int c = i / 1320, rem = i % 1320;
        int ty = rem / 132, tx = rem % 132;
        int hh = h0 + ty - 1, ww = tx - 1;
        float v = 0.f;
        if (hh >= 0 && hh < H2 && ww >= 0 && ww < W2)
            v = p1[((size_t)(b*6+c))*PL2 + hh*W2 + ww];
        tile[c][ty][tx] = v;
    }
    __syncthreads();
    int hl = t >> 5, wq = (t & 31)*4;
    float A[6][3][6];
    #pragma unroll
    for (int c = 0; c < 6; ++c)
      #pragma unroll
      for (int ky = 0; ky < 3; ++ky) {
        float4 v4 = *(const float4*)&tile[c][hl+ky][wq];
        float2 v2 = *(const float2*)&tile[c][hl+ky][wq+4];
        A[c][ky][0]=v4.x; A[c][ky][1]=v4.y; A[c][ky][2]=v4.z; A[c][ky][3]=v4.w;
        A[c][ky][4]=v2.x; A[c][ky][5]=v2.y;
      }
    int h = h0 + hl;
    #pragma unroll 1
    for (int o = 0; o < 24; ++o) {
        const float* ko = kw + o*54;
        float w[54];
        #pragma unroll
        for (int j = 0; j < 54; ++j) w[j] = ko[j];
        float bv = bias[o];
        float a0=bv, a1=bv, a2=bv, a3=bv;
        #pragma unroll
        for (int c = 0; c < 6; ++c)
          #pragma unroll
          for (int ky = 0; ky < 3; ++ky)
            #pragma unroll
            for (int kx = 0; kx < 3; ++kx) {
                float wv = w[c*9 + ky*3 + kx];
                a0 += A[c][ky][kx+0]*wv;
                a1 += A[c][ky][kx+1]*wv;
                a2 += A[c][ky][kx+2]*wv;
                a3 += A[c][ky][kx+3]*wv;
            }
        uint2 pk;
        pk.x = bfbits(a0) | (bfbits(a1) << 16);
        pk.y = bfbits(a2) | (bfbits(a3) << 16);
        *(uint2*)(c2 + ((size_t)(b*24+o)*H2 + h)*W2 + wq) = pk;
        float s = a0+a1+a2+a3, q = a0*a0+a1*a1+a2*a2+a3*a3;
        wred2(s, q);
        if (lane == 0) { red[wid][o][0] = s; red[wid][o][1] = q; }
    }
    __syncthreads();
    if (t < 24) {
        float S = 0.f, Q = 0.f;
        #pragma unroll
        for (int wv = 0; wv < 4; ++wv) { S += red[wv][t][0]; Q += red[wv][t][1]; }
        atomicAdd(&mc2[((size_t)b*24 + t)*2],     S);
        atomicAdd(&mc2[((size_t)b*24 + t)*2 + 1], Q);
    }
}

// ---------------------------------------------------------------------------
// K8: tconv 2x2 s2, 24->24. Thread per INPUT pixel. Fused u3 stats. 512 blocks.
__global__ __launch_bounds__(256) void k_tconv3(
    const float* __restrict__ a, const float* __restrict__ k,
    const float* __restrict__ bias, bf* __restrict__ u3, float* __restrict__ mu3)
{
    __shared__ float wt[24*24*4];
    __shared__ float red[4][24][2];
    int t = threadIdx.x;
    int b  = blockIdx.x >> 3;
    int pg = blockIdx.x & 7;
    for (int i = t; i < 2304; i += 256) wt[i] = k[i];
    __syncthreads();
    int pix = pg*256 + t;
    int h = pix >> 6, w = pix & 63;
    int lane = t & 63, wid = t >> 6;
    const float* ap = a + ((size_t)b*24)*PL4 + pix;
    float acc[24][4];
    #pragma unroll
    for (int o = 0; o < 24; ++o) {
        float bv = bias[o];
        #pragma unroll
        for (int j = 0; j < 4; ++j) acc[o][j] = bv;
    }
    for (int c = 0; c < 24; ++c) {
        float v = ap[(size_t)c*PL4];
        const float* wr = wt + c*96;
        #pragma unroll
        for (int o = 0; o < 24; ++o) {
            acc[o][0] += v * wr[o*4+0];
            acc[o][1] += v * wr[o*4+1];
            acc[o][2] += v * wr[o*4+2];
            acc[o][3] += v * wr[o*4+3];
        }
    }
    #pragma unroll
    for (int o = 0; o < 24; ++o) {
        #pragma unroll
        for (int d = 0; d < 2; ++d) {
            bf2 pk; pk.x = tob(acc[o][d*2+0]); pk.y = tob(acc[o][d*2+1]);
            *(bf2*)(u3 + (((size_t)(b*24+o)*H2 + 2*h+d)*W2 + 2*w)) = pk;
        }
        float s = acc[o][0]+acc[o][1]+acc[o][2]+acc[o][3];
        float q = acc[o][0]*acc[o][0]+acc[o][1]*acc[o][1]
                + acc[o][2]*acc[o][2]+acc[o][3]*acc[o][3];
        wred2(s, q);
        if (lane == 0) { red[wid][o][0] = s; red[wid][o][1] = q; }
    }
    __syncthreads();
    if (t < 24) {
        float S = 0.f, Q = 0.f;
        #pragma unroll
        for (int wv = 0; wv < 4; ++wv) { S += red[wv][t][0]; Q += red[wv][t][1]; }
        atomicAdd(&mu3[((size_t)b*24 + t)*2],     S);
        atomicAdd(&mu3[((size_t)b*24 + t)*2 + 1], Q);
    }
}

// ---------------------------------------------------------------------------
// K10: gn3-fused tconv 2x2 s2, 48->12 via MFMA implicit GEMM.
// Block = 256 input px (2 rows), M=256, K=48(pad 64), N=48. 2048 blocks.
// C round-trips LDS for coalesced writes + fused u4 stats.
__global__ __launch_bounds__(256) void k_tconv4(
    const bf* __restrict__ c2, const bf* __restrict__ u3,
    const float* __restrict__ ss3, const float* __restrict__ k4,
    const float* __restrict__ bias4, bf* __restrict__ u4, float* __restrict__ mu4)
{
    __shared__ ushortt sA[256*72];   // [px][kpad] bf16, also reused as C staging
    __shared__ ushortt sW[48*72];    // [n][kpad] bf16
    __shared__ float redS[12], redQ[12];
    int t = threadIdx.x;
    int b = blockIdx.x >> 5, pg = blockIdx.x & 31;
    int lane = t & 63, wid = t >> 6;
    if (t < 12) { redS[t] = 0.f; redQ[t] = 0.f; }
    // stage W transposed: global [c][n] -> LDS [n][kpad=c] (+ bias folded later)
    #pragma unroll
    for (int j = 0; j < 9; ++j) {
        int e = j*256 + t;
        if (e < 2304) {
            int c = e / 48, n = e % 48;
            sW[n*72 + c] = (ushortt)bfbits(k4[e]);
        }
    }
    if (t < 96) {
        uint4 z = {0,0,0,0};
        int n = t >> 1, c0 = 48 + (t & 1)*8;
        *(uint4*)&sW[n*72 + c0] = z;
    }
    // stage A: gn3-affine of concat(c2,u3) -> [px][kpad]
    {
        int pix = pg*256 + t;
        const bf* c2p = c2 + (size_t)b*24*PL2 + pix;
        const bf* u3p = u3 + (size_t)b*24*PL2 + pix;
        const float* ssp = ss3 + (size_t)b*96;
        ushortt* row = &sA[t*72];
        #pragma unroll
        for (int g = 0; g < 6; ++g) {
            unsigned pr[4];
            #pragma unroll
            for (int hc = 0; hc < 4; ++hc) {
                int c0 = g*8 + hc*2;
                float r0 = (c0 < 24) ? tof(c2p[(size_t)c0*PL2]) : tof(u3p[(size_t)(c0-24)*PL2]);
                float r1 = (c0+1 < 24) ? tof(c2p[(size_t)(c0+1)*PL2]) : tof(u3p[(size_t)(c0+1-24)*PL2]);
                float v0 = r0 * ssp[2*c0]   + ssp[2*c0+1];
                float v1 = r1 * ssp[2*c0+2] + ssp[2*c0+3];
                pr[hc] = bfbits(v0) | (bfbits(v1) << 16);
            }
            uint4 pk; pk.x = pr[0]; pk.y = pr[1]; pk.z = pr[2]; pk.w = pr[3];
            *(uint4*)&row[g*8] = pk;
        }
        uint4 z = {0,0,0,0};
        *(uint4*)&row[48] = z;
        *(uint4*)&row[56] = z;
    }
    __syncthreads();
    // MFMA: each wave: 64 px (4 M-tiles) x 48 n (3 N-tiles), K=64 (2 steps)
    int m = lane & 15, kq = (lane >> 4)*8;
    b8v bfr[3][2];
    #pragma unroll
    for (int nt = 0; nt < 3; ++nt)
      #pragma unroll
      for (int ks = 0; ks < 2; ++ks)
        bfr[nt][ks] = *(const b8v*)&sW[(nt*16 + m)*72 + ks*32 + kq];
    f4v acc[4][3] = {};
    #pragma unroll
    for (int mt = 0; mt < 4; ++mt) {
        const ushortt* ab = &sA[(wid*64 + mt*16 + m)*72 + kq];
        b8v a0 = *(const b8v*)(ab);
        b8v a1 = *(const b8v*)(ab + 32);
        #pragma unroll
        for (int nt = 0; nt < 3; ++nt) {
            acc[mt][nt] = __builtin_amdgcn_mfma_f32_16x16x32_bf16(a0, bfr[nt][0], acc[mt][nt], 0, 0, 0);
            acc[mt][nt] = __builtin_amdgcn_mfma_f32_16x16x32_bf16(a1, bfr[nt][1], acc[mt][nt], 0, 0, 0);
        }
    }
    __syncthreads();
    // C -> LDS staging in output layout [o][yl(4)][x(256)] bf16 (alias sA)
    ushortt* sC = sA;
    int q4 = lane >> 4;
    #pragma unroll
    for (int mt = 0; mt < 4; ++mt) {
        int pxb = wid*64 + mt*16 + q4*4;
        #pragma unroll
        for (int nt = 0; nt < 3; ++nt) {
            int n = nt*16 + m;
            int o = n >> 2, d = (n >> 1) & 1, qq = n & 1;
            float bo = bias4[o];
            #pragma unroll
            for (int r = 0; r < 4; ++r) {
                int px = pxb + r;
                int yl = ((px >> 7) << 1) + d;
                int xx = ((px & 127) << 1) + qq;
                sC[o*1024 + yl*256 + xx] = (ushortt)bfbits(acc[mt][nt][r] + bo);
            }
        }
    }
    __syncthreads();
    // coalesced global write + stats
    {
        bf* outb = u4 + (size_t)b*12*HP;
        #pragma unroll
        for (int j = 0; j < 6; ++j) {
            int idx16 = j*256 + t;
            int el = idx16*8;
            int o = el >> 10, rem = el & 1023, yl = rem >> 8, x0 = rem & 255;
            uint4 v = *(const uint4*)&sC[el];
            *(uint4*)(outb + ((size_t)o*HH + pg*4 + yl)*EE + x0) = v;
            float v0 = b2f(v.x & 0xffff), v1 = b2f(v.x >> 16);
            float v2 = b2f(v.y & 0xffff), v3 = b2f(v.y >> 16);
            float v4 = b2f(v.z & 0xffff), v5 = b2f(v.z >> 16);
            float v6 = b2f(v.w & 0xffff), v7 = b2f(v.w >> 16);
            float s = v0+v1+v2+v3+v4+v5+v6+v7;
            float qv = v0*v0+v1*v1+v2*v2+v3*v3+v4*v4+v5*v5+v6*v6+v7*v7;
            wred2(s, qv);
            if (lane == 0) { atomicAdd(&redS[o], s); atomicAdd(&redQ[o], qv); }
        }
    }
    __syncthreads();
    if (t < 12) {
        atomicAdd(&mu4[((size_t)b*12 + t)*2],     redS[t]);
        atomicAdd(&mu4[((size_t)b*12 + t)*2 + 1], redQ[t]);
    }
}

// ---------------------------------------------------------------------------
// K12: gn4-fused 1x1 conv 18->6. 4 px/thread. Fused u5 stats. 2048 blocks.
__global__ __launch_bounds__(256) void k_conv1x1_u5(
    const bf* __restrict__ c1, const bf* __restrict__ u4,
    const float* __restrict__ ss4, const float* __restrict__ k,
    const float* __restrict__ bias, bf* __restrict__ u5, float* __restrict__ mu5)
{
    __shared__ float red[4][6][2];
    int t = threadIdx.x;
    int b  = blockIdx.x >> 5;
    int pg = blockIdx.x & 31;
    int pix = pg*1024 + t*4;
    int lane = t & 63, wid = t >> 6;
    const bf* c1p = c1 + ((size_t)b*6)*HP + pix;
    const bf* u4p = u4 + ((size_t)b*12)*HP + pix;
    const float* ssp = ss4 + (size_t)b*36;
    float acc[6][4];
    #pragma unroll
    for (int o = 0; o < 6; ++o) {
        float bv = bias[o];
        #pragma unroll
        for (int j = 0; j < 4; ++j) acc[o][j] = bv;
    }
    #pragma unroll
    for (int c = 0; c < 18; ++c) {
        uint2 r = (c < 6) ? *(const uint2*)(c1p + (size_t)c*HP)
                          : *(const uint2*)(u4p + (size_t)(c-6)*HP);
        float sc = ssp[2*c], sh = ssp[2*c+1];
        float v0 = b2f(r.x & 0xffff)*sc + sh;
        float v1 = b2f(r.x >> 16)   *sc + sh;
        float v2 = b2f(r.y & 0xffff)*sc + sh;
        float v3 = b2f(r.y >> 16)   *sc + sh;
        #pragma unroll
        for (int o = 0; o < 6; ++o) {
            float wv = k[o*18 + c];
            acc[o][0] += v0*wv; acc[o][1] += v1*wv;
            acc[o][2] += v2*wv; acc[o][3] += v3*wv;
        }
    }
    #pragma unroll
    for (int o = 0; o < 6; ++o) {
        uint2 pk;
        pk.x = bfbits(acc[o][0]) | (bfbits(acc[o][1]) << 16);
        pk.y = bfbits(acc[o][2]) | (bfbits(acc[o][3]) << 16);
        *(uint2*)(u5 + ((size_t)(b*6+o))*HP + pix) = pk;
        float s = acc[o][0]+acc[o][1]+acc[o][2]+acc[o][3];
        float q = acc[o][0]*acc[o][0]+acc[o][1]*acc[o][1]
                + acc[o][2]*acc[o][2]+acc[o][3]*acc[o][3];
        wred2(s, q);
        if (lane == 0) { red[wid][o][0] = s; red[wid][o][1] = q; }
    }
    __syncthreads();
    if (t < 6) {
        float S = 0.f, Q = 0.f;
        #pragma unroll
        for (int wv = 0; wv < 4; ++wv) { S += red[wv][t][0]; Q += red[wv][t][1]; }
        atomicAdd(&mu5[((size_t)b*6 + t)*2],     S);
        atomicAdd(&mu5[((size_t)b*6 + t)*2 + 1], Q);
    }
}

// ---------------------------------------------------------------------------
// K14: gn5-fused final 1x1 conv (6->1) + divide by std(t). 4 px/thread.
__global__ __launch_bounds__(256) void k_final(
    const bf* __restrict__ u5, const float* __restrict__ ss5,
    const float* __restrict__ k, const float* __restrict__ bias,
    const float* __restrict__ t, float* __restrict__ out)
{
    int idx = blockIdx.x*256 + threadIdx.x;
    int b = idx >> 13;
    int pix = (idx & 8191)*4;
    const bf* up = u5 + (size_t)b*6*HP + pix;
    const float* ssp = ss5 + (size_t)b*12;
    float a0 = bias[0], a1 = a0, a2 = a0, a3 = a0;
    #pragma unroll
    for (int c = 0; c < 6; ++c) {
        uint2 r = *(const uint2*)(up + (size_t)c*HP);
        float sc = ssp[2*c], sh = ssp[2*c+1];
        float wv = k[c];
        a0 += (b2f(r.x & 0xffff)*sc + sh) * wv;
        a1 += (b2f(r.x >> 16)   *sc + sh) * wv;
        a2 += (b2f(r.y & 0xffff)*sc + sh) * wv;
        a3 += (b2f(r.y >> 16)   *sc + sh) * wv;
    }
    float tb = t[b];
    const float lns = 3.2188758248682007492f;      // ln 25
    float var = (expf(2.f*tb*lns) - 1.f) / (2.f*lns);
    float rs = rsqrtf(var);
    float4 ov; ov.x = a0*rs; ov.y = a1*rs; ov.z = a2*rs; ov.w = a3*rs;
    *(float4*)(out + (size_t)b*HP + pix) = ov;
}

// ---------------------------------------------------------------------------
extern "C" void kernel_launch(void* const* d_in, const int* in_sizes, int n_in,
                              void* d_out, int out_size, void* d_ws, size_t ws_size,
                              hipStream_t stream)
{
    const float* x       = (const float*)d_in[0];
    const float* t       = (const float*)d_in[1];
    const float* Wf      = (const float*)d_in[2];
    const float* fc1_w   = (const float*)d_in[3];
    const float* fc1_b   = (const float*)d_in[4];
    const float* conv1_k = (const float*)d_in[5];
    const float* conv1_b = (const float*)d_in[6];
    const float* gn1_g   = (const float*)d_in[7];
    const float* gn1_b   = (const float*)d_in[8];
    const float* conv2_k = (const float*)d_in[9];
    const float* conv2_b = (const float*)d_in[10];
    const float* gn2_g   = (const float*)d_in[11];
    const float* gn2_b   = (const float*)d_in[12];
    const float* t3_k    = (const float*)d_in[13];
    const float* t3_b    = (const float*)d_in[14];
    const float* gn3_g   = (const float*)d_in[15];
    const float* gn3_b   = (const float*)d_in[16];
    const float* t4_k    = (const float*)d_in[17];
    const float* t4_b    = (const float*)d_in[18];
    const float* gn4_g   = (const float*)d_in[19];
    const float* gn4_b   = (const float*)d_in[20];
    const float* t5_k    = (const float*)d_in[21];
    const float* t5_b    = (const float*)d_in[22];
    const float* gn5_g   = (const float*)d_in[23];
    const float* gn5_b   = (const float*)d_in[24];
    const float* fin_k   = (const float*)d_in[25];
    const float* fin_b   = (const float*)d_in[26];

    // Workspace (bf16-element units). Peak ~120.1 MiB.
    bf* wsb = (bf*)d_ws;
    bf* c1 = wsb;                          // conv1..conv1x1
    bf* c2 = wsb + 12582912;               // conv2..tconv4
    bf* u3 = wsb + 25165824;               // tconv3..tconv4
    bf* u4 = wsb + 37748736;               // tconv4..conv1x1
    bf*    xe = wsb + 37748736;            // fourier..gemm (in u4 region)
    bf*    xf = wsb + 39845888;            // gemm..conv1
    float* p1 = (float*)(wsb + 41943040);  // pool1..conv2
    float* a_ = (float*)(wsb + 48234496);  // pool2..tconv3
    bf* u5 = wsb + 12582912;               // reuses c2, conv1x1..final
    float* st = (float*)(wsb + 62914560);
    float* s1 = st;             // 768
    float* s2 = st + 768;       // 3072
    float* s3 = st + 3840;      // 6144
    float* s4 = st + 9984;      // 2304
    float* s5 = st + 12288;     // 768
    float* mb = st + 13056;     // raw channel sums
    float* mc1 = mb;            // 768
    float* mc2 = mb + 768;      // 3072
    float* mu3 = mb + 3840;     // 3072
    float* mu4 = mb + 6912;     // 1536
    float* mu5 = mb + 8448;     // 768

    k_zero<<<9, 256, 0, stream>>>(mb, 9216);
    k_fourier<<<2048, 256, 0, stream>>>(x, Wf, xe);
    k_gemm_fc1<<<512, 256, 0, stream>>>(xe, fc1_w, fc1_b, xf);
    k_conv1<<<4096, 256, 0, stream>>>(xf, conv1_k, conv1_b, c1, mc1);
    k_stats_final<<<2, 256, 0, stream>>>(mc1, 6, (const float*)nullptr, 0,
                                         gn1_g, gn1_b, 1, 1.f/HP, 384, s1);
    k_gn_relu_pool<<<6144, 256, 0, stream>>>(c1, s1, p1, 6, HH, EE, 0);
    k_conv2<<<512, 256, 0, stream>>>(p1, conv2_k, conv2_b, c2, mc2);
    k_stats_final<<<6, 256, 0, stream>>>(mc2, 24, (const float*)nullptr, 0,
                                         gn2_g, gn2_b, 1, 1.f/PL2, 1536, s2);
    k_gn_relu_pool<<<6144, 256, 0, stream>>>(c2, s2, a_, 24, H2, W2, 1);
    k_tconv3<<<512, 256, 0, stream>>>(a_, t3_k, t3_b, u3, mu3);
    k_stats_final<<<2, 256, 0, stream>>>(mc2, 24, mu3, 24,
                                         gn3_g, gn3_b, 8, 1.f/(PL2*8), 384, s3);
    k_tconv4<<<2048, 256, 0, stream>>>(c2, u3, s3, t4_k, t4_b, u4, mu4);
    k_stats_final<<<2, 256, 0, stream>>>(mc1, 6, mu4, 12,
                                         gn4_g, gn4_b, 3, 1.f/(HP*3), 384, s4);
    k_conv1x1_u5<<<2048, 256, 0, stream>>>(c1, u4, s4, t5_k, t5_b, u5, mu5);
    k_stats_final<<<2, 256, 0, stream>>>(mu5, 6, (const float*)nullptr, 0,
                                         gn5_g, gn5_b, 1, 1.f/HP, 384, s5);
    k_final<<<2048, 256, 0, stream>>>(u5, s5, fin_k, fin_b, t, (float*)d_out);
}

// Round 6
// 287.312 us; speedup vs baseline: 4.3477x; 1.1609x over previous
//
#include <hip/hip_runtime.h>
#include <hip/hip_bf16.h>
#include <math.h>

#define BB 64
#define HH 128
#define WW 128
#define EE 256
#define HP (HH*EE)        // 32768
#define H2 64
#define W2 128
#define PL2 (H2*W2)       // 8192
#define H4 32
#define W4 64
#define PL4 (H4*W4)       // 2048

typedef __hip_bfloat16 bf;
typedef __hip_bfloat162 bf2;
typedef unsigned short ushortt;
typedef __attribute__((ext_vector_type(8))) __bf16 b8v;
typedef __attribute__((ext_vector_type(4))) float f4v;

__device__ __forceinline__ float tof(float v) { return v; }
__device__ __forceinline__ float tof(bf v)    { return __bfloat162float(v); }
__device__ __forceinline__ bf    tob(float v) { return __float2bfloat16(v); }
__device__ __forceinline__ unsigned int bfbits(float v) {
    return (unsigned int)__builtin_bit_cast(ushortt, __float2bfloat16(v));
}
__device__ __forceinline__ float b2f(unsigned int u16) {
    unsigned int x = u16 << 16;
    return __builtin_bit_cast(float, x);
}
__device__ __forceinline__ void wred2(float& s, float& q) {
    #pragma unroll
    for (int m = 32; m; m >>= 1) {
        s += __shfl_xor(s, m);
        q += __shfl_xor(q, m);
    }
}

// ---------------------------------------------------------------------------
__global__ __launch_bounds__(256) void k_zero(float* __restrict__ p, int n)
{
    for (int i = blockIdx.x*256 + threadIdx.x; i < n; i += gridDim.x*256) p[i] = 0.f;
}

// ---------------------------------------------------------------------------
// K1a: Gaussian Fourier features -> xe bf16 [8192][256]. 2048 blocks.
__global__ __launch_bounds__(256) void k_fourier(
    const float* __restrict__ x, const float* __restrict__ Wf, bf* __restrict__ xe)
{
    int idx = blockIdx.x*256 + threadIdx.x;
    int row = idx >> 6, wp = idx & 63;
    float2 xv = *(const float2*)(x + (size_t)row*WW + wp*2);
    float2 wv = *(const float2*)(Wf + (size_t)(row & (HH-1))*WW + wp*2);
    const float TP = 6.2831853071795864769f;
    float s0, c0, s1, c1;
    sincosf(xv.x*wv.x*TP, &s0, &c0);
    sincosf(xv.y*wv.y*TP, &s1, &c1);
    bf* rp = xe + (size_t)row*EE + wp*2;
    bf2 sv; sv.x = tob(s0); sv.y = tob(s1); *(bf2*)rp = sv;
    bf2 cv; cv.x = tob(c0); cv.y = tob(c1); *(bf2*)(rp + WW) = cv;
}

// ---------------------------------------------------------------------------
// K1b: fc1 GEMM via MFMA. 512 blocks.
__global__ __launch_bounds__(256) void k_gemm_fc1(
    const bf* __restrict__ xe, const float* __restrict__ fc1_w,
    const float* __restrict__ fc1_b, bf* __restrict__ xf)
{
    __shared__ ushortt sA[64*264];
    __shared__ ushortt sB[64*264];
    int tid = threadIdx.x;
    int rb = blockIdx.x >> 2, cb = blockIdx.x & 3;
    int row0 = rb*64, col0 = cb*64;
    #pragma unroll
    for (int it = 0; it < 8; ++it) {
        int i = it*256 + tid;
        int r = i >> 5, ch = i & 31;
        uint4 v = *(const uint4*)(xe + (size_t)(row0 + r)*EE + ch*8);
        *(uint4*)&sA[r*264 + ch*8] = v;
    }
    #pragma unroll
    for (int it = 0; it < 16; ++it) {
        int i = it*256 + tid;
        int o = i >> 6, c4 = i & 63;
        float4 w4 = *(const float4*)(fc1_w + (size_t)(col0 + o)*EE + c4*4);
        uint2 pk;
        pk.x = bfbits(w4.x) | (bfbits(w4.y) << 16);
        pk.y = bfbits(w4.z) | (bfbits(w4.w) << 16);
        *(uint2*)&sB[o*264 + c4*4] = pk;
    }
    __syncthreads();
    int lane = tid & 63, wid = tid >> 6;
    int m = lane & 15, kq = (lane >> 4) * 8;
    f4v acc[4] = {};
    const ushortt* aBase = &sA[(wid*16 + m)*264 + kq];
    #pragma unroll
    for (int k0 = 0; k0 < 8; ++k0) {
        b8v av = *(const b8v*)(aBase + k0*32);
        #pragma unroll
        for (int t4 = 0; t4 < 4; ++t4) {
            b8v bv = *(const b8v*)&sB[(t4*16 + m)*264 + k0*32 + kq];
            acc[t4] = __builtin_amdgcn_mfma_f32_16x16x32_bf16(av, bv, acc[t4], 0, 0, 0);
        }
    }
    int rbase = row0 + wid*16 + (lane >> 4)*4;
    #pragma unroll
    for (int t4 = 0; t4 < 4; ++t4) {
        int col = col0 + t4*16 + m;
        float bias = fc1_b[col];
        #pragma unroll
        for (int r = 0; r < 4; ++r)
            xf[(size_t)(rbase + r)*EE + col] = tob(acc[t4][r] + bias);
    }
}

// ---------------------------------------------------------------------------
// K2: conv1 3x3, 1->6, LDS-staged rows, 4 px/thread. 2048 blocks. Fused gn1 stats.
__global__ __launch_bounds__(256) void k_conv1(
    const bf* __restrict__ xf, const float* __restrict__ k,
    const float* __restrict__ bias, bf* __restrict__ c1, float* __restrict__ mc1)
{
    __shared__ ushortt sT[6*272];    // 6 rows, data at [8..263], zero halos
    __shared__ float red[4][6][2];
    int t = threadIdx.x;
    int ht = blockIdx.x & 31, b = blockIdx.x >> 5;
    int h0 = ht*4;
    const bf* src = xf + (size_t)b*HP;
    if (t < 192) {
        int r = t >> 5, i = t & 31;
        int gy = h0 - 1 + r;
        uint4 v = {0,0,0,0};
        if (gy >= 0 && gy < HH) v = *(const uint4*)(src + (size_t)gy*EE + i*8);
        *(uint4*)&sT[r*272 + 8 + i*8] = v;
    } else if (t < 204) {
        int e = t - 192;
        int r = e >> 1, s = e & 1;
        uint4 z = {0,0,0,0};
        *(uint4*)&sT[r*272 + s*264] = z;
    }
    __syncthreads();
    int wq = (t & 63)*4, hl = t >> 6;
    int lane = t & 63, wid = t >> 6;
    float v[3][6];
    #pragma unroll
    for (int ky = 0; ky < 3; ++ky)
      #pragma unroll
      for (int j = 0; j < 6; ++j)
        v[ky][j] = b2f((unsigned)sT[(hl+ky)*272 + 7 + wq + j]);
    int h = h0 + hl;
    #pragma unroll
    for (int o = 0; o < 6; ++o) {
        float bv = bias[o];
        float a0=bv, a1=bv, a2=bv, a3=bv;
        #pragma unroll
        for (int ky = 0; ky < 3; ++ky)
          #pragma unroll
          for (int kx = 0; kx < 3; ++kx) {
            float wv = k[o*9 + ky*3 + kx];
            a0 += v[ky][kx+0]*wv;
            a1 += v[ky][kx+1]*wv;
            a2 += v[ky][kx+2]*wv;
            a3 += v[ky][kx+3]*wv;
          }
        uint2 pk;
        pk.x = bfbits(a0) | (bfbits(a1) << 16);
        pk.y = bfbits(a2) | (bfbits(a3) << 16);
        *(uint2*)(c1 + ((size_t)(b*6+o)*HH + h)*EE + wq) = pk;
        float s = a0+a1+a2+a3, q = a0*a0+a1*a1+a2*a2+a3*a3;
        wred2(s, q);
        if (lane == 0) { red[wid][o][0] = s; red[wid][o][1] = q; }
    }
    __syncthreads();
    if (t < 6) {
        float S = 0.f, Q = 0.f;
        #pragma unroll
        for (int wv = 0; wv < 4; ++wv) { S += red[wv][t][0]; Q += red[wv][t][1]; }
        atomicAdd(&mc1[((size_t)b*6 + t)*2],     S);
        atomicAdd(&mc1[((size_t)b*6 + t)*2 + 1], Q);
    }
}

// ---------------------------------------------------------------------------
__global__ __launch_bounds__(256) void k_stats_final(
    const float* __restrict__ A, int ca, const float* __restrict__ Bs, int cb,
    const float* __restrict__ gamma, const float* __restrict__ beta,
    int cpg, float inv_n, int n, float* __restrict__ ss)
{
    int idx = blockIdx.x*256 + threadIdx.x;
    if (idx >= n) return;
    int C = ca + cb;
    int ng = C / cpg;
    int g = idx % ng;
    int b = idx / ng;
    float s = 0.f, q = 0.f;
    for (int cl = 0; cl < cpg; ++cl) {
        int gc = g*cpg + cl;
        const float* p = (gc < ca) ? A + ((size_t)b*ca + gc)*2
                                   : Bs + ((size_t)b*cb + (gc - ca))*2;
        s += p[0]; q += p[1];
    }
    float mean = s * inv_n;
    float var  = q * inv_n - mean*mean;
    float rstd = rsqrtf(var + 1e-5f);
    for (int cl = 0; cl < cpg; ++cl) {
        int gc = g*cpg + cl;
        float sc = gamma[gc] * rstd;
        ss[((size_t)b*C + gc)*2]   = sc;
        ss[((size_t)b*C + gc)*2+1] = beta[gc] - mean*sc;
    }
}

// ---------------------------------------------------------------------------
// GN apply + ReLU + 2x2 maxpool (+ optional SiLU). 2 out-px/thread, bf16 out.
__global__ __launch_bounds__(256) void k_gn_relu_pool(
    const bf* __restrict__ src, const float* __restrict__ ss,
    bf* __restrict__ dst, int C, int hi, int wi, int do_silu)
{
    int idx = blockIdx.x*256 + threadIdx.x;
    int wo2 = wi >> 2, ho = hi >> 1;
    int xp = idx % wo2; int tmp = idx / wo2;
    int yo = tmp % ho; tmp /= ho;
    int c = tmp % C; int b = tmp / C;
    const bf* p = src + ((size_t)(b*C + c)*hi + yo*2)*wi + xp*4;
    uint2 r0 = *(const uint2*)p;
    uint2 r1 = *(const uint2*)(p + wi);
    float sc = ss[(b*C+c)*2], sh = ss[(b*C+c)*2+1];
    float e0 = fmaxf(b2f(r0.x & 0xffff)*sc+sh, 0.f);
    float e1 = fmaxf(b2f(r0.x >> 16)   *sc+sh, 0.f);
    float e2 = fmaxf(b2f(r0.y & 0xffff)*sc+sh, 0.f);
    float e3 = fmaxf(b2f(r0.y >> 16)   *sc+sh, 0.f);
    float f0 = fmaxf(b2f(r1.x & 0xffff)*sc+sh, 0.f);
    float f1 = fmaxf(b2f(r1.x >> 16)   *sc+sh, 0.f);
    float f2 = fmaxf(b2f(r1.y & 0xffff)*sc+sh, 0.f);
    float f3 = fmaxf(b2f(r1.y >> 16)   *sc+sh, 0.f);
    float m0 = fmaxf(fmaxf(e0, e1), fmaxf(f0, f1));
    float m1 = fmaxf(fmaxf(e2, e3), fmaxf(f2, f3));
    if (do_silu) {
        m0 = m0 / (1.f + expf(-m0));
        m1 = m1 / (1.f + expf(-m1));
    }
    unsigned pk = bfbits(m0) | (bfbits(m1) << 16);
    *(unsigned*)(dst + (size_t)idx*2) = pk;
}

// ---------------------------------------------------------------------------
// K5: conv2 3x3, 6->24, bf16 in/out. Register activations, 4 px/thread.
// 512 blocks. Fused gn2 stats.
__global__ __launch_bounds__(256) void k_conv2(
    const bf* __restrict__ p1, const float* __restrict__ kw,
    const float* __restrict__ bias, bf* __restrict__ c2, float* __restrict__ mc2)
{
    __shared__ float tile[6][10][132];
    __shared__ float red[4][24][2];
    int t = threadIdx.x;
    int ht = blockIdx.x & 7, b = blockIdx.x >> 3;
    int h0 = ht*8;
    int lane = t & 63, wid = t >> 6;
    for (int i = t; i < 7920; i += 256) {
        int c = i / 1320, rem = i % 1320;
        int ty = rem / 132, tx = rem % 132;
        int hh = h0 + ty - 1, ww = tx - 1;
        float v = 0.f;
        if (hh >= 0 && hh < H2 && ww >= 0 && ww < W2)
            v = tof(p1[((size_t)(b*6+c))*PL2 + hh*W2 + ww]);
        tile[c][ty][tx] = v;
    }
    __syncthreads();
    int hl = t >> 5, wq = (t & 31)*4;
    float A[6][3][6];
    #pragma unroll
    for (int c = 0; c < 6; ++c)
      #pragma unroll
      for (int ky = 0; ky < 3; ++ky) {
        float4 v4 = *(const float4*)&tile[c][hl+ky][wq];
        float2 v2 = *(const float2*)&tile[c][hl+ky][wq+4];
        A[c][ky][0]=v4.x; A[c][ky][1]=v4.y; A[c][ky][2]=v4.z; A[c][ky][3]=v4.w;
        A[c][ky][4]=v2.x; A[c][ky][5]=v2.y;
      }
    int h = h0 + hl;
    #pragma unroll 1
    for (int o = 0; o < 24; ++o) {
        const float* ko = kw + o*54;
        float w[54];
        #pragma unroll
        for (int j = 0; j < 54; ++j) w[j] = ko[j];
        float bv = bias[o];
        float a0=bv, a1=bv, a2=bv, a3=bv;
        #pragma unroll
        for (int c = 0; c < 6; ++c)
          #pragma unroll
          for (int ky = 0; ky < 3; ++ky)
            #pragma unroll
            for (int kx = 0; kx < 3; ++kx) {
                float wv = w[c*9 + ky*3 + kx];
                a0 += A[c][ky][kx+0]*wv;
                a1 += A[c][ky][kx+1]*wv;
                a2 += A[c][ky][kx+2]*wv;
                a3 += A[c][ky][kx+3]*wv;
            }
        uint2 pk;
        pk.x = bfbits(a0) | (bfbits(a1) << 16);
        pk.y = bfbits(a2) | (bfbits(a3) << 16);
        *(uint2*)(c2 + ((size_t)(b*24+o)*H2 + h)*W2 + wq) = pk;
        float s = a0+a1+a2+a3, q = a0*a0+a1*a1+a2*a2+a3*a3;
        wred2(s, q);
        if (lane == 0) { red[wid][o][0] = s; red[wid][o][1] = q; }
    }
    __syncthreads();
    if (t < 24) {
        float S = 0.f, Q = 0.f;
        #pragma unroll
        for (int wv = 0; wv < 4; ++wv) { S += red[wv][t][0]; Q += red[wv][t][1]; }
        atomicAdd(&mc2[((size_t)b*24 + t)*2],     S);
        atomicAdd(&mc2[((size_t)b*24 + t)*2 + 1], Q);
    }
}

// ---------------------------------------------------------------------------
// K8: tconv3 2x2 s2, 24->24 via MFMA implicit GEMM.
// Block = 256 input px (4 rows of 64), M=256, K=24(pad32), N=96. 512 blocks.
__global__ __launch_bounds__(256) void k_tconv3(
    const bf* __restrict__ a, const float* __restrict__ k3,
    const float* __restrict__ b3, bf* __restrict__ u3, float* __restrict__ mu3)
{
    __shared__ ushortt sBuf[27648];       // A[256*40] + W[96*40] aliased by C[24*1152]
    __shared__ float redS[24], redQ[24];
    ushortt* sA = sBuf;
    ushortt* sW = sBuf + 10240;
    int t = threadIdx.x;
    int b = blockIdx.x >> 3, pg = blockIdx.x & 7;
    int lane = t & 63, wid = t >> 6;
    if (t < 24) { redS[t] = 0.f; redQ[t] = 0.f; }
    // stage W: k3[c][o][dq] -> sW[n=o*4+dq][kpad=c]
    #pragma unroll
    for (int j = 0; j < 9; ++j) {
        int e = j*256 + t;
        int c = e / 96, n = e % 96;
        sW[n*40 + c] = (ushortt)bfbits(k3[e]);
    }
    if (t < 96) { uint4 z = {0,0,0,0}; *(uint4*)&sW[t*40 + 24] = z; }
    // stage A: 24 channels of this pixel
    {
        int pix = pg*256 + t;
        const bf* ap = a + (size_t)b*24*PL4 + pix;
        #pragma unroll
        for (int g = 0; g < 3; ++g) {
            unsigned pr[4];
            #pragma unroll
            for (int hc = 0; hc < 4; ++hc) {
                int c0 = g*8 + hc*2;
                pr[hc] = (unsigned)__builtin_bit_cast(ushortt, ap[(size_t)c0*PL4])
                       | ((unsigned)__builtin_bit_cast(ushortt, ap[(size_t)(c0+1)*PL4]) << 16);
            }
            uint4 pk; pk.x = pr[0]; pk.y = pr[1]; pk.z = pr[2]; pk.w = pr[3];
            *(uint4*)&sA[t*40 + g*8] = pk;
        }
        uint4 z = {0,0,0,0};
        *(uint4*)&sA[t*40 + 24] = z;
    }
    __syncthreads();
    int m = lane & 15, kq = (lane >> 4)*8;
    b8v wv[6];
    #pragma unroll
    for (int nt = 0; nt < 6; ++nt)
        wv[nt] = *(const b8v*)&sW[(nt*16 + m)*40 + kq];
    f4v acc[4][6] = {};
    #pragma unroll
    for (int mt = 0; mt < 4; ++mt) {
        b8v av = *(const b8v*)&sA[(wid*64 + mt*16 + m)*40 + kq];
        #pragma unroll
        for (int nt = 0; nt < 6; ++nt)
            acc[mt][nt] = __builtin_amdgcn_mfma_f32_16x16x32_bf16(av, wv[nt], acc[mt][nt], 0, 0, 0);
    }
    __syncthreads();
    // C staging: sC[o][yl(8)][x(128)] with row stride 144, o stride 1152
    ushortt* sC = sBuf;
    int q4 = lane >> 4;
    #pragma unroll
    for (int mt = 0; mt < 4; ++mt) {
        int pxb = wid*64 + mt*16 + q4*4;
        #pragma unroll
        for (int nt = 0; nt < 6; ++nt) {
            int n = nt*16 + m;
            int o = n >> 2, d = (n >> 1) & 1, qq = n & 1;
            float bo = b3[o];
            #pragma unroll
            for (int r = 0; r < 4; ++r) {
                int px = pxb + r;
                int yl = ((px >> 6) << 1) + d;
                int xx = ((px & 63) << 1) + qq;
                sC[o*1152 + yl*144 + xx] = (ushortt)bfbits(acc[mt][nt][r] + bo);
            }
        }
    }
    __syncthreads();
    bf* outb = u3 + (size_t)b*24*PL2;
    #pragma unroll
    for (int j = 0; j < 12; ++j) {
        int idx = j*256 + t;              // 3072 vec4 chunks
        int o = idx >> 7;
        int rem = idx & 127;
        int yl = rem >> 4, xc = (rem & 15)*8;
        uint4 v = *(const uint4*)&sC[o*1152 + yl*144 + xc];
        *(uint4*)(outb + ((size_t)o*H2 + pg*8 + yl)*W2 + xc) = v;
        float v0 = b2f(v.x & 0xffff), v1 = b2f(v.x >> 16);
        float v2 = b2f(v.y & 0xffff), v3 = b2f(v.y >> 16);
        float v4 = b2f(v.z & 0xffff), v5 = b2f(v.z >> 16);
        float v6 = b2f(v.w & 0xffff), v7 = b2f(v.w >> 16);
        float s = v0+v1+v2+v3+v4+v5+v6+v7;
        float qv = v0*v0+v1*v1+v2*v2+v3*v3+v4*v4+v5*v5+v6*v6+v7*v7;
        wred2(s, qv);
        if (lane == 0) { atomicAdd(&redS[o], s); atomicAdd(&redQ[o], qv); }
    }
    __syncthreads();
    if (t < 24) {
        atomicAdd(&mu3[((size_t)b*24 + t)*2],     redS[t]);
        atomicAdd(&mu3[((size_t)b*24 + t)*2 + 1], redQ[t]);
    }
}

// ---------------------------------------------------------------------------
// K10: gn3-fused tconv4 2x2 s2, 48->12 via MFMA implicit GEMM. 2048 blocks.
__global__ __launch_bounds__(256) void k_tconv4(
    const bf* __restrict__ c2, const bf* __restrict__ u3,
    const float* __restrict__ ss3, const float* __restrict__ k4,
    const float* __restrict__ bias4, bf* __restrict__ u4, float* __restrict__ mu4)
{
    __shared__ ushortt sA[256*72];
    __shared__ ushortt sW[48*72];
    __shared__ float redS[12], redQ[12];
    int t = threadIdx.x;
    int b = blockIdx.x >> 5, pg = blockIdx.x & 31;
    int lane = t & 63, wid = t >> 6;
    if (t < 12) { redS[t] = 0.f; redQ[t] = 0.f; }
    #pragma unroll
    for (int j = 0; j < 9; ++j) {
        int e = j*256 + t;
        if (e < 2304) {
            int c = e / 48, n = e % 48;
            sW[n*72 + c] = (ushortt)bfbits(k4[e]);
        }
    }
    if (t < 96) {
        uint4 z = {0,0,0,0};
        int n = t >> 1, c0 = 48 + (t & 1)*8;
        *(uint4*)&sW[n*72 + c0] = z;
    }
    {
        int pix = pg*256 + t;
        const bf* c2p = c2 + (size_t)b*24*PL2 + pix;
        const bf* u3p = u3 + (size_t)b*24*PL2 + pix;
        const float* ssp = ss3 + (size_t)b*96;
        ushortt* row = &sA[t*72];
        #pragma unroll
        for (int g = 0; g < 6; ++g) {
            unsigned pr[4];
            #pragma unroll
            for (int hc = 0; hc < 4; ++hc) {
                int c0 = g*8 + hc*2;
                float r0 = (c0 < 24) ? tof(c2p[(size_t)c0*PL2]) : tof(u3p[(size_t)(c0-24)*PL2]);
                float r1 = (c0+1 < 24) ? tof(c2p[(size_t)(c0+1)*PL2]) : tof(u3p[(size_t)(c0+1-24)*PL2]);
                float v0 = r0 * ssp[2*c0]   + ssp[2*c0+1];
                float v1 = r1 * ssp[2*c0+2] + ssp[2*c0+3];
                pr[hc] = bfbits(v0) | (bfbits(v1) << 16);
            }
            uint4 pk; pk.x = pr[0]; pk.y = pr[1]; pk.z = pr[2]; pk.w = pr[3];
            *(uint4*)&row[g*8] = pk;
        }
        uint4 z = {0,0,0,0};
        *(uint4*)&row[48] = z;
        *(uint4*)&row[56] = z;
    }
    __syncthreads();
    int m = lane & 15, kq = (lane >> 4)*8;
    b8v bfr[3][2];
    #pragma unroll
    for (int nt = 0; nt < 3; ++nt)
      #pragma unroll
      for (int ks = 0; ks < 2; ++ks)
        bfr[nt][ks] = *(const b8v*)&sW[(nt*16 + m)*72 + ks*32 + kq];
    f4v acc[4][3] = {};
    #pragma unroll
    for (int mt = 0; mt < 4; ++mt) {
        const ushortt* ab = &sA[(wid*64 + mt*16 + m)*72 + kq];
        b8v a0 = *(const b8v*)(ab);
        b8v a1 = *(const b8v*)(ab + 32);
        #pragma unroll
        for (int nt = 0; nt < 3; ++nt) {
            acc[mt][nt] = __builtin_amdgcn_mfma_f32_16x16x32_bf16(a0, bfr[nt][0], acc[mt][nt], 0, 0, 0);
            acc[mt][nt] = __builtin_amdgcn_mfma_f32_16x16x32_bf16(a1, bfr[nt][1], acc[mt][nt], 0, 0, 0);
        }
    }
    __syncthreads();
    ushortt* sC = sA;
    int q4 = lane >> 4;
    #pragma unroll
    for (int mt = 0; mt < 4; ++mt) {
        int pxb = wid*64 + mt*16 + q4*4;
        #pragma unroll
        for (int nt = 0; nt < 3; ++nt) {
            int n = nt*16 + m;
            int o = n >> 2, d = (n >> 1) & 1, qq = n & 1;
            float bo = bias4[o];
            #pragma unroll
            for (int r = 0; r < 4; ++r) {
                int px = pxb + r;
                int yl = ((px >> 7) << 1) + d;
                int xx = ((px & 127) << 1) + qq;
                sC[o*1024 + yl*256 + xx] = (ushortt)bfbits(acc[mt][nt][r] + bo);
            }
        }
    }
    __syncthreads();
    {
        bf* outb = u4 + (size_t)b*12*HP;
        #pragma unroll
        for (int j = 0; j < 6; ++j) {
            int idx16 = j*256 + t;
            int el = idx16*8;
            int o = el >> 10, rem = el & 1023, yl = rem >> 8, x0 = rem & 255;
            uint4 v = *(const uint4*)&sC[el];
            *(uint4*)(outb + ((size_t)o*HH + pg*4 + yl)*EE + x0) = v;
            float v0 = b2f(v.x & 0xffff), v1 = b2f(v.x >> 16);
            float v2 = b2f(v.y & 0xffff), v3 = b2f(v.y >> 16);
            float v4 = b2f(v.z & 0xffff), v5 = b2f(v.z >> 16);
            float v6 = b2f(v.w & 0xffff), v7 = b2f(v.w >> 16);
            float s = v0+v1+v2+v3+v4+v5+v6+v7;
            float qv = v0*v0+v1*v1+v2*v2+v3*v3+v4*v4+v5*v5+v6*v6+v7*v7;
            wred2(s, qv);
            if (lane == 0) { atomicAdd(&redS[o], s); atomicAdd(&redQ[o], qv); }
        }
    }
    __syncthreads();
    if (t < 12) {
        atomicAdd(&mu4[((size_t)b*12 + t)*2],     redS[t]);
        atomicAdd(&mu4[((size_t)b*12 + t)*2 + 1], redQ[t]);
    }
}

// ---------------------------------------------------------------------------
// K12: gn4-fused 1x1 conv 18->6. 4 px/thread. Fused u5 stats. 2048 blocks.
__global__ __launch_bounds__(256) void k_conv1x1_u5(
    const bf* __restrict__ c1, const bf* __restrict__ u4,
    const float* __restrict__ ss4, const float* __restrict__ k,
    const float* __restrict__ bias, bf* __restrict__ u5, float* __restrict__ mu5)
{
    __shared__ float red[4][6][2];
    int t = threadIdx.x;
    int b  = blockIdx.x >> 5;
    int pg = blockIdx.x & 31;
    int pix = pg*1024 + t*4;
    int lane = t & 63, wid = t >> 6;
    const bf* c1p = c1 + ((size_t)b*6)*HP + pix;
    const bf* u4p = u4 + ((size_t)b*12)*HP + pix;
    const float* ssp = ss4 + (size_t)b*36;
    float acc[6][4];
    #pragma unroll
    for (int o = 0; o < 6; ++o) {
        float bv = bias[o];
        #pragma unroll
        for (int j = 0; j < 4; ++j) acc[o][j] = bv;
    }
    #pragma unroll
    for (int c = 0; c < 18; ++c) {
        uint2 r = (c < 6) ? *(const uint2*)(c1p + (size_t)c*HP)
                          : *(const uint2*)(u4p + (size_t)(c-6)*HP);
        float sc = ssp[2*c], sh = ssp[2*c+1];
        float v0 = b2f(r.x & 0xffff)*sc + sh;
        float v1 = b2f(r.x >> 16)   *sc + sh;
        float v2 = b2f(r.y & 0xffff)*sc + sh;
        float v3 = b2f(r.y >> 16)   *sc + sh;
        #pragma unroll
        for (int o = 0; o < 6; ++o) {
            float wv = k[o*18 + c];
            acc[o][0] += v0*wv; acc[o][1] += v1*wv;
            acc[o][2] += v2*wv; acc[o][3] += v3*wv;
        }
    }
    #pragma unroll
    for (int o = 0; o < 6; ++o) {
        uint2 pk;
        pk.x = bfbits(acc[o][0]) | (bfbits(acc[o][1]) << 16);
        pk.y = bfbits(acc[o][2]) | (bfbits(acc[o][3]) << 16);
        *(uint2*)(u5 + ((size_t)(b*6+o))*HP + pix) = pk;
        float s = acc[o][0]+acc[o][1]+acc[o][2]+acc[o][3];
        float q = acc[o][0]*acc[o][0]+acc[o][1]*acc[o][1]
                + acc[o][2]*acc[o][2]+acc[o][3]*acc[o][3];
        wred2(s, q);
        if (lane == 0) { red[wid][o][0] = s; red[wid][o][1] = q; }
    }
    __syncthreads();
    if (t < 6) {
        float S = 0.f, Q = 0.f;
        #pragma unroll
        for (int wv = 0; wv < 4; ++wv) { S += red[wv][t][0]; Q += red[wv][t][1]; }
        atomicAdd(&mu5[((size_t)b*6 + t)*2],     S);
        atomicAdd(&mu5[((size_t)b*6 + t)*2 + 1], Q);
    }
}

// ---------------------------------------------------------------------------
// K14: gn5-fused final 1x1 conv (6->1) + divide by std(t). 4 px/thread.
__global__ __launch_bounds__(256) void k_final(
    const bf* __restrict__ u5, const float* __restrict__ ss5,
    const float* __restrict__ k, const float* __restrict__ bias,
    const float* __restrict__ t, float* __restrict__ out)
{
    int idx = blockIdx.x*256 + threadIdx.x;
    int b = idx >> 13;
    int pix = (idx & 8191)*4;
    const bf* up = u5 + (size_t)b*6*HP + pix;
    const float* ssp = ss5 + (size_t)b*12;
    float a0 = bias[0], a1 = a0, a2 = a0, a3 = a0;
    #pragma unroll
    for (int c = 0; c < 6; ++c) {
        uint2 r = *(const uint2*)(up + (size_t)c*HP);
        float sc = ssp[2*c], sh = ssp[2*c+1];
        float wv = k[c];
        a0 += (b2f(r.x & 0xffff)*sc + sh) * wv;
        a1 += (b2f(r.x >> 16)   *sc + sh) * wv;
        a2 += (b2f(r.y & 0xffff)*sc + sh) * wv;
        a3 += (b2f(r.y >> 16)   *sc + sh) * wv;
    }
    float tb = t[b];
    const float lns = 3.2188758248682007492f;
    float var = (expf(2.f*tb*lns) - 1.f) / (2.f*lns);
    float rs = rsqrtf(var);
    float4 ov; ov.x = a0*rs; ov.y = a1*rs; ov.z = a2*rs; ov.w = a3*rs;
    *(float4*)(out + (size_t)b*HP + pix) = ov;
}

// ---------------------------------------------------------------------------
extern "C" void kernel_launch(void* const* d_in, const int* in_sizes, int n_in,
                              void* d_out, int out_size, void* d_ws, size_t ws_size,
                              hipStream_t stream)
{
    const float* x       = (const float*)d_in[0];
    const float* t       = (const float*)d_in[1];
    const float* Wf      = (const float*)d_in[2];
    const float* fc1_w   = (const float*)d_in[3];
    const float* fc1_b   = (const float*)d_in[4];
    const float* conv1_k = (const float*)d_in[5];
    const float* conv1_b = (const float*)d_in[6];
    const float* gn1_g   = (const float*)d_in[7];
    const float* gn1_b   = (const float*)d_in[8];
    const float* conv2_k = (const float*)d_in[9];
    const float* conv2_b = (const float*)d_in[10];
    const float* gn2_g   = (const float*)d_in[11];
    const float* gn2_b   = (const float*)d_in[12];
    const float* t3_k    = (const float*)d_in[13];
    const float* t3_b    = (const float*)d_in[14];
    const float* gn3_g   = (const float*)d_in[15];
    const float* gn3_b   = (const float*)d_in[16];
    const float* t4_k    = (const float*)d_in[17];
    const float* t4_b    = (const float*)d_in[18];
    const float* gn4_g   = (const float*)d_in[19];
    const float* gn4_b   = (const float*)d_in[20];
    const float* t5_k    = (const float*)d_in[21];
    const float* t5_b    = (const float*)d_in[22];
    const float* gn5_g   = (const float*)d_in[23];
    const float* gn5_b   = (const float*)d_in[24];
    const float* fin_k   = (const float*)d_in[25];
    const float* fin_b   = (const float*)d_in[26];

    bf* wsb = (bf*)d_ws;
    bf* c1 = wsb;                          // conv1..conv1x1
    bf* c2 = wsb + 12582912;               // conv2..tconv4
    bf* u3 = wsb + 25165824;               // tconv3..tconv4
    bf* u4 = wsb + 37748736;               // tconv4..conv1x1
    bf* xe = wsb + 37748736;               // fourier..gemm (u4 region)
    bf* xf = wsb + 39845888;               // gemm..conv1
    bf* p1 = wsb + 41943040;               // pool1..conv2 (bf16 now)
    bf* a_ = wsb + 48234496;               // pool2..tconv3 (bf16 now)
    bf* u5 = wsb + 12582912;               // reuses c2, conv1x1..final
    float* st = (float*)(wsb + 62914560);
    float* s1 = st;             // 768
    float* s2 = st + 768;       // 3072
    float* s3 = st + 3840;      // 6144
    float* s4 = st + 9984;      // 2304
    float* s5 = st + 12288;     // 768
    float* mb = st + 13056;     // raw channel sums
    float* mc1 = mb;            // 768
    float* mc2 = mb + 768;      // 3072
    float* mu3 = mb + 3840;     // 3072
    float* mu4 = mb + 6912;     // 1536
    float* mu5 = mb + 8448;     // 768

    k_zero<<<9, 256, 0, stream>>>(mb, 9216);
    k_fourier<<<2048, 256, 0, stream>>>(x, Wf, xe);
    k_gemm_fc1<<<512, 256, 0, stream>>>(xe, fc1_w, fc1_b, xf);
    k_conv1<<<2048, 256, 0, stream>>>(xf, conv1_k, conv1_b, c1, mc1);
    k_stats_final<<<2, 256, 0, stream>>>(mc1, 6, (const float*)nullptr, 0,
                                         gn1_g, gn1_b, 1, 1.f/HP, 384, s1);
    k_gn_relu_pool<<<6144, 256, 0, stream>>>(c1, s1, p1, 6, HH, EE, 0);
    k_conv2<<<512, 256, 0, stream>>>(p1, conv2_k, conv2_b, c2, mc2);
    k_stats_final<<<6, 256, 0, stream>>>(mc2, 24, (const float*)nullptr, 0,
                                         gn2_g, gn2_b, 1, 1.f/PL2, 1536, s2);
    k_gn_relu_pool<<<6144, 256, 0, stream>>>(c2, s2, a_, 24, H2, W2, 1);
    k_tconv3<<<512, 256, 0, stream>>>(a_, t3_k, t3_b, u3, mu3);
    k_stats_final<<<2, 256, 0, stream>>>(mc2, 24, mu3, 24,
                                         gn3_g, gn3_b, 8, 1.f/(PL2*8), 384, s3);
    k_tconv4<<<2048, 256, 0, stream>>>(c2, u3, s3, t4_k, t4_b, u4, mu4);
    k_stats_final<<<2, 256, 0, stream>>>(mc1, 6, mu4, 12,
                                         gn4_g, gn4_b, 3, 1.f/(HP*3), 384, s4);
    k_conv1x1_u5<<<2048, 256, 0, stream>>>(c1, u4, s4, t5_k, t5_b, u5, mu5);
    k_stats_final<<<2, 256, 0, stream>>>(mu5, 6, (const float*)nullptr, 0,
                                         gn5_g, gn5_b, 1, 1.f/HP, 384, s5);
    k_final<<<2048, 256, 0, stream>>>(u5, s5, fin_k, fin_b, t, (float*)d_out);
}

// Round 7
// 279.022 us; speedup vs baseline: 4.4769x; 1.0297x over previous
//
#include <hip/hip_runtime.h>
#include <hip/hip_bf16.h>
#include <math.h>

#define BB 64
#define HH 128
#define WW 128
#define EE 256
#define HP (HH*EE)        // 32768
#define H2 64
#define W2 128
#define PL2 (H2*W2)       // 8192
#define H4 32
#define W4 64
#define PL4 (H4*W4)       // 2048

typedef __hip_bfloat16 bf;
typedef __hip_bfloat162 bf2;
typedef unsigned short ushortt;
typedef __attribute__((ext_vector_type(8))) __bf16 b8v;
typedef __attribute__((ext_vector_type(4))) float f4v;

__device__ __forceinline__ float tof(float v) { return v; }
__device__ __forceinline__ float tof(bf v)    { return __bfloat162float(v); }
__device__ __forceinline__ bf    tob(float v) { return __float2bfloat16(v); }
__device__ __forceinline__ unsigned int bfbits(float v) {
    return (unsigned int)__builtin_bit_cast(ushortt, __float2bfloat16(v));
}
__device__ __forceinline__ float b2f(unsigned int u16) {
    unsigned int x = u16 << 16;
    return __builtin_bit_cast(float, x);
}
__device__ __forceinline__ void wred2(float& s, float& q) {
    #pragma unroll
    for (int m = 32; m; m >>= 1) {
        s += __shfl_xor(s, m);
        q += __shfl_xor(q, m);
    }
}

// ---------------------------------------------------------------------------
__global__ __launch_bounds__(256) void k_zero(float* __restrict__ p, int n)
{
    for (int i = blockIdx.x*256 + threadIdx.x; i < n; i += gridDim.x*256) p[i] = 0.f;
}

// ---------------------------------------------------------------------------
// K1: fused Fourier features + fc1 GEMM via MFMA. 512 blocks.
// Each block computes its 64-row sincos A-tile in-LDS (no xe round-trip).
__global__ __launch_bounds__(256) void k_fourier_fc1(
    const float* __restrict__ x, const float* __restrict__ Wf,
    const float* __restrict__ fc1_w, const float* __restrict__ fc1_b,
    bf* __restrict__ xf)
{
    __shared__ ushortt sA[64*264];
    __shared__ ushortt sB[64*264];
    int t = threadIdx.x;
    int rb = blockIdx.x >> 2, cb = blockIdx.x & 3;
    int row0 = rb*64, col0 = cb*64;
    const float TP = 6.2831853071795864769f;
    for (int it = 0; it < 32; ++it) {       // 8192 = 64 rows x 128 w
        int i = it*256 + t;
        int r = i >> 7, w = i & 127;
        int rg = row0 + r;
        float p = x[(size_t)rg*WW + w] * Wf[(size_t)(rg & (HH-1))*WW + w] * TP;
        float s, c;
        sincosf(p, &s, &c);
        sA[r*264 + w]       = (ushortt)bfbits(s);
        sA[r*264 + 128 + w] = (ushortt)bfbits(c);
    }
    #pragma unroll
    for (int it = 0; it < 16; ++it) {       // B: fp32 -> bf16
        int i = it*256 + t;
        int o = i >> 6, c4 = i & 63;
        float4 w4 = *(const float4*)(fc1_w + (size_t)(col0 + o)*EE + c4*4);
        uint2 pk;
        pk.x = bfbits(w4.x) | (bfbits(w4.y) << 16);
        pk.y = bfbits(w4.z) | (bfbits(w4.w) << 16);
        *(uint2*)&sB[o*264 + c4*4] = pk;
    }
    __syncthreads();
    int lane = t & 63, wid = t >> 6;
    int m = lane & 15, kq = (lane >> 4) * 8;
    f4v acc[4] = {};
    const ushortt* aBase = &sA[(wid*16 + m)*264 + kq];
    #pragma unroll
    for (int k0 = 0; k0 < 8; ++k0) {
        b8v av = *(const b8v*)(aBase + k0*32);
        #pragma unroll
        for (int t4 = 0; t4 < 4; ++t4) {
            b8v bv = *(const b8v*)&sB[(t4*16 + m)*264 + k0*32 + kq];
            acc[t4] = __builtin_amdgcn_mfma_f32_16x16x32_bf16(av, bv, acc[t4], 0, 0, 0);
        }
    }
    int rbase = row0 + wid*16 + (lane >> 4)*4;
    #pragma unroll
    for (int t4 = 0; t4 < 4; ++t4) {
        int col = col0 + t4*16 + m;
        float bias = fc1_b[col];
        #pragma unroll
        for (int r = 0; r < 4; ++r)
            xf[(size_t)(rbase + r)*EE + col] = tob(acc[t4][r] + bias);
    }
}

// ---------------------------------------------------------------------------
// K2: conv1 3x3, 1->6, LDS-staged rows, 4 px/thread. 2048 blocks. Fused gn1 stats.
__global__ __launch_bounds__(256) void k_conv1(
    const bf* __restrict__ xf, const float* __restrict__ k,
    const float* __restrict__ bias, bf* __restrict__ c1, float* __restrict__ mc1)
{
    __shared__ ushortt sT[6*272];    // 6 rows, data at [8..263], zero halos
    __shared__ float red[4][6][2];
    int t = threadIdx.x;
    int ht = blockIdx.x & 31, b = blockIdx.x >> 5;
    int h0 = ht*4;
    const bf* src = xf + (size_t)b*HP;
    if (t < 192) {
        int r = t >> 5, i = t & 31;
        int gy = h0 - 1 + r;
        uint4 v = {0,0,0,0};
        if (gy >= 0 && gy < HH) v = *(const uint4*)(src + (size_t)gy*EE + i*8);
        *(uint4*)&sT[r*272 + 8 + i*8] = v;
    } else if (t < 204) {
        int e = t - 192;
        int r = e >> 1, s = e & 1;
        uint4 z = {0,0,0,0};
        *(uint4*)&sT[r*272 + s*264] = z;
    }
    __syncthreads();
    int wq = (t & 63)*4, hl = t >> 6;
    int lane = t & 63, wid = t >> 6;
    float v[3][6];
    #pragma unroll
    for (int ky = 0; ky < 3; ++ky)
      #pragma unroll
      for (int j = 0; j < 6; ++j)
        v[ky][j] = b2f((unsigned)sT[(hl+ky)*272 + 7 + wq + j]);
    int h = h0 + hl;
    #pragma unroll
    for (int o = 0; o < 6; ++o) {
        float bv = bias[o];
        float a0=bv, a1=bv, a2=bv, a3=bv;
        #pragma unroll
        for (int ky = 0; ky < 3; ++ky)
          #pragma unroll
          for (int kx = 0; kx < 3; ++kx) {
            float wv = k[o*9 + ky*3 + kx];
            a0 += v[ky][kx+0]*wv;
            a1 += v[ky][kx+1]*wv;
            a2 += v[ky][kx+2]*wv;
            a3 += v[ky][kx+3]*wv;
          }
        uint2 pk;
        pk.x = bfbits(a0) | (bfbits(a1) << 16);
        pk.y = bfbits(a2) | (bfbits(a3) << 16);
        *(uint2*)(c1 + ((size_t)(b*6+o)*HH + h)*EE + wq) = pk;
        float s = a0+a1+a2+a3, q = a0*a0+a1*a1+a2*a2+a3*a3;
        wred2(s, q);
        if (lane == 0) { red[wid][o][0] = s; red[wid][o][1] = q; }
    }
    __syncthreads();
    if (t < 6) {
        float S = 0.f, Q = 0.f;
        #pragma unroll
        for (int wv = 0; wv < 4; ++wv) { S += red[wv][t][0]; Q += red[wv][t][1]; }
        atomicAdd(&mc1[((size_t)b*6 + t)*2],     S);
        atomicAdd(&mc1[((size_t)b*6 + t)*2 + 1], Q);
    }
}

// ---------------------------------------------------------------------------
// K5: conv2 3x3, 6->24 with fused gn1+ReLU+pool staging from c1 (no p1 buffer).
// s1 computed in prologue from mc1. 512 blocks. Fused gn2 stats -> mc2.
__global__ __launch_bounds__(256) void k_conv2(
    const bf* __restrict__ c1, const float* __restrict__ mc1,
    const float* __restrict__ g1, const float* __restrict__ be1,
    const float* __restrict__ kw, const float* __restrict__ bias,
    bf* __restrict__ c2, float* __restrict__ mc2)
{
    __shared__ float tile[6][10][132];
    __shared__ float red[4][24][2];
    __shared__ float ssl[12];
    int t = threadIdx.x;
    int ht = blockIdx.x & 7, b = blockIdx.x >> 3;
    int h0 = ht*8;
    int lane = t & 63, wid = t >> 6;
    if (t < 6) {
        float s = mc1[((size_t)b*6 + t)*2], q = mc1[((size_t)b*6 + t)*2 + 1];
        float mean = s * (1.f/HP);
        float var  = q * (1.f/HP) - mean*mean;
        float rstd = rsqrtf(var + 1e-5f);
        float sc = g1[t]*rstd;
        ssl[t*2] = sc; ssl[t*2+1] = be1[t] - mean*sc;
    }
    __syncthreads();
    for (int i = t; i < 7920; i += 256) {
        int c = i / 1320, rem = i % 1320;
        int ty = rem / 132, tx = rem % 132;
        int gy = h0 + ty - 1, gx = tx - 1;   // pooled coords
        float v = 0.f;
        if (gy >= 0 && gy < H2 && gx >= 0 && gx < W2) {
            const bf* pp = c1 + ((size_t)(b*6+c)*HH + 2*gy)*EE + 2*gx;
            unsigned r0 = *(const unsigned*)pp;
            unsigned r1 = *(const unsigned*)(pp + EE);
            float sc = ssl[c*2], sh = ssl[c*2+1];
            float e0 = fmaxf(b2f(r0 & 0xffff)*sc+sh, 0.f);
            float e1 = fmaxf(b2f(r0 >> 16)   *sc+sh, 0.f);
            float e2 = fmaxf(b2f(r1 & 0xffff)*sc+sh, 0.f);
            float e3 = fmaxf(b2f(r1 >> 16)   *sc+sh, 0.f);
            v = fmaxf(fmaxf(e0,e1), fmaxf(e2,e3));
        }
        tile[c][ty][tx] = v;
    }
    __syncthreads();
    int hl = t >> 5, wq = (t & 31)*4;
    float A[6][3][6];
    #pragma unroll
    for (int c = 0; c < 6; ++c)
      #pragma unroll
      for (int ky = 0; ky < 3; ++ky) {
        float4 v4 = *(const float4*)&tile[c][hl+ky][wq];
        float2 v2 = *(const float2*)&tile[c][hl+ky][wq+4];
        A[c][ky][0]=v4.x; A[c][ky][1]=v4.y; A[c][ky][2]=v4.z; A[c][ky][3]=v4.w;
        A[c][ky][4]=v2.x; A[c][ky][5]=v2.y;
      }
    int h = h0 + hl;
    #pragma unroll 1
    for (int o = 0; o < 24; ++o) {
        const float* ko = kw + o*54;
        float w[54];
        #pragma unroll
        for (int j = 0; j < 54; ++j) w[j] = ko[j];
        float bv = bias[o];
        float a0=bv, a1=bv, a2=bv, a3=bv;
        #pragma unroll
        for (int c = 0; c < 6; ++c)
          #pragma unroll
          for (int ky = 0; ky < 3; ++ky)
            #pragma unroll
            for (int kx = 0; kx < 3; ++kx) {
                float wv = w[c*9 + ky*3 + kx];
                a0 += A[c][ky][kx+0]*wv;
                a1 += A[c][ky][kx+1]*wv;
                a2 += A[c][ky][kx+2]*wv;
                a3 += A[c][ky][kx+3]*wv;
            }
        uint2 pk;
        pk.x = bfbits(a0) | (bfbits(a1) << 16);
        pk.y = bfbits(a2) | (bfbits(a3) << 16);
        *(uint2*)(c2 + ((size_t)(b*24+o)*H2 + h)*W2 + wq) = pk;
        float s = a0+a1+a2+a3, q = a0*a0+a1*a1+a2*a2+a3*a3;
        wred2(s, q);
        if (lane == 0) { red[wid][o][0] = s; red[wid][o][1] = q; }
    }
    __syncthreads();
    if (t < 24) {
        float S = 0.f, Q = 0.f;
        #pragma unroll
        for (int wv = 0; wv < 4; ++wv) { S += red[wv][t][0]; Q += red[wv][t][1]; }
        atomicAdd(&mc2[((size_t)b*24 + t)*2],     S);
        atomicAdd(&mc2[((size_t)b*24 + t)*2 + 1], Q);
    }
}

// ---------------------------------------------------------------------------
// K8: tconv3 2x2 s2, 24->24 via MFMA, with fused gn2+ReLU+pool+SiLU staging
// from c2 (no a_ buffer). s2 computed in prologue from mc2. 512 blocks.
__global__ __launch_bounds__(256) void k_tconv3(
    const bf* __restrict__ c2, const float* __restrict__ mc2,
    const float* __restrict__ g2, const float* __restrict__ be2,
    const float* __restrict__ k3, const float* __restrict__ b3,
    bf* __restrict__ u3, float* __restrict__ mu3)
{
    __shared__ ushortt sBuf[27648];       // A[256*40] + W[96*40] aliased by C[24*1152]
    __shared__ float redS[24], redQ[24];
    __shared__ float ssl[48];
    ushortt* sA = sBuf;
    ushortt* sW = sBuf + 10240;
    int t = threadIdx.x;
    int b = blockIdx.x >> 3, pg = blockIdx.x & 7;
    int lane = t & 63, wid = t >> 6;
    if (t < 24) {
        redS[t] = 0.f; redQ[t] = 0.f;
        float s = mc2[((size_t)b*24 + t)*2], q = mc2[((size_t)b*24 + t)*2 + 1];
        float mean = s * (1.f/PL2);
        float var  = q * (1.f/PL2) - mean*mean;
        float rstd = rsqrtf(var + 1e-5f);
        float sc = g2[t]*rstd;
        ssl[t*2] = sc; ssl[t*2+1] = be2[t] - mean*sc;
    }
    // stage W: k3[c][o][dq] -> sW[n=o*4+dq][kpad=c]
    #pragma unroll
    for (int j = 0; j < 9; ++j) {
        int e = j*256 + t;
        int c = e / 96, n = e % 96;
        sW[n*40 + c] = (ushortt)bfbits(k3[e]);
    }
    if (t < 96) { uint4 z = {0,0,0,0}; *(uint4*)&sW[t*40 + 24] = z; }
    __syncthreads();
    // stage A: pooled+SiLU activations of this block's 256 a-pixels
    {
        int pix = pg*256 + t;             // [0, 2048)
        int h4 = pix >> 6, w4 = pix & 63;
        const bf* base = c2 + (size_t)b*24*PL2 + (size_t)(2*h4)*W2 + 2*w4;
        #pragma unroll
        for (int g = 0; g < 3; ++g) {
            unsigned pr[4];
            #pragma unroll
            for (int hc = 0; hc < 4; ++hc) {
                unsigned two[2];
                #pragma unroll
                for (int cc = 0; cc < 2; ++cc) {
                    int c = g*8 + hc*2 + cc;
                    const bf* pp = base + (size_t)c*PL2;
                    unsigned r0 = *(const unsigned*)pp;
                    unsigned r1 = *(const unsigned*)(pp + W2);
                    float sc = ssl[c*2], sh = ssl[c*2+1];
                    float e0 = fmaxf(b2f(r0 & 0xffff)*sc+sh, 0.f);
                    float e1 = fmaxf(b2f(r0 >> 16)   *sc+sh, 0.f);
                    float e2 = fmaxf(b2f(r1 & 0xffff)*sc+sh, 0.f);
                    float e3 = fmaxf(b2f(r1 >> 16)   *sc+sh, 0.f);
                    float mm = fmaxf(fmaxf(e0,e1), fmaxf(e2,e3));
                    mm = mm / (1.f + expf(-mm));
                    two[cc] = bfbits(mm);
                }
                pr[hc] = two[0] | (two[1] << 16);
            }
            uint4 pk; pk.x = pr[0]; pk.y = pr[1]; pk.z = pr[2]; pk.w = pr[3];
            *(uint4*)&sA[t*40 + g*8] = pk;
        }
        uint4 z = {0,0,0,0};
        *(uint4*)&sA[t*40 + 24] = z;
    }
    __syncthreads();
    int m = lane & 15, kq = (lane >> 4)*8;
    b8v wv[6];
    #pragma unroll
    for (int nt = 0; nt < 6; ++nt)
        wv[nt] = *(const b8v*)&sW[(nt*16 + m)*40 + kq];
    f4v acc[4][6] = {};
    #pragma unroll
    for (int mt = 0; mt < 4; ++mt) {
        b8v av = *(const b8v*)&sA[(wid*64 + mt*16 + m)*40 + kq];
        #pragma unroll
        for (int nt = 0; nt < 6; ++nt)
            acc[mt][nt] = __builtin_amdgcn_mfma_f32_16x16x32_bf16(av, wv[nt], acc[mt][nt], 0, 0, 0);
    }
    __syncthreads();
    // C staging: sC[o][yl(8)][x(128)] row stride 144, o stride 1152
    ushortt* sC = sBuf;
    int q4 = lane >> 4;
    #pragma unroll
    for (int mt = 0; mt < 4; ++mt) {
        int pxb = wid*64 + mt*16 + q4*4;
        #pragma unroll
        for (int nt = 0; nt < 6; ++nt) {
            int n = nt*16 + m;
            int o = n >> 2, d = (n >> 1) & 1, qq = n & 1;
            float bo = b3[o];
            #pragma unroll
            for (int r = 0; r < 4; ++r) {
                int px = pxb + r;
                int yl = ((px >> 6) << 1) + d;
                int xx = ((px & 63) << 1) + qq;
                sC[o*1152 + yl*144 + xx] = (ushortt)bfbits(acc[mt][nt][r] + bo);
            }
        }
    }
    __syncthreads();
    bf* outb = u3 + (size_t)b*24*PL2;
    #pragma unroll
    for (int j = 0; j < 12; ++j) {
        int idx = j*256 + t;
        int o = idx >> 7;
        int rem = idx & 127;
        int yl = rem >> 4, xc = (rem & 15)*8;
        uint4 v = *(const uint4*)&sC[o*1152 + yl*144 + xc];
        *(uint4*)(outb + ((size_t)o*H2 + pg*8 + yl)*W2 + xc) = v;
        float v0 = b2f(v.x & 0xffff), v1 = b2f(v.x >> 16);
        float v2 = b2f(v.y & 0xffff), v3 = b2f(v.y >> 16);
        float v4 = b2f(v.z & 0xffff), v5 = b2f(v.z >> 16);
        float v6 = b2f(v.w & 0xffff), v7 = b2f(v.w >> 16);
        float s = v0+v1+v2+v3+v4+v5+v6+v7;
        float qv = v0*v0+v1*v1+v2*v2+v3*v3+v4*v4+v5*v5+v6*v6+v7*v7;
        wred2(s, qv);
        if (lane == 0) { atomicAdd(&redS[o], s); atomicAdd(&redQ[o], qv); }
    }
    __syncthreads();
    if (t < 24) {
        atomicAdd(&mu3[((size_t)b*24 + t)*2],     redS[t]);
        atomicAdd(&mu3[((size_t)b*24 + t)*2 + 1], redQ[t]);
    }
}

// ---------------------------------------------------------------------------
// K10: gn3-fused tconv4 2x2 s2, 48->12 via MFMA. s3 computed in prologue
// from mc2+mu3. 2048 blocks. Fused u4 stats -> mu4.
__global__ __launch_bounds__(256) void k_tconv4(
    const bf* __restrict__ c2, const bf* __restrict__ u3,
    const float* __restrict__ mc2, const float* __restrict__ mu3,
    const float* __restrict__ g3, const float* __restrict__ be3,
    const float* __restrict__ k4, const float* __restrict__ bias4,
    bf* __restrict__ u4, float* __restrict__ mu4)
{
    __shared__ ushortt sA[256*72];
    __shared__ ushortt sW[48*72];
    __shared__ float redS[12], redQ[12];
    __shared__ float ssl[96];
    int t = threadIdx.x;
    int b = blockIdx.x >> 5, pg = blockIdx.x & 31;
    int lane = t & 63, wid = t >> 6;
    if (t < 12) { redS[t] = 0.f; redQ[t] = 0.f; }
    if (t < 6) {
        float s = 0.f, q = 0.f;
        #pragma unroll
        for (int cl = 0; cl < 8; ++cl) {
            int gc = t*8 + cl;
            const float* p = (gc < 24) ? mc2 + ((size_t)b*24 + gc)*2
                                       : mu3 + ((size_t)b*24 + gc - 24)*2;
            s += p[0]; q += p[1];
        }
        float inv_n = 1.f/((float)PL2*8.f);
        float mean = s*inv_n;
        float var  = q*inv_n - mean*mean;
        float rstd = rsqrtf(var + 1e-5f);
        #pragma unroll
        for (int cl = 0; cl < 8; ++cl) {
            int gc = t*8 + cl;
            float sc = g3[gc]*rstd;
            ssl[gc*2] = sc; ssl[gc*2+1] = be3[gc] - mean*sc;
        }
    }
    #pragma unroll
    for (int j = 0; j < 9; ++j) {
        int e = j*256 + t;
        if (e < 2304) {
            int c = e / 48, n = e % 48;
            sW[n*72 + c] = (ushortt)bfbits(k4[e]);
        }
    }
    if (t < 96) {
        uint4 z = {0,0,0,0};
        int n = t >> 1, c0 = 48 + (t & 1)*8;
        *(uint4*)&sW[n*72 + c0] = z;
    }
    __syncthreads();
    {
        int pix = pg*256 + t;
        const bf* c2p = c2 + (size_t)b*24*PL2 + pix;
        const bf* u3p = u3 + (size_t)b*24*PL2 + pix;
        ushortt* row = &sA[t*72];
        #pragma unroll
        for (int g = 0; g < 6; ++g) {
            unsigned pr[4];
            #pragma unroll
            for (int hc = 0; hc < 4; ++hc) {
                int c0 = g*8 + hc*2;
                float r0 = (c0 < 24) ? tof(c2p[(size_t)c0*PL2]) : tof(u3p[(size_t)(c0-24)*PL2]);
                float r1 = (c0+1 < 24) ? tof(c2p[(size_t)(c0+1)*PL2]) : tof(u3p[(size_t)(c0+1-24)*PL2]);
                float v0 = r0 * ssl[2*c0]   + ssl[2*c0+1];
                float v1 = r1 * ssl[2*c0+2] + ssl[2*c0+3];
                pr[hc] = bfbits(v0) | (bfbits(v1) << 16);
            }
            uint4 pk; pk.x = pr[0]; pk.y = pr[1]; pk.z = pr[2]; pk.w = pr[3];
            *(uint4*)&row[g*8] = pk;
        }
        uint4 z = {0,0,0,0};
        *(uint4*)&row[48] = z;
        *(uint4*)&row[56] = z;
    }
    __syncthreads();
    int m = lane & 15, kq = (lane >> 4)*8;
    b8v bfr[3][2];
    #pragma unroll
    for (int nt = 0; nt < 3; ++nt)
      #pragma unroll
      for (int ks = 0; ks < 2; ++ks)
        bfr[nt][ks] = *(const b8v*)&sW[(nt*16 + m)*72 + ks*32 + kq];
    f4v acc[4][3] = {};
    #pragma unroll
    for (int mt = 0; mt < 4; ++mt) {
        const ushortt* ab = &sA[(wid*64 + mt*16 + m)*72 + kq];
        b8v a0 = *(const b8v*)(ab);
        b8v a1 = *(const b8v*)(ab + 32);
        #pragma unroll
        for (int nt = 0; nt < 3; ++nt) {
            acc[mt][nt] = __builtin_amdgcn_mfma_f32_16x16x32_bf16(a0, bfr[nt][0], acc[mt][nt], 0, 0, 0);
            acc[mt][nt] = __builtin_amdgcn_mfma_f32_16x16x32_bf16(a1, bfr[nt][1], acc[mt][nt], 0, 0, 0);
        }
    }
    __syncthreads();
    ushortt* sC = sA;
    int q4 = lane >> 4;
    #pragma unroll
    for (int mt = 0; mt < 4; ++mt) {
        int pxb = wid*64 + mt*16 + q4*4;
        #pragma unroll
        for (int nt = 0; nt < 3; ++nt) {
            int n = nt*16 + m;
            int o = n >> 2, d = (n >> 1) & 1, qq = n & 1;
            float bo = bias4[o];
            #pragma unroll
            for (int r = 0; r < 4; ++r) {
                int px = pxb + r;
                int yl = ((px >> 7) << 1) + d;
                int xx = ((px & 127) << 1) + qq;
                sC[o*1024 + yl*256 + xx] = (ushortt)bfbits(acc[mt][nt][r] + bo);
            }
        }
    }
    __syncthreads();
    {
        bf* outb = u4 + (size_t)b*12*HP;
        #pragma unroll
        for (int j = 0; j < 6; ++j) {
            int idx16 = j*256 + t;
            int el = idx16*8;
            int o = el >> 10, rem = el & 1023, yl = rem >> 8, x0 = rem & 255;
            uint4 v = *(const uint4*)&sC[el];
            *(uint4*)(outb + ((size_t)o*HH + pg*4 + yl)*EE + x0) = v;
            float v0 = b2f(v.x & 0xffff), v1 = b2f(v.x >> 16);
            float v2 = b2f(v.y & 0xffff), v3 = b2f(v.y >> 16);
            float v4 = b2f(v.z & 0xffff), v5 = b2f(v.z >> 16);
            float v6 = b2f(v.w & 0xffff), v7 = b2f(v.w >> 16);
            float s = v0+v1+v2+v3+v4+v5+v6+v7;
            float qv = v0*v0+v1*v1+v2*v2+v3*v3+v4*v4+v5*v5+v6*v6+v7*v7;
            wred2(s, qv);
            if (lane == 0) { atomicAdd(&redS[o], s); atomicAdd(&redQ[o], qv); }
        }
    }
    __syncthreads();
    if (t < 12) {
        atomicAdd(&mu4[((size_t)b*12 + t)*2],     redS[t]);
        atomicAdd(&mu4[((size_t)b*12 + t)*2 + 1], redQ[t]);
    }
}

// ---------------------------------------------------------------------------
// K12: gn4-fused 1x1 conv 18->6. s4 computed in prologue from mc1+mu4.
// 4 px/thread. Fused u5 stats. 2048 blocks.
__global__ __launch_bounds__(256) void k_conv1x1_u5(
    const bf* __restrict__ c1, const bf* __restrict__ u4,
    const float* __restrict__ mc1, const float* __restrict__ mu4,
    const float* __restrict__ g4, const float* __restrict__ be4,
    const float* __restrict__ k, const float* __restrict__ bias,
    bf* __restrict__ u5, float* __restrict__ mu5)
{
    __shared__ float red[4][6][2];
    __shared__ float ssl[36];
    int t = threadIdx.x;
    int b  = blockIdx.x >> 5;
    int pg = blockIdx.x & 31;
    int pix = pg*1024 + t*4;
    int lane = t & 63, wid = t >> 6;
    if (t < 6) {
        float s = 0.f, q = 0.f;
        #pragma unroll
        for (int cl = 0; cl < 3; ++cl) {
            int gc = t*3 + cl;
            const float* p = (gc < 6) ? mc1 + ((size_t)b*6 + gc)*2
                                      : mu4 + ((size_t)b*12 + gc - 6)*2;
            s += p[0]; q += p[1];
        }
        float inv_n = 1.f/((float)HP*3.f);
        float mean = s*inv_n;
        float var  = q*inv_n - mean*mean;
        float rstd = rsqrtf(var + 1e-5f);
        #pragma unroll
        for (int cl = 0; cl < 3; ++cl) {
            int gc = t*3 + cl;
            float sc = g4[gc]*rstd;
            ssl[gc*2] = sc; ssl[gc*2+1] = be4[gc] - mean*sc;
        }
    }
    __syncthreads();
    const bf* c1p = c1 + ((size_t)b*6)*HP + pix;
    const bf* u4p = u4 + ((size_t)b*12)*HP + pix;
    float acc[6][4];
    #pragma unroll
    for (int o = 0; o < 6; ++o) {
        float bv = bias[o];
        #pragma unroll
        for (int j = 0; j < 4; ++j) acc[o][j] = bv;
    }
    #pragma unroll
    for (int c = 0; c < 18; ++c) {
        uint2 r = (c < 6) ? *(const uint2*)(c1p + (size_t)c*HP)
                          : *(const uint2*)(u4p + (size_t)(c-6)*HP);
        float sc = ssl[2*c], sh = ssl[2*c+1];
        float v0 = b2f(r.x & 0xffff)*sc + sh;
        float v1 = b2f(r.x >> 16)   *sc + sh;
        float v2 = b2f(r.y & 0xffff)*sc + sh;
        float v3 = b2f(r.y >> 16)   *sc + sh;
        #pragma unroll
        for (int o = 0; o < 6; ++o) {
            float wv = k[o*18 + c];
            acc[o][0] += v0*wv; acc[o][1] += v1*wv;
            acc[o][2] += v2*wv; acc[o][3] += v3*wv;
        }
    }
    #pragma unroll
    for (int o = 0; o < 6; ++o) {
        uint2 pk;
        pk.x = bfbits(acc[o][0]) | (bfbits(acc[o][1]) << 16);
        pk.y = bfbits(acc[o][2]) | (bfbits(acc[o][3]) << 16);
        *(uint2*)(u5 + ((size_t)(b*6+o))*HP + pix) = pk;
        float s = acc[o][0]+acc[o][1]+acc[o][2]+acc[o][3];
        float q = acc[o][0]*acc[o][0]+acc[o][1]*acc[o][1]
                + acc[o][2]*acc[o][2]+acc[o][3]*acc[o][3];
        wred2(s, q);
        if (lane == 0) { red[wid][o][0] = s; red[wid][o][1] = q; }
    }
    __syncthreads();
    if (t < 6) {
        float S = 0.f, Q = 0.f;
        #pragma unroll
        for (int wv = 0; wv < 4; ++wv) { S += red[wv][t][0]; Q += red[wv][t][1]; }
        atomicAdd(&mu5[((size_t)b*6 + t)*2],     S);
        atomicAdd(&mu5[((size_t)b*6 + t)*2 + 1], Q);
    }
}

// ---------------------------------------------------------------------------
// K14: gn5-fused final 1x1 conv (6->1) + divide by std(t). s5 in prologue.
__global__ __launch_bounds__(256) void k_final(
    const bf* __restrict__ u5, const float* __restrict__ mu5,
    const float* __restrict__ g5, const float* __restrict__ be5,
    const float* __restrict__ k, const float* __restrict__ bias,
    const float* __restrict__ t, float* __restrict__ out)
{
    __shared__ float ssl[12];
    int tt = threadIdx.x;
    int b = blockIdx.x >> 5;
    int pix = ((blockIdx.x & 31)*256 + tt)*4;
    if (tt < 6) {
        float s = mu5[((size_t)b*6 + tt)*2], q = mu5[((size_t)b*6 + tt)*2 + 1];
        float mean = s * (1.f/HP);
        float var  = q * (1.f/HP) - mean*mean;
        float rstd = rsqrtf(var + 1e-5f);
        float sc = g5[tt]*rstd;
        ssl[tt*2] = sc; ssl[tt*2+1] = be5[tt] - mean*sc;
    }
    __syncthreads();
    const bf* up = u5 + (size_t)b*6*HP + pix;
    float a0 = bias[0], a1 = a0, a2 = a0, a3 = a0;
    #pragma unroll
    for (int c = 0; c < 6; ++c) {
        uint2 r = *(const uint2*)(up + (size_t)c*HP);
        float sc = ssl[2*c], sh = ssl[2*c+1];
        float wv = k[c];
        a0 += (b2f(r.x & 0xffff)*sc + sh) * wv;
        a1 += (b2f(r.x >> 16)   *sc + sh) * wv;
        a2 += (b2f(r.y & 0xffff)*sc + sh) * wv;
        a3 += (b2f(r.y >> 16)   *sc + sh) * wv;
    }
    float tb = t[b];
    const float lns = 3.2188758248682007492f;
    float var = (expf(2.f*tb*lns) - 1.f) / (2.f*lns);
    float rs = rsqrtf(var);
    float4 ov; ov.x = a0*rs; ov.y = a1*rs; ov.z = a2*rs; ov.w = a3*rs;
    *(float4*)(out + (size_t)b*HP + pix) = ov;
}

// ---------------------------------------------------------------------------
extern "C" void kernel_launch(void* const* d_in, const int* in_sizes, int n_in,
                              void* d_out, int out_size, void* d_ws, size_t ws_size,
                              hipStream_t stream)
{
    const float* x       = (const float*)d_in[0];
    const float* t       = (const float*)d_in[1];
    const float* Wf      = (const float*)d_in[2];
    const float* fc1_w   = (const float*)d_in[3];
    const float* fc1_b   = (const float*)d_in[4];
    const float* conv1_k = (const float*)d_in[5];
    const float* conv1_b = (const float*)d_in[6];
    const float* gn1_g   = (const float*)d_in[7];
    const float* gn1_b   = (const float*)d_in[8];
    const float* conv2_k = (const float*)d_in[9];
    const float* conv2_b = (const float*)d_in[10];
    const float* gn2_g   = (const float*)d_in[11];
    const float* gn2_b   = (const float*)d_in[12];
    const float* t3_k    = (const float*)d_in[13];
    const float* t3_b    = (const float*)d_in[14];
    const float* gn3_g   = (const float*)d_in[15];
    const float* gn3_b   = (const float*)d_in[16];
    const float* t4_k    = (const float*)d_in[17];
    const float* t4_b    = (const float*)d_in[18];
    const float* gn4_g   = (const float*)d_in[19];
    const float* gn4_b   = (const float*)d_in[20];
    const float* t5_k    = (const float*)d_in[21];
    const float* t5_b    = (const float*)d_in[22];
    const float* gn5_g   = (const float*)d_in[23];
    const float* gn5_b   = (const float*)d_in[24];
    const float* fin_k   = (const float*)d_in[25];
    const float* fin_b   = (const float*)d_in[26];

    bf* wsb = (bf*)d_ws;
    bf* c1 = wsb;                          // conv1..conv1x1
    bf* c2 = wsb + 12582912;               // conv2..tconv4
    bf* u3 = wsb + 25165824;               // tconv3..tconv4
    bf* u4 = wsb + 37748736;               // tconv4..conv1x1
    bf* xf = wsb + 39845888;               // fc1..conv1 (in u4 region)
    bf* u5 = wsb + 12582912;               // reuses c2, conv1x1..final
    float* mb = (float*)(wsb + 62914560);  // raw channel sums
    float* mc1 = mb;            // 768
    float* mc2 = mb + 768;      // 3072
    float* mu3 = mb + 3840;     // 3072
    float* mu4 = mb + 6912;     // 1536
    float* mu5 = mb + 8448;     // 768

    k_zero<<<9, 256, 0, stream>>>(mb, 9216);
    k_fourier_fc1<<<512, 256, 0, stream>>>(x, Wf, fc1_w, fc1_b, xf);
    k_conv1<<<2048, 256, 0, stream>>>(xf, conv1_k, conv1_b, c1, mc1);
    k_conv2<<<512, 256, 0, stream>>>(c1, mc1, gn1_g, gn1_b,
                                     conv2_k, conv2_b, c2, mc2);
    k_tconv3<<<512, 256, 0, stream>>>(c2, mc2, gn2_g, gn2_b,
                                      t3_k, t3_b, u3, mu3);
    k_tconv4<<<2048, 256, 0, stream>>>(c2, u3, mc2, mu3, gn3_g, gn3_b,
                                       t4_k, t4_b, u4, mu4);
    k_conv1x1_u5<<<2048, 256, 0, stream>>>(c1, u4, mc1, mu4, gn4_g, gn4_b,
                                           t5_k, t5_b, u5, mu5);
    k_final<<<2048, 256, 0, stream>>>(u5, mu5, gn5_g, gn5_b,
                                      fin_k, fin_b, t, (float*)d_out);
}

// Round 8
// 272.196 us; speedup vs baseline: 4.5891x; 1.0251x over previous
//
#include <hip/hip_runtime.h>
#include <hip/hip_bf16.h>
#include <math.h>

#define BB 64
#define HH 128
#define WW 128
#define EE 256
#define HP (HH*EE)        // 32768
#define H2 64
#define W2 128
#define PL2 (H2*W2)       // 8192
#define H4 32
#define W4 64
#define PL4 (H4*W4)       // 2048

typedef __hip_bfloat16 bf;
typedef __hip_bfloat162 bf2;
typedef unsigned short ushortt;
typedef __attribute__((ext_vector_type(8))) __bf16 b8v;
typedef __attribute__((ext_vector_type(4))) float f4v;

__device__ __forceinline__ float tof(float v) { return v; }
__device__ __forceinline__ float tof(bf v)    { return __bfloat162float(v); }
__device__ __forceinline__ bf    tob(float v) { return __float2bfloat16(v); }
__device__ __forceinline__ unsigned int bfbits(float v) {
    return (unsigned int)__builtin_bit_cast(ushortt, __float2bfloat16(v));
}
__device__ __forceinline__ float b2f(unsigned int u16) {
    unsigned int x = u16 << 16;
    return __builtin_bit_cast(float, x);
}
__device__ __forceinline__ void wred2(float& s, float& q) {
    #pragma unroll
    for (int m = 32; m; m >>= 1) {
        s += __shfl_xor(s, m);
        q += __shfl_xor(q, m);
    }
}
// 32-lane reduction (for chunks where o is constant per half-wave only)
__device__ __forceinline__ void wred2_32(float& s, float& q) {
    #pragma unroll
    for (int m = 16; m; m >>= 1) {
        s += __shfl_xor(s, m);
        q += __shfl_xor(q, m);
    }
}

// ---------------------------------------------------------------------------
__global__ __launch_bounds__(256) void k_zero(float* __restrict__ p, int n)
{
    for (int i = blockIdx.x*256 + threadIdx.x; i < n; i += gridDim.x*256) p[i] = 0.f;
}

// ---------------------------------------------------------------------------
// K1: fused Fourier features + fc1 GEMM via MFMA. 512 blocks.
__global__ __launch_bounds__(256) void k_fourier_fc1(
    const float* __restrict__ x, const float* __restrict__ Wf,
    const float* __restrict__ fc1_w, const float* __restrict__ fc1_b,
    bf* __restrict__ xf)
{
    __shared__ ushortt sA[64*264];
    __shared__ ushortt sB[64*264];
    int t = threadIdx.x;
    int rb = blockIdx.x >> 2, cb = blockIdx.x & 3;
    int row0 = rb*64, col0 = cb*64;
    const float TP = 6.2831853071795864769f;
    for (int it = 0; it < 32; ++it) {       // 8192 = 64 rows x 128 w
        int i = it*256 + t;
        int r = i >> 7, w = i & 127;
        int rg = row0 + r;
        float p = x[(size_t)rg*WW + w] * Wf[(size_t)(rg & (HH-1))*WW + w] * TP;
        float s, c;
        sincosf(p, &s, &c);
        sA[r*264 + w]       = (ushortt)bfbits(s);
        sA[r*264 + 128 + w] = (ushortt)bfbits(c);
    }
    #pragma unroll
    for (int it = 0; it < 16; ++it) {       // B: fp32 -> bf16
        int i = it*256 + t;
        int o = i >> 6, c4 = i & 63;
        float4 w4 = *(const float4*)(fc1_w + (size_t)(col0 + o)*EE + c4*4);
        uint2 pk;
        pk.x = bfbits(w4.x) | (bfbits(w4.y) << 16);
        pk.y = bfbits(w4.z) | (bfbits(w4.w) << 16);
        *(uint2*)&sB[o*264 + c4*4] = pk;
    }
    __syncthreads();
    int lane = t & 63, wid = t >> 6;
    int m = lane & 15, kq = (lane >> 4) * 8;
    f4v acc[4] = {};
    const ushortt* aBase = &sA[(wid*16 + m)*264 + kq];
    #pragma unroll
    for (int k0 = 0; k0 < 8; ++k0) {
        b8v av = *(const b8v*)(aBase + k0*32);
        #pragma unroll
        for (int t4 = 0; t4 < 4; ++t4) {
            b8v bv = *(const b8v*)&sB[(t4*16 + m)*264 + k0*32 + kq];
            acc[t4] = __builtin_amdgcn_mfma_f32_16x16x32_bf16(av, bv, acc[t4], 0, 0, 0);
        }
    }
    int rbase = row0 + wid*16 + (lane >> 4)*4;
    #pragma unroll
    for (int t4 = 0; t4 < 4; ++t4) {
        int col = col0 + t4*16 + m;
        float bias = fc1_b[col];
        #pragma unroll
        for (int r = 0; r < 4; ++r)
            xf[(size_t)(rbase + r)*EE + col] = tob(acc[t4][r] + bias);
    }
}

// ---------------------------------------------------------------------------
// K2: conv1 3x3, 1->6, LDS-staged rows, 4 px/thread. 2048 blocks. Fused gn1 stats.
__global__ __launch_bounds__(256) void k_conv1(
    const bf* __restrict__ xf, const float* __restrict__ k,
    const float* __restrict__ bias, bf* __restrict__ c1, float* __restrict__ mc1)
{
    __shared__ ushortt sT[6*272];    // 6 rows, data at [8..263], zero halos
    __shared__ float red[4][6][2];
    int t = threadIdx.x;
    int ht = blockIdx.x & 31, b = blockIdx.x >> 5;
    int h0 = ht*4;
    const bf* src = xf + (size_t)b*HP;
    if (t < 192) {
        int r = t >> 5, i = t & 31;
        int gy = h0 - 1 + r;
        uint4 v = {0,0,0,0};
        if (gy >= 0 && gy < HH) v = *(const uint4*)(src + (size_t)gy*EE + i*8);
        *(uint4*)&sT[r*272 + 8 + i*8] = v;
    } else if (t < 204) {
        int e = t - 192;
        int r = e >> 1, s = e & 1;
        uint4 z = {0,0,0,0};
        *(uint4*)&sT[r*272 + s*264] = z;
    }
    __syncthreads();
    int wq = (t & 63)*4, hl = t >> 6;
    int lane = t & 63, wid = t >> 6;
    float v[3][6];
    #pragma unroll
    for (int ky = 0; ky < 3; ++ky)
      #pragma unroll
      for (int j = 0; j < 6; ++j)
        v[ky][j] = b2f((unsigned)sT[(hl+ky)*272 + 7 + wq + j]);
    int h = h0 + hl;
    #pragma unroll
    for (int o = 0; o < 6; ++o) {
        float bv = bias[o];
        float a0=bv, a1=bv, a2=bv, a3=bv;
        #pragma unroll
        for (int ky = 0; ky < 3; ++ky)
          #pragma unroll
          for (int kx = 0; kx < 3; ++kx) {
            float wv = k[o*9 + ky*3 + kx];
            a0 += v[ky][kx+0]*wv;
            a1 += v[ky][kx+1]*wv;
            a2 += v[ky][kx+2]*wv;
            a3 += v[ky][kx+3]*wv;
          }
        uint2 pk;
        pk.x = bfbits(a0) | (bfbits(a1) << 16);
        pk.y = bfbits(a2) | (bfbits(a3) << 16);
        *(uint2*)(c1 + ((size_t)(b*6+o)*HH + h)*EE + wq) = pk;
        float s = a0+a1+a2+a3, q = a0*a0+a1*a1+a2*a2+a3*a3;
        wred2(s, q);
        if (lane == 0) { red[wid][o][0] = s; red[wid][o][1] = q; }
    }
    __syncthreads();
    if (t < 6) {
        float S = 0.f, Q = 0.f;
        #pragma unroll
        for (int wv = 0; wv < 4; ++wv) { S += red[wv][t][0]; Q += red[wv][t][1]; }
        atomicAdd(&mc1[((size_t)b*6 + t)*2],     S);
        atomicAdd(&mc1[((size_t)b*6 + t)*2 + 1], Q);
    }
}

// ---------------------------------------------------------------------------
// K5: conv2 3x3, 6->24 via MFMA implicit GEMM, fused gn1+ReLU+pool staging.
// Block = 2 output rows x 128 cols = 256 px. M=256, K=54(pad64), N=24(pad32).
// 2048 blocks. Fused gn2 stats -> mc2.
__global__ __launch_bounds__(256) void k_conv2(
    const bf* __restrict__ c1, const float* __restrict__ mc1,
    const float* __restrict__ g1, const float* __restrict__ be1,
    const float* __restrict__ kw, const float* __restrict__ bias,
    bf* __restrict__ c2, float* __restrict__ mc2)
{
    __shared__ ushortt sA[256*72];     // im2col A; aliased by sC after MFMA
    __shared__ ushortt sW[32*72];
    __shared__ ushortt sP[6*4*136];    // pooled halo tile
    __shared__ float ssl[12];
    __shared__ float redS[24], redQ[24];
    int t = threadIdx.x;
    int ht = blockIdx.x & 31, b = blockIdx.x >> 5;
    int h0 = ht*2;                     // output rows h0, h0+1 (of 64)
    int lane = t & 63, wid = t >> 6;
    if (t < 24) { redS[t] = 0.f; redQ[t] = 0.f; }
    if (t < 6) {
        float s = mc1[((size_t)b*6 + t)*2], q = mc1[((size_t)b*6 + t)*2 + 1];
        float mean = s * (1.f/HP);
        float var  = q * (1.f/HP) - mean*mean;
        float rstd = rsqrtf(var + 1e-5f);
        float sc = g1[t]*rstd;
        ssl[t*2] = sc; ssl[t*2+1] = be1[t] - mean*sc;
    }
    for (int i = t; i < 1152; i += 256) ((unsigned*)sW)[i] = 0;   // zero W pad
    __syncthreads();
    // stage pooled tile (gn1+ReLU+pool): 6 ch x 4 rows x 130 cols
    for (int i = t; i < 3120; i += 256) {
        int c = i / 520, rem = i % 520;
        int ry = rem / 130, rx = rem % 130;
        int gy = h0 - 1 + ry, gx = rx - 1;
        float v = 0.f;
        if (gy >= 0 && gy < H2 && gx >= 0 && gx < W2) {
            const bf* pp = c1 + ((size_t)(b*6+c)*HH + 2*gy)*EE + 2*gx;
            unsigned r0 = *(const unsigned*)pp;
            unsigned r1 = *(const unsigned*)(pp + EE);
            float sc = ssl[c*2], sh = ssl[c*2+1];
            float e0 = fmaxf(b2f(r0 & 0xffff)*sc+sh, 0.f);
            float e1 = fmaxf(b2f(r0 >> 16)   *sc+sh, 0.f);
            float e2 = fmaxf(b2f(r1 & 0xffff)*sc+sh, 0.f);
            float e3 = fmaxf(b2f(r1 >> 16)   *sc+sh, 0.f);
            v = fmaxf(fmaxf(e0,e1), fmaxf(e2,e3));
        }
        sP[c*544 + ry*136 + rx] = (ushortt)bfbits(v);
    }
    // stage W data: kw[o][c][ky][kx] -> sW[o][k=c*9+ky*3+kx]
    for (int e = t; e < 1296; e += 256) {
        int o = e / 54, kk = e % 54;
        sW[o*72 + kk] = (ushortt)bfbits(kw[e]);
    }
    __syncthreads();
    // im2col: thread t -> px (r = t>>7, xx = t&127)
    {
        int r = t >> 7, xx = t & 127;
        unsigned u[32];
        #pragma unroll
        for (int p = 0; p < 27; ++p) {
            int k0 = 2*p, k1 = 2*p + 1;
            int c0 = k0/9, y0 = (k0%9)/3, x0 = k0%3;
            int c1i = k1/9, y1 = (k1%9)/3, x1 = k1%3;
            unsigned lo = sP[c0*544 + (r+y0)*136 + xx + x0];
            unsigned hi = sP[c1i*544 + (r+y1)*136 + xx + x1];
            u[p] = lo | (hi << 16);
        }
        #pragma unroll
        for (int p = 27; p < 32; ++p) u[p] = 0;
        #pragma unroll
        for (int e = 0; e < 8; ++e) {
            uint4 pk; pk.x = u[4*e]; pk.y = u[4*e+1]; pk.z = u[4*e+2]; pk.w = u[4*e+3];
            *(uint4*)&sA[t*72 + e*8] = pk;
        }
    }
    __syncthreads();
    int m = lane & 15, kq = (lane >> 4)*8;
    b8v wv[2][2];
    #pragma unroll
    for (int nt = 0; nt < 2; ++nt)
      #pragma unroll
      for (int ks = 0; ks < 2; ++ks)
        wv[nt][ks] = *(const b8v*)&sW[(nt*16 + m)*72 + ks*32 + kq];
    f4v acc[4][2] = {};
    #pragma unroll
    for (int mt = 0; mt < 4; ++mt) {
        const ushortt* ab = &sA[(wid*64 + mt*16 + m)*72 + kq];
        b8v a0 = *(const b8v*)(ab);
        b8v a1 = *(const b8v*)(ab + 32);
        #pragma unroll
        for (int nt = 0; nt < 2; ++nt) {
            acc[mt][nt] = __builtin_amdgcn_mfma_f32_16x16x32_bf16(a0, wv[nt][0], acc[mt][nt], 0, 0, 0);
            acc[mt][nt] = __builtin_amdgcn_mfma_f32_16x16x32_bf16(a1, wv[nt][1], acc[mt][nt], 0, 0, 0);
        }
    }
    __syncthreads();
    // C staging: sC[o][r(2)][x(128)]: stride o*272 + r*136 + x
    ushortt* sC = sA;
    int q4 = lane >> 4;
    #pragma unroll
    for (int mt = 0; mt < 4; ++mt) {
        int pxb = wid*64 + mt*16 + q4*4;
        #pragma unroll
        for (int nt = 0; nt < 2; ++nt) {
            int o = nt*16 + m;
            if (o < 24) {
                float bo = bias[o];
                #pragma unroll
                for (int r = 0; r < 4; ++r) {
                    int px = pxb + r;
                    sC[o*272 + (px >> 7)*136 + (px & 127)] =
                        (ushortt)bfbits(acc[mt][nt][r] + bo);
                }
            }
        }
    }
    __syncthreads();
    // coalesced writeback + gn2 stats (o constant per 32 consecutive lanes)
    #pragma unroll
    for (int j = 0; j < 3; ++j) {
        int idx = j*256 + t;               // 768 uint4 chunks
        int o = idx >> 5;
        int rem = idx & 31;
        int r = rem >> 4, x8 = (rem & 15)*8;
        uint4 v = *(const uint4*)&sC[o*272 + r*136 + x8];
        *(uint4*)(c2 + ((size_t)(b*24+o)*H2 + h0 + r)*W2 + x8) = v;
        float v0 = b2f(v.x & 0xffff), v1 = b2f(v.x >> 16);
        float v2 = b2f(v.y & 0xffff), v3 = b2f(v.y >> 16);
        float v4 = b2f(v.z & 0xffff), v5 = b2f(v.z >> 16);
        float v6 = b2f(v.w & 0xffff), v7 = b2f(v.w >> 16);
        float s = v0+v1+v2+v3+v4+v5+v6+v7;
        float qv = v0*v0+v1*v1+v2*v2+v3*v3+v4*v4+v5*v5+v6*v6+v7*v7;
        wred2_32(s, qv);
        if ((lane & 31) == 0) { atomicAdd(&redS[o], s); atomicAdd(&redQ[o], qv); }
    }
    __syncthreads();
    if (t < 24) {
        atomicAdd(&mc2[((size_t)b*24 + t)*2],     redS[t]);
        atomicAdd(&mc2[((size_t)b*24 + t)*2 + 1], redQ[t]);
    }
}

// ---------------------------------------------------------------------------
// K8: tconv3 2x2 s2, 24->24 via MFMA, fused gn2+ReLU+pool+SiLU staging from c2.
// A-staging via (c, px-pair) items with uint2 loads. 512 blocks.
__global__ __launch_bounds__(256) void k_tconv3(
    const bf* __restrict__ c2, const float* __restrict__ mc2,
    const float* __restrict__ g2, const float* __restrict__ be2,
    const float* __restrict__ k3, const float* __restrict__ b3,
    bf* __restrict__ u3, float* __restrict__ mu3)
{
    __shared__ ushortt sBuf[27648];       // A[256*40] + W[96*40] aliased by C[24*1152]
    __shared__ float redS[24], redQ[24];
    __shared__ float ssl[48];
    ushortt* sA = sBuf;
    ushortt* sW = sBuf + 10240;
    int t = threadIdx.x;
    int b = blockIdx.x >> 3, pg = blockIdx.x & 7;
    int lane = t & 63, wid = t >> 6;
    if (t < 24) {
        redS[t] = 0.f; redQ[t] = 0.f;
        float s = mc2[((size_t)b*24 + t)*2], q = mc2[((size_t)b*24 + t)*2 + 1];
        float mean = s * (1.f/PL2);
        float var  = q * (1.f/PL2) - mean*mean;
        float rstd = rsqrtf(var + 1e-5f);
        float sc = g2[t]*rstd;
        ssl[t*2] = sc; ssl[t*2+1] = be2[t] - mean*sc;
    }
    // stage W: k3[c][o][dq] -> sW[n=o*4+dq][kpad=c]
    #pragma unroll
    for (int j = 0; j < 9; ++j) {
        int e = j*256 + t;
        int c = e / 96, n = e % 96;
        sW[n*40 + c] = (ushortt)bfbits(k3[e]);
    }
    if (t < 96) { uint4 z = {0,0,0,0}; *(uint4*)&sW[t*40 + 24] = z; }
    { uint4 z = {0,0,0,0}; *(uint4*)&sA[t*40 + 24] = z; }   // zero A k-pad
    __syncthreads();
    // stage A: item = (c, px-pair). 24*128 = 3072 items, uint2 loads.
    #pragma unroll
    for (int j = 0; j < 12; ++j) {
        int i = j*256 + t;
        int c = i >> 7, pr = i & 127;
        int px0 = pr*2;
        int h4 = (pg*256 + px0) >> 6, w4 = px0 & 63;     // w4 even
        const bf* pp = c2 + ((size_t)b*24 + c)*PL2 + (size_t)(2*h4)*W2 + 2*w4;
        uint2 r0 = *(const uint2*)pp;
        uint2 r1 = *(const uint2*)(pp + W2);
        float sc = ssl[c*2], sh = ssl[c*2+1];
        float e0 = fmaxf(b2f(r0.x & 0xffff)*sc+sh, 0.f);
        float e1 = fmaxf(b2f(r0.x >> 16)   *sc+sh, 0.f);
        float f0 = fmaxf(b2f(r1.x & 0xffff)*sc+sh, 0.f);
        float f1 = fmaxf(b2f(r1.x >> 16)   *sc+sh, 0.f);
        float m0 = fmaxf(fmaxf(e0,e1), fmaxf(f0,f1));
        m0 = m0 / (1.f + expf(-m0));
        float e2 = fmaxf(b2f(r0.y & 0xffff)*sc+sh, 0.f);
        float e3 = fmaxf(b2f(r0.y >> 16)   *sc+sh, 0.f);
        float f2 = fmaxf(b2f(r1.y & 0xffff)*sc+sh, 0.f);
        float f3 = fmaxf(b2f(r1.y >> 16)   *sc+sh, 0.f);
        float m1 = fmaxf(fmaxf(e2,e3), fmaxf(f2,f3));
        m1 = m1 / (1.f + expf(-m1));
        sA[px0*40 + c]     = (ushortt)bfbits(m0);
        sA[(px0+1)*40 + c] = (ushortt)bfbits(m1);
    }
    __syncthreads();
    int m = lane & 15, kq = (lane >> 4)*8;
    b8v wv[6];
    #pragma unroll
    for (int nt = 0; nt < 6; ++nt)
        wv[nt] = *(const b8v*)&sW[(nt*16 + m)*40 + kq];
    f4v acc[4][6] = {};
    #pragma unroll
    for (int mt = 0; mt < 4; ++mt) {
        b8v av = *(const b8v*)&sA[(wid*64 + mt*16 + m)*40 + kq];
        #pragma unroll
        for (int nt = 0; nt < 6; ++nt)
            acc[mt][nt] = __builtin_amdgcn_mfma_f32_16x16x32_bf16(av, wv[nt], acc[mt][nt], 0, 0, 0);
    }
    __syncthreads();
    // C staging: sC[o][yl(8)][x(128)] row stride 144, o stride 1152
    ushortt* sC = sBuf;
    int q4 = lane >> 4;
    #pragma unroll
    for (int mt = 0; mt < 4; ++mt) {
        int pxb = wid*64 + mt*16 + q4*4;
        #pragma unroll
        for (int nt = 0; nt < 6; ++nt) {
            int n = nt*16 + m;
            int o = n >> 2, d = (n >> 1) & 1, qq = n & 1;
            float bo = b3[o];
            #pragma unroll
            for (int r = 0; r < 4; ++r) {
                int px = pxb + r;
                int yl = ((px >> 6) << 1) + d;
                int xx = ((px & 63) << 1) + qq;
                sC[o*1152 + yl*144 + xx] = (ushortt)bfbits(acc[mt][nt][r] + bo);
            }
        }
    }
    __syncthreads();
    bf* outb = u3 + (size_t)b*24*PL2;
    #pragma unroll
    for (int j = 0; j < 12; ++j) {
        int idx = j*256 + t;
        int o = idx >> 7;
        int rem = idx & 127;
        int yl = rem >> 4, xc = (rem & 15)*8;
        uint4 v = *(const uint4*)&sC[o*1152 + yl*144 + xc];
        *(uint4*)(outb + ((size_t)o*H2 + pg*8 + yl)*W2 + xc) = v;
        float v0 = b2f(v.x & 0xffff), v1 = b2f(v.x >> 16);
        float v2 = b2f(v.y & 0xffff), v3 = b2f(v.y >> 16);
        float v4 = b2f(v.z & 0xffff), v5 = b2f(v.z >> 16);
        float v6 = b2f(v.w & 0xffff), v7 = b2f(v.w >> 16);
        float s = v0+v1+v2+v3+v4+v5+v6+v7;
        float qv = v0*v0+v1*v1+v2*v2+v3*v3+v4*v4+v5*v5+v6*v6+v7*v7;
        wred2(s, qv);
        if (lane == 0) { atomicAdd(&redS[o], s); atomicAdd(&redQ[o], qv); }
    }
    __syncthreads();
    if (t < 24) {
        atomicAdd(&mu3[((size_t)b*24 + t)*2],     redS[t]);
        atomicAdd(&mu3[((size_t)b*24 + t)*2 + 1], redQ[t]);
    }
}

// ---------------------------------------------------------------------------
// K10: gn3-fused tconv4 2x2 s2, 48->12 via MFMA. 2048 blocks.
__global__ __launch_bounds__(256) void k_tconv4(
    const bf* __restrict__ c2, const bf* __restrict__ u3,
    const float* __restrict__ mc2, const float* __restrict__ mu3,
    const float* __restrict__ g3, const float* __restrict__ be3,
    const float* __restrict__ k4, const float* __restrict__ bias4,
    bf* __restrict__ u4, float* __restrict__ mu4)
{
    __shared__ ushortt sA[256*72];
    __shared__ ushortt sW[48*72];
    __shared__ float redS[12], redQ[12];
    __shared__ float ssl[96];
    int t = threadIdx.x;
    int b = blockIdx.x >> 5, pg = blockIdx.x & 31;
    int lane = t & 63, wid = t >> 6;
    if (t < 12) { redS[t] = 0.f; redQ[t] = 0.f; }
    if (t < 6) {
        float s = 0.f, q = 0.f;
        #pragma unroll
        for (int cl = 0; cl < 8; ++cl) {
            int gc = t*8 + cl;
            const float* p = (gc < 24) ? mc2 + ((size_t)b*24 + gc)*2
                                       : mu3 + ((size_t)b*24 + gc - 24)*2;
            s += p[0]; q += p[1];
        }
        float inv_n = 1.f/((float)PL2*8.f);
        float mean = s*inv_n;
        float var  = q*inv_n - mean*mean;
        float rstd = rsqrtf(var + 1e-5f);
        #pragma unroll
        for (int cl = 0; cl < 8; ++cl) {
            int gc = t*8 + cl;
            float sc = g3[gc]*rstd;
            ssl[gc*2] = sc; ssl[gc*2+1] = be3[gc] - mean*sc;
        }
    }
    #pragma unroll
    for (int j = 0; j < 9; ++j) {
        int e = j*256 + t;
        if (e < 2304) {
            int c = e / 48, n = e % 48;
            sW[n*72 + c] = (ushortt)bfbits(k4[e]);
        }
    }
    if (t < 96) {
        uint4 z = {0,0,0,0};
        int n = t >> 1, c0 = 48 + (t & 1)*8;
        *(uint4*)&sW[n*72 + c0] = z;
    }
    __syncthreads();
    {
        int pix = pg*256 + t;
        const bf* c2p = c2 + (size_t)b*24*PL2 + pix;
        const bf* u3p = u3 + (size_t)b*24*PL2 + pix;
        ushortt* row = &sA[t*72];
        #pragma unroll
        for (int g = 0; g < 6; ++g) {
            unsigned pr[4];
            #pragma unroll
            for (int hc = 0; hc < 4; ++hc) {
                int c0 = g*8 + hc*2;
                float r0 = (c0 < 24) ? tof(c2p[(size_t)c0*PL2]) : tof(u3p[(size_t)(c0-24)*PL2]);
                float r1 = (c0+1 < 24) ? tof(c2p[(size_t)(c0+1)*PL2]) : tof(u3p[(size_t)(c0+1-24)*PL2]);
                float v0 = r0 * ssl[2*c0]   + ssl[2*c0+1];
                float v1 = r1 * ssl[2*c0+2] + ssl[2*c0+3];
                pr[hc] = bfbits(v0) | (bfbits(v1) << 16);
            }
            uint4 pk; pk.x = pr[0]; pk.y = pr[1]; pk.z = pr[2]; pk.w = pr[3];
            *(uint4*)&row[g*8] = pk;
        }
        uint4 z = {0,0,0,0};
        *(uint4*)&row[48] = z;
        *(uint4*)&row[56] = z;
    }
    __syncthreads();
    int m = lane & 15, kq = (lane >> 4)*8;
    b8v bfr[3][2];
    #pragma unroll
    for (int nt = 0; nt < 3; ++nt)
      #pragma unroll
      for (int ks = 0; ks < 2; ++ks)
        bfr[nt][ks] = *(const b8v*)&sW[(nt*16 + m)*72 + ks*32 + kq];
    f4v acc[4][3] = {};
    #pragma unroll
    for (int mt = 0; mt < 4; ++mt) {
        const ushortt* ab = &sA[(wid*64 + mt*16 + m)*72 + kq];
        b8v a0 = *(const b8v*)(ab);
        b8v a1 = *(const b8v*)(ab + 32);
        #pragma unroll
        for (int nt = 0; nt < 3; ++nt) {
            acc[mt][nt] = __builtin_amdgcn_mfma_f32_16x16x32_bf16(a0, bfr[nt][0], acc[mt][nt], 0, 0, 0);
            acc[mt][nt] = __builtin_amdgcn_mfma_f32_16x16x32_bf16(a1, bfr[nt][1], acc[mt][nt], 0, 0, 0);
        }
    }
    __syncthreads();
    ushortt* sC = sA;
    int q4 = lane >> 4;
    #pragma unroll
    for (int mt = 0; mt < 4; ++mt) {
        int pxb = wid*64 + mt*16 + q4*4;
        #pragma unroll
        for (int nt = 0; nt < 3; ++nt) {
            int n = nt*16 + m;
            int o = n >> 2, d = (n >> 1) & 1, qq = n & 1;
            float bo = bias4[o];
            #pragma unroll
            for (int r = 0; r < 4; ++r) {
                int px = pxb + r;
                int yl = ((px >> 7) << 1) + d;
                int xx = ((px & 127) << 1) + qq;
                sC[o*1024 + yl*256 + xx] = (ushortt)bfbits(acc[mt][nt][r] + bo);
            }
        }
    }
    __syncthreads();
    {
        bf* outb = u4 + (size_t)b*12*HP;
        #pragma unroll
        for (int j = 0; j < 6; ++j) {
            int idx16 = j*256 + t;
            int el = idx16*8;
            int o = el >> 10, rem = el & 1023, yl = rem >> 8, x0 = rem & 255;
            uint4 v = *(const uint4*)&sC[el];
            *(uint4*)(outb + ((size_t)o*HH + pg*4 + yl)*EE + x0) = v;
            float v0 = b2f(v.x & 0xffff), v1 = b2f(v.x >> 16);
            float v2 = b2f(v.y & 0xffff), v3 = b2f(v.y >> 16);
            float v4 = b2f(v.z & 0xffff), v5 = b2f(v.z >> 16);
            float v6 = b2f(v.w & 0xffff), v7 = b2f(v.w >> 16);
            float s = v0+v1+v2+v3+v4+v5+v6+v7;
            float qv = v0*v0+v1*v1+v2*v2+v3*v3+v4*v4+v5*v5+v6*v6+v7*v7;
            wred2(s, qv);
            if (lane == 0) { atomicAdd(&redS[o], s); atomicAdd(&redQ[o], qv); }
        }
    }
    __syncthreads();
    if (t < 12) {
        atomicAdd(&mu4[((size_t)b*12 + t)*2],     redS[t]);
        atomicAdd(&mu4[((size_t)b*12 + t)*2 + 1], redQ[t]);
    }
}

// ---------------------------------------------------------------------------
// K12: gn4-fused 1x1 conv 18->6. 4 px/thread. Fused u5 stats. 2048 blocks.
__global__ __launch_bounds__(256) void k_conv1x1_u5(
    const bf* __restrict__ c1, const bf* __restrict__ u4,
    const float* __restrict__ mc1, const float* __restrict__ mu4,
    const float* __restrict__ g4, const float* __restrict__ be4,
    const float* __restrict__ k, const float* __restrict__ bias,
    bf* __restrict__ u5, float* __restrict__ mu5)
{
    __shared__ float red[4][6][2];
    __shared__ float ssl[36];
    int t = threadIdx.x;
    int b  = blockIdx.x >> 5;
    int pg = blockIdx.x & 31;
    int pix = pg*1024 + t*4;
    int lane = t & 63, wid = t >> 6;
    if (t < 6) {
        float s = 0.f, q = 0.f;
        #pragma unroll
        for (int cl = 0; cl < 3; ++cl) {
            int gc = t*3 + cl;
            const float* p = (gc < 6) ? mc1 + ((size_t)b*6 + gc)*2
                                      : mu4 + ((size_t)b*12 + gc - 6)*2;
            s += p[0]; q += p[1];
        }
        float inv_n = 1.f/((float)HP*3.f);
        float mean = s*inv_n;
        float var  = q*inv_n - mean*mean;
        float rstd = rsqrtf(var + 1e-5f);
        #pragma unroll
        for (int cl = 0; cl < 3; ++cl) {
            int gc = t*3 + cl;
            float sc = g4[gc]*rstd;
            ssl[gc*2] = sc; ssl[gc*2+1] = be4[gc] - mean*sc;
        }
    }
    __syncthreads();
    const bf* c1p = c1 + ((size_t)b*6)*HP + pix;
    const bf* u4p = u4 + ((size_t)b*12)*HP + pix;
    float acc[6][4];
    #pragma unroll
    for (int o = 0; o < 6; ++o) {
        float bv = bias[o];
        #pragma unroll
        for (int j = 0; j < 4; ++j) acc[o][j] = bv;
    }
    #pragma unroll
    for (int c = 0; c < 18; ++c) {
        uint2 r = (c < 6) ? *(const uint2*)(c1p + (size_t)c*HP)
                          : *(const uint2*)(u4p + (size_t)(c-6)*HP);
        float sc = ssl[2*c], sh = ssl[2*c+1];
        float v0 = b2f(r.x & 0xffff)*sc + sh;
        float v1 = b2f(r.x >> 16)   *sc + sh;
        float v2 = b2f(r.y & 0xffff)*sc + sh;
        float v3 = b2f(r.y >> 16)   *sc + sh;
        #pragma unroll
        for (int o = 0; o < 6; ++o) {
            float wv = k[o*18 + c];
            acc[o][0] += v0*wv; acc[o][1] += v1*wv;
            acc[o][2] += v2*wv; acc[o][3] += v3*wv;
        }
    }
    #pragma unroll
    for (int o = 0; o < 6; ++o) {
        uint2 pk;
        pk.x = bfbits(acc[o][0]) | (bfbits(acc[o][1]) << 16);
        pk.y = bfbits(acc[o][2]) | (bfbits(acc[o][3]) << 16);
        *(uint2*)(u5 + ((size_t)(b*6+o))*HP + pix) = pk;
        float s = acc[o][0]+acc[o][1]+acc[o][2]+acc[o][3];
        float q = acc[o][0]*acc[o][0]+acc[o][1]*acc[o][1]
                + acc[o][2]*acc[o][2]+acc[o][3]*acc[o][3];
        wred2(s, q);
        if (lane == 0) { red[wid][o][0] = s; red[wid][o][1] = q; }
    }
    __syncthreads();
    if (t < 6) {
        float S = 0.f, Q = 0.f;
        #pragma unroll
        for (int wv = 0; wv < 4; ++wv) { S += red[wv][t][0]; Q += red[wv][t][1]; }
        atomicAdd(&mu5[((size_t)b*6 + t)*2],     S);
        atomicAdd(&mu5[((size_t)b*6 + t)*2 + 1], Q);
    }
}

// ---------------------------------------------------------------------------
// K14: gn5-fused final 1x1 conv (6->1) + divide by std(t). s5 in prologue.
__global__ __launch_bounds__(256) void k_final(
    const bf* __restrict__ u5, const float* __restrict__ mu5,
    const float* __restrict__ g5, const float* __restrict__ be5,
    const float* __restrict__ k, const float* __restrict__ bias,
    const float* __restrict__ t, float* __restrict__ out)
{
    __shared__ float ssl[12];
    int tt = threadIdx.x;
    int b = blockIdx.x >> 5;
    int pix = ((blockIdx.x & 31)*256 + tt)*4;
    if (tt < 6) {
        float s = mu5[((size_t)b*6 + tt)*2], q = mu5[((size_t)b*6 + tt)*2 + 1];
        float mean = s * (1.f/HP);
        float var  = q * (1.f/HP) - mean*mean;
        float rstd = rsqrtf(var + 1e-5f);
        float sc = g5[tt]*rstd;
        ssl[tt*2] = sc; ssl[tt*2+1] = be5[tt] - mean*sc;
    }
    __syncthreads();
    const bf* up = u5 + (size_t)b*6*HP + pix;
    float a0 = bias[0], a1 = a0, a2 = a0, a3 = a0;
    #pragma unroll
    for (int c = 0; c < 6; ++c) {
        uint2 r = *(const uint2*)(up + (size_t)c*HP);
        float sc = ssl[2*c], sh = ssl[2*c+1];
        float wv = k[c];
        a0 += (b2f(r.x & 0xffff)*sc + sh) * wv;
        a1 += (b2f(r.x >> 16)   *sc + sh) * wv;
        a2 += (b2f(r.y & 0xffff)*sc + sh) * wv;
        a3 += (b2f(r.y >> 16)   *sc + sh) * wv;
    }
    float tb = t[b];
    const float lns = 3.2188758248682007492f;
    float var = (expf(2.f*tb*lns) - 1.f) / (2.f*lns);
    float rs = rsqrtf(var);
    float4 ov; ov.x = a0*rs; ov.y = a1*rs; ov.z = a2*rs; ov.w = a3*rs;
    *(float4*)(out + (size_t)b*HP + pix) = ov;
}

// ---------------------------------------------------------------------------
extern "C" void kernel_launch(void* const* d_in, const int* in_sizes, int n_in,
                              void* d_out, int out_size, void* d_ws, size_t ws_size,
                              hipStream_t stream)
{
    const float* x       = (const float*)d_in[0];
    const float* t       = (const float*)d_in[1];
    const float* Wf      = (const float*)d_in[2];
    const float* fc1_w   = (const float*)d_in[3];
    const float* fc1_b   = (const float*)d_in[4];
    const float* conv1_k = (const float*)d_in[5];
    const float* conv1_b = (const float*)d_in[6];
    const float* gn1_g   = (const float*)d_in[7];
    const float* gn1_b   = (const float*)d_in[8];
    const float* conv2_k = (const float*)d_in[9];
    const float* conv2_b = (const float*)d_in[10];
    const float* gn2_g   = (const float*)d_in[11];
    const float* gn2_b   = (const float*)d_in[12];
    const float* t3_k    = (const float*)d_in[13];
    const float* t3_b    = (const float*)d_in[14];
    const float* gn3_g   = (const float*)d_in[15];
    const float* gn3_b   = (const float*)d_in[16];
    const float* t4_k    = (const float*)d_in[17];
    const float* t4_b    = (const float*)d_in[18];
    const float* gn4_g   = (const float*)d_in[19];
    const float* gn4_b   = (const float*)d_in[20];
    const float* t5_k    = (const float*)d_in[21];
    const float* t5_b    = (const float*)d_in[22];
    const float* gn5_g   = (const float*)d_in[23];
    const float* gn5_b   = (const float*)d_in[24];
    const float* fin_k   = (const float*)d_in[25];
    const float* fin_b   = (const float*)d_in[26];

    bf* wsb = (bf*)d_ws;
    bf* c1 = wsb;                          // conv1..conv1x1
    bf* c2 = wsb + 12582912;               // conv2..tconv4
    bf* u3 = wsb + 25165824;               // tconv3..tconv4
    bf* u4 = wsb + 37748736;               // tconv4..conv1x1
    bf* xf = wsb + 39845888;               // fc1..conv1 (in u4 region)
    bf* u5 = wsb + 12582912;               // reuses c2, conv1x1..final
    float* mb = (float*)(wsb + 62914560);  // raw channel sums
    float* mc1 = mb;            // 768
    float* mc2 = mb + 768;      // 3072
    float* mu3 = mb + 3840;     // 3072
    float* mu4 = mb + 6912;     // 1536
    float* mu5 = mb + 8448;     // 768

    k_zero<<<9, 256, 0, stream>>>(mb, 9216);
    k_fourier_fc1<<<512, 256, 0, stream>>>(x, Wf, fc1_w, fc1_b, xf);
    k_conv1<<<2048, 256, 0, stream>>>(xf, conv1_k, conv1_b, c1, mc1);
    k_conv2<<<2048, 256, 0, stream>>>(c1, mc1, gn1_g, gn1_b,
                                      conv2_k, conv2_b, c2, mc2);
    k_tconv3<<<512, 256, 0, stream>>>(c2, mc2, gn2_g, gn2_b,
                                      t3_k, t3_b, u3, mu3);
    k_tconv4<<<2048, 256, 0, stream>>>(c2, u3, mc2, mu3, gn3_g, gn3_b,
                                       t4_k, t4_b, u4, mu4);
    k_conv1x1_u5<<<2048, 256, 0, stream>>>(c1, u4, mc1, mu4, gn4_g, gn4_b,
                                           t5_k, t5_b, u5, mu5);
    k_final<<<2048, 256, 0, stream>>>(u5, mu5, gn5_g, gn5_b,
                                      fin_k, fin_b, t, (float*)d_out);
}

// Round 10
// 257.126 us; speedup vs baseline: 4.8581x; 1.0586x over previous
//
#include <hip/hip_runtime.h>
#include <hip/hip_bf16.h>
#include <math.h>

#define BB 64
#define HH 128
#define WW 128
#define EE 256
#define HP (HH*EE)        // 32768
#define H2 64
#define W2 128
#define PL2 (H2*W2)       // 8192
#define H4 32
#define W4 64
#define PL4 (H4*W4)       // 2048

typedef __hip_bfloat16 bf;
typedef unsigned short ushortt;
typedef __attribute__((ext_vector_type(8))) __bf16 b8v;
typedef __attribute__((ext_vector_type(4))) float f4v;

__device__ __forceinline__ float tof(bf v)    { return __bfloat162float(v); }
__device__ __forceinline__ bf    tob(float v) { return __float2bfloat16(v); }
__device__ __forceinline__ unsigned int bfbits(float v) {
    return (unsigned int)__builtin_bit_cast(ushortt, __float2bfloat16(v));
}
__device__ __forceinline__ float b2f(unsigned int u16) {
    unsigned int x = u16 << 16;
    return __builtin_bit_cast(float, x);
}
__device__ __forceinline__ void wred2(float& s, float& q) {
    #pragma unroll
    for (int m = 32; m; m >>= 1) {
        s += __shfl_xor(s, m);
        q += __shfl_xor(q, m);
    }
}
__device__ __forceinline__ void wred2_32(float& s, float& q) {
    #pragma unroll
    for (int m = 16; m; m >>= 1) {
        s += __shfl_xor(s, m);
        q += __shfl_xor(q, m);
    }
}

// ---------------------------------------------------------------------------
// K1: fused Fourier features + fc1 GEMM via MFMA. 512 blocks.
// Prologue grid-stride zeroes the stats buffer (mb, 9216 floats) — ordered
// ahead of all consumers by the kernel boundary.
__global__ __launch_bounds__(256) void k_fourier_fc1(
    const float* __restrict__ x, const float* __restrict__ Wf,
    const float* __restrict__ fc1_w, const float* __restrict__ fc1_b,
    bf* __restrict__ xf, float* __restrict__ mb)
{
    __shared__ ushortt sA[64*264];
    __shared__ ushortt sB[64*264];
    int t = threadIdx.x;
    for (int i = blockIdx.x*256 + t; i < 9216; i += 512*256) mb[i] = 0.f;
    int rb = blockIdx.x >> 2, cb = blockIdx.x & 3;
    int row0 = rb*64, col0 = cb*64;
    const float TP = 6.2831853071795864769f;
    for (int it = 0; it < 32; ++it) {       // 8192 = 64 rows x 128 w
        int i = it*256 + t;
        int r = i >> 7, w = i & 127;
        int rg = row0 + r;
        float p = x[(size_t)rg*WW + w] * Wf[(size_t)(rg & (HH-1))*WW + w] * TP;
        sA[r*264 + w]       = (ushortt)bfbits(__sinf(p));
        sA[r*264 + 128 + w] = (ushortt)bfbits(__cosf(p));
    }
    #pragma unroll
    for (int it = 0; it < 16; ++it) {       // B: fp32 -> bf16
        int i = it*256 + t;
        int o = i >> 6, c4 = i & 63;
        float4 w4 = *(const float4*)(fc1_w + (size_t)(col0 + o)*EE + c4*4);
        uint2 pk;
        pk.x = bfbits(w4.x) | (bfbits(w4.y) << 16);
        pk.y = bfbits(w4.z) | (bfbits(w4.w) << 16);
        *(uint2*)&sB[o*264 + c4*4] = pk;
    }
    __syncthreads();
    int lane = t & 63, wid = t >> 6;
    int m = lane & 15, kq = (lane >> 4) * 8;
    f4v acc[4] = {};
    const ushortt* aBase = &sA[(wid*16 + m)*264 + kq];
    #pragma unroll
    for (int k0 = 0; k0 < 8; ++k0) {
        b8v av = *(const b8v*)(aBase + k0*32);
        #pragma unroll
        for (int t4 = 0; t4 < 4; ++t4) {
            b8v bv = *(const b8v*)&sB[(t4*16 + m)*264 + k0*32 + kq];
            acc[t4] = __builtin_amdgcn_mfma_f32_16x16x32_bf16(av, bv, acc[t4], 0, 0, 0);
        }
    }
    int rbase = row0 + wid*16 + (lane >> 4)*4;
    #pragma unroll
    for (int t4 = 0; t4 < 4; ++t4) {
        int col = col0 + t4*16 + m;
        float bias = fc1_b[col];
        #pragma unroll
        for (int r = 0; r < 4; ++r)
            xf[(size_t)(rbase + r)*EE + col] = tob(acc[t4][r] + bias);
    }
}

// ---------------------------------------------------------------------------
// K2: conv1 3x3, 1->6, LDS-staged rows, 4 px/thread. 2048 blocks. Fused gn1 stats.
__global__ __launch_bounds__(256) void k_conv1(
    const bf* __restrict__ xf, const float* __restrict__ k,
    const float* __restrict__ bias, bf* __restrict__ c1, float* __restrict__ mc1)
{
    __shared__ ushortt sT[6*272];    // 6 rows, data at [8..263], zero halos
    __shared__ float red[4][6][2];
    int t = threadIdx.x;
    int ht = blockIdx.x & 31, b = blockIdx.x >> 5;
    int h0 = ht*4;
    const bf* src = xf + (size_t)b*HP;
    if (t < 192) {
        int r = t >> 5, i = t & 31;
        int gy = h0 - 1 + r;
        uint4 v = {0,0,0,0};
        if (gy >= 0 && gy < HH) v = *(const uint4*)(src + (size_t)gy*EE + i*8);
        *(uint4*)&sT[r*272 + 8 + i*8] = v;
    } else if (t < 204) {
        int e = t - 192;
        int r = e >> 1, s = e & 1;
        uint4 z = {0,0,0,0};
        *(uint4*)&sT[r*272 + s*264] = z;
    }
    __syncthreads();
    int wq = (t & 63)*4, hl = t >> 6;
    int lane = t & 63, wid = t >> 6;
    float v[3][6];
    #pragma unroll
    for (int ky = 0; ky < 3; ++ky)
      #pragma unroll
      for (int j = 0; j < 6; ++j)
        v[ky][j] = b2f((unsigned)sT[(hl+ky)*272 + 7 + wq + j]);
    int h = h0 + hl;
    #pragma unroll
    for (int o = 0; o < 6; ++o) {
        float bv = bias[o];
        float a0=bv, a1=bv, a2=bv, a3=bv;
        #pragma unroll
        for (int ky = 0; ky < 3; ++ky)
          #pragma unroll
          for (int kx = 0; kx < 3; ++kx) {
            float wv = k[o*9 + ky*3 + kx];
            a0 += v[ky][kx+0]*wv;
            a1 += v[ky][kx+1]*wv;
            a2 += v[ky][kx+2]*wv;
            a3 += v[ky][kx+3]*wv;
          }
        uint2 pk;
        pk.x = bfbits(a0) | (bfbits(a1) << 16);
        pk.y = bfbits(a2) | (bfbits(a3) << 16);
        *(uint2*)(c1 + ((size_t)(b*6+o)*HH + h)*EE + wq) = pk;
        float s = a0+a1+a2+a3, q = a0*a0+a1*a1+a2*a2+a3*a3;
        wred2(s, q);
        if (lane == 0) { red[wid][o][0] = s; red[wid][o][1] = q; }
    }
    __syncthreads();
    if (t < 6) {
        float S = 0.f, Q = 0.f;
        #pragma unroll
        for (int wv = 0; wv < 4; ++wv) { S += red[wv][t][0]; Q += red[wv][t][1]; }
        atomicAdd(&mc1[((size_t)b*6 + t)*2],     S);
        atomicAdd(&mc1[((size_t)b*6 + t)*2 + 1], Q);
    }
}

// ---------------------------------------------------------------------------
// K5: conv2 3x3, 6->24 via MFMA implicit GEMM, fused gn1+ReLU+pool staging.
// Block = 2 output rows x 128 cols = 256 px. M=256, K=54(pad64), N=24(pad32).
// 2048 blocks. Fused gn2 stats -> mc2.
__global__ __launch_bounds__(256) void k_conv2(
    const bf* __restrict__ c1, const float* __restrict__ mc1,
    const float* __restrict__ g1, const float* __restrict__ be1,
    const float* __restrict__ kw, const float* __restrict__ bias,
    bf* __restrict__ c2, float* __restrict__ mc2)
{
    __shared__ ushortt sA[256*72];     // im2col A; aliased by sC after MFMA
    __shared__ ushortt sW[32*72];
    __shared__ ushortt sP[6*4*136];    // pooled halo tile
    __shared__ float ssl[12];
    __shared__ float redS[24], redQ[24];
    int t = threadIdx.x;
    int ht = blockIdx.x & 31, b = blockIdx.x >> 5;
    int h0 = ht*2;                     // output rows h0, h0+1 (of 64)
    int lane = t & 63, wid = t >> 6;
    if (t < 24) { redS[t] = 0.f; redQ[t] = 0.f; }
    if (t < 6) {
        float s = mc1[((size_t)b*6 + t)*2], q = mc1[((size_t)b*6 + t)*2 + 1];
        float mean = s * (1.f/HP);
        float var  = q * (1.f/HP) - mean*mean;
        float rstd = rsqrtf(var + 1e-5f);
        float sc = g1[t]*rstd;
        ssl[t*2] = sc; ssl[t*2+1] = be1[t] - mean*sc;
    }
    for (int i = t; i < 1152; i += 256) ((unsigned*)sW)[i] = 0;   // zero W pad
    __syncthreads();
    // stage pooled tile (gn1+ReLU+pool): 6 ch x 4 rows x 130 cols
    for (int i = t; i < 3120; i += 256) {
        int c = i / 520, rem = i % 520;
        int ry = rem / 130, rx = rem % 130;
        int gy = h0 - 1 + ry, gx = rx - 1;
        float v = 0.f;
        if (gy >= 0 && gy < H2 && gx >= 0 && gx < W2) {
            const bf* pp = c1 + ((size_t)(b*6+c)*HH + 2*gy)*EE + 2*gx;
            unsigned r0 = *(const unsigned*)pp;
            unsigned r1 = *(const unsigned*)(pp + EE);
            float sc = ssl[c*2], sh = ssl[c*2+1];
            float e0 = fmaxf(b2f(r0 & 0xffff)*sc+sh, 0.f);
            float e1 = fmaxf(b2f(r0 >> 16)   *sc+sh, 0.f);
            float e2 = fmaxf(b2f(r1 & 0xffff)*sc+sh, 0.f);
            float e3 = fmaxf(b2f(r1 >> 16)   *sc+sh, 0.f);
            v = fmaxf(fmaxf(e0,e1), fmaxf(e2,e3));
        }
        sP[c*544 + ry*136 + rx] = (ushortt)bfbits(v);
    }
    // stage W data: kw[o][c][ky][kx] -> sW[o][k=c*9+ky*3+kx]
    for (int e = t; e < 1296; e += 256) {
        int o = e / 54, kk = e % 54;
        sW[o*72 + kk] = (ushortt)bfbits(kw[e]);
    }
    __syncthreads();
    // im2col: thread t -> px (r = t>>7, xx = t&127)
    {
        int r = t >> 7, xx = t & 127;
        unsigned u[32];
        #pragma unroll
        for (int p = 0; p < 27; ++p) {
            int k0 = 2*p, k1 = 2*p + 1;
            int c0 = k0/9, y0 = (k0%9)/3, x0 = k0%3;
            int c1i = k1/9, y1 = (k1%9)/3, x1 = k1%3;
            unsigned lo = sP[c0*544 + (r+y0)*136 + xx + x0];
            unsigned hi = sP[c1i*544 + (r+y1)*136 + xx + x1];
            u[p] = lo | (hi << 16);
        }
        #pragma unroll
        for (int p = 27; p < 32; ++p) u[p] = 0;
        #pragma unroll
        for (int e = 0; e < 8; ++e) {
            uint4 pk; pk.x = u[4*e]; pk.y = u[4*e+1]; pk.z = u[4*e+2]; pk.w = u[4*e+3];
            *(uint4*)&sA[t*72 + e*8] = pk;
        }
    }
    __syncthreads();
    int m = lane & 15, kq = (lane >> 4)*8;
    b8v wv[2][2];
    #pragma unroll
    for (int nt = 0; nt < 2; ++nt)
      #pragma unroll
      for (int ks = 0; ks < 2; ++ks)
        wv[nt][ks] = *(const b8v*)&sW[(nt*16 + m)*72 + ks*32 + kq];
    f4v acc[4][2] = {};
    #pragma unroll
    for (int mt = 0; mt < 4; ++mt) {
        const ushortt* ab = &sA[(wid*64 + mt*16 + m)*72 + kq];
        b8v a0 = *(const b8v*)(ab);
        b8v a1 = *(const b8v*)(ab + 32);
        #pragma unroll
        for (int nt = 0; nt < 2; ++nt) {
            acc[mt][nt] = __builtin_amdgcn_mfma_f32_16x16x32_bf16(a0, wv[nt][0], acc[mt][nt], 0, 0, 0);
            acc[mt][nt] = __builtin_amdgcn_mfma_f32_16x16x32_bf16(a1, wv[nt][1], acc[mt][nt], 0, 0, 0);
        }
    }
    __syncthreads();
    // C staging: sC[o][r(2)][x(128)]: stride o*272 + r*136 + x
    ushortt* sC = sA;
    int q4 = lane >> 4;
    #pragma unroll
    for (int mt = 0; mt < 4; ++mt) {
        int pxb = wid*64 + mt*16 + q4*4;
        #pragma unroll
        for (int nt = 0; nt < 2; ++nt) {
            int o = nt*16 + m;
            if (o < 24) {
                float bo = bias[o];
                #pragma unroll
                for (int r = 0; r < 4; ++r) {
                    int px = pxb + r;
                    sC[o*272 + (px >> 7)*136 + (px & 127)] =
                        (ushortt)bfbits(acc[mt][nt][r] + bo);
                }
            }
        }
    }
    __syncthreads();
    // coalesced writeback + gn2 stats (o constant per 32 consecutive lanes)
    #pragma unroll
    for (int j = 0; j < 3; ++j) {
        int idx = j*256 + t;               // 768 uint4 chunks
        int o = idx >> 5;
        int rem = idx & 31;
        int r = rem >> 4, x8 = (rem & 15)*8;
        uint4 v = *(const uint4*)&sC[o*272 + r*136 + x8];
        *(uint4*)(c2 + ((size_t)(b*24+o)*H2 + h0 + r)*W2 + x8) = v;
        float v0 = b2f(v.x & 0xffff), v1 = b2f(v.x >> 16);
        float v2 = b2f(v.y & 0xffff), v3 = b2f(v.y >> 16);
        float v4 = b2f(v.z & 0xffff), v5 = b2f(v.z >> 16);
        float v6 = b2f(v.w & 0xffff), v7 = b2f(v.w >> 16);
        float s = v0+v1+v2+v3+v4+v5+v6+v7;
        float qv = v0*v0+v1*v1+v2*v2+v3*v3+v4*v4+v5*v5+v6*v6+v7*v7;
        wred2_32(s, qv);
        if ((lane & 31) == 0) { atomicAdd(&redS[o], s); atomicAdd(&redQ[o], qv); }
    }
    __syncthreads();
    if (t < 24) {
        atomicAdd(&mc2[((size_t)b*24 + t)*2],     redS[t]);
        atomicAdd(&mc2[((size_t)b*24 + t)*2 + 1], redQ[t]);
    }
}

// ---------------------------------------------------------------------------
// K8: tconv3 2x2 s2, 24->24 via MFMA, fused gn2+ReLU+pool+SiLU staging from c2.
// A-staging via (c, px-pair) items with uint2 loads. 512 blocks.
__global__ __launch_bounds__(256) void k_tconv3(
    const bf* __restrict__ c2, const float* __restrict__ mc2,
    const float* __restrict__ g2, const float* __restrict__ be2,
    const float* __restrict__ k3, const float* __restrict__ b3,
    bf* __restrict__ u3, float* __restrict__ mu3)
{
    __shared__ ushortt sBuf[27648];       // A[256*40] + W[96*40] aliased by C[24*1152]
    __shared__ float redS[24], redQ[24];
    __shared__ float ssl[48];
    ushortt* sA = sBuf;
    ushortt* sW = sBuf + 10240;
    int t = threadIdx.x;
    int b = blockIdx.x >> 3, pg = blockIdx.x & 7;
    int lane = t & 63, wid = t >> 6;
    if (t < 24) {
        redS[t] = 0.f; redQ[t] = 0.f;
        float s = mc2[((size_t)b*24 + t)*2], q = mc2[((size_t)b*24 + t)*2 + 1];
        float mean = s * (1.f/PL2);
        float var  = q * (1.f/PL2) - mean*mean;
        float rstd = rsqrtf(var + 1e-5f);
        float sc = g2[t]*rstd;
        ssl[t*2] = sc; ssl[t*2+1] = be2[t] - mean*sc;
    }
    // stage W: k3[c][o][dq] -> sW[n=o*4+dq][kpad=c]
    #pragma unroll
    for (int j = 0; j < 9; ++j) {
        int e = j*256 + t;
        int c = e / 96, n = e % 96;
        sW[n*40 + c] = (ushortt)bfbits(k3[e]);
    }
    if (t < 96) { uint4 z = {0,0,0,0}; *(uint4*)&sW[t*40 + 24] = z; }
    { uint4 z = {0,0,0,0}; *(uint4*)&sA[t*40 + 24] = z; }   // zero A k-pad
    __syncthreads();
    // stage A: item = (c, px-pair). 24*128 = 3072 items, uint2 loads.
    #pragma unroll
    for (int j = 0; j < 12; ++j) {
        int i = j*256 + t;
        int c = i >> 7, pr = i & 127;
        int px0 = pr*2;
        int h4 = (pg*256 + px0) >> 6, w4 = px0 & 63;     // w4 even
        const bf* pp = c2 + ((size_t)b*24 + c)*PL2 + (size_t)(2*h4)*W2 + 2*w4;
        uint2 r0 = *(const uint2*)pp;
        uint2 r1 = *(const uint2*)(pp + W2);
        float sc = ssl[c*2], sh = ssl[c*2+1];
        float e0 = fmaxf(b2f(r0.x & 0xffff)*sc+sh, 0.f);
        float e1 = fmaxf(b2f(r0.x >> 16)   *sc+sh, 0.f);
        float f0 = fmaxf(b2f(r1.x & 0xffff)*sc+sh, 0.f);
        float f1 = fmaxf(b2f(r1.x >> 16)   *sc+sh, 0.f);
        float m0 = fmaxf(fmaxf(e0,e1), fmaxf(f0,f1));
        m0 = m0 / (1.f + expf(-m0));
        float e2 = fmaxf(b2f(r0.y & 0xffff)*sc+sh, 0.f);
        float e3 = fmaxf(b2f(r0.y >> 16)   *sc+sh, 0.f);
        float f2 = fmaxf(b2f(r1.y & 0xffff)*sc+sh, 0.f);
        float f3 = fmaxf(b2f(r1.y >> 16)   *sc+sh, 0.f);
        float m1 = fmaxf(fmaxf(e2,e3), fmaxf(f2,f3));
        m1 = m1 / (1.f + expf(-m1));
        sA[px0*40 + c]     = (ushortt)bfbits(m0);
        sA[(px0+1)*40 + c] = (ushortt)bfbits(m1);
    }
    __syncthreads();
    int m = lane & 15, kq = (lane >> 4)*8;
    b8v wv[6];
    #pragma unroll
    for (int nt = 0; nt < 6; ++nt)
        wv[nt] = *(const b8v*)&sW[(nt*16 + m)*40 + kq];
    f4v acc[4][6] = {};
    #pragma unroll
    for (int mt = 0; mt < 4; ++mt) {
        b8v av = *(const b8v*)&sA[(wid*64 + mt*16 + m)*40 + kq];
        #pragma unroll
        for (int nt = 0; nt < 6; ++nt)
            acc[mt][nt] = __builtin_amdgcn_mfma_f32_16x16x32_bf16(av, wv[nt], acc[mt][nt], 0, 0, 0);
    }
    __syncthreads();
    // C staging: sC[o][yl(8)][x(128)] row stride 144, o stride 1152
    ushortt* sC = sBuf;
    int q4 = lane >> 4;
    #pragma unroll
    for (int mt = 0; mt < 4; ++mt) {
        int pxb = wid*64 + mt*16 + q4*4;
        #pragma unroll
        for (int nt = 0; nt < 6; ++nt) {
            int n = nt*16 + m;
            int o = n >> 2, d = (n >> 1) & 1, qq = n & 1;
            float bo = b3[o];
            #pragma unroll
            for (int r = 0; r < 4; ++r) {
                int px = pxb + r;
                int yl = ((px >> 6) << 1) + d;
                int xx = ((px & 63) << 1) + qq;
                sC[o*1152 + yl*144 + xx] = (ushortt)bfbits(acc[mt][nt][r] + bo);
            }
        }
    }
    __syncthreads();
    bf* outb = u3 + (size_t)b*24*PL2;
    #pragma unroll
    for (int j = 0; j < 12; ++j) {
        int idx = j*256 + t;
        int o = idx >> 7;
        int rem = idx & 127;
        int yl = rem >> 4, xc = (rem & 15)*8;
        uint4 v = *(const uint4*)&sC[o*1152 + yl*144 + xc];
        *(uint4*)(outb + ((size_t)o*H2 + pg*8 + yl)*W2 + xc) = v;
        float v0 = b2f(v.x & 0xffff), v1 = b2f(v.x >> 16);
        float v2 = b2f(v.y & 0xffff), v3 = b2f(v.y >> 16);
        float v4 = b2f(v.z & 0xffff), v5 = b2f(v.z >> 16);
        float v6 = b2f(v.w & 0xffff), v7 = b2f(v.w >> 16);
        float s = v0+v1+v2+v3+v4+v5+v6+v7;
        float qv = v0*v0+v1*v1+v2*v2+v3*v3+v4*v4+v5*v5+v6*v6+v7*v7;
        wred2(s, qv);
        if (lane == 0) { atomicAdd(&redS[o], s); atomicAdd(&redQ[o], qv); }
    }
    __syncthreads();
    if (t < 24) {
        atomicAdd(&mu3[((size_t)b*24 + t)*2],     redS[t]);
        atomicAdd(&mu3[((size_t)b*24 + t)*2 + 1], redQ[t]);
    }
}

// ---------------------------------------------------------------------------
// K10: gn3-fused tconv4 2x2 s2, 48->12 via MFMA. gn3 prologue from mc2+mu3.
// 2048 blocks.
__global__ __launch_bounds__(256) void k_tconv4(
    const bf* __restrict__ c2, const bf* __restrict__ u3,
    const float* __restrict__ mc2, const float* __restrict__ mu3,
    const float* __restrict__ g3, const float* __restrict__ be3,
    const float* __restrict__ k4, const float* __restrict__ bias4,
    bf* __restrict__ u4, float* __restrict__ mu4)
{
    __shared__ ushortt sA[256*72];
    __shared__ ushortt sW[48*72];
    __shared__ float redS[12], redQ[12];
    __shared__ float ssl[96];
    int t = threadIdx.x;
    int b = blockIdx.x >> 5, pg = blockIdx.x & 31;
    int lane = t & 63, wid = t >> 6;
    if (t < 12) { redS[t] = 0.f; redQ[t] = 0.f; }
    if (t < 6) {
        float s = 0.f, q = 0.f;
        #pragma unroll
        for (int cl = 0; cl < 8; ++cl) {
            int gc = t*8 + cl;
            const float* p = (gc < 24) ? mc2 + ((size_t)b*24 + gc)*2
                                       : mu3 + ((size_t)b*24 + gc - 24)*2;
            s += p[0]; q += p[1];
        }
        float inv_n = 1.f/((float)PL2*8.f);
        float mean = s*inv_n;
        float var  = q*inv_n - mean*mean;
        float rstd = rsqrtf(var + 1e-5f);
        #pragma unroll
        for (int cl = 0; cl < 8; ++cl) {
            int gc = t*8 + cl;
            float sc = g3[gc]*rstd;
            ssl[gc*2] = sc; ssl[gc*2+1] = be3[gc] - mean*sc;
        }
    }
    #pragma unroll
    for (int j = 0; j < 9; ++j) {
        int e = j*256 + t;
        if (e < 2304) {
            int c = e / 48, n = e % 48;
            sW[n*72 + c] = (ushortt)bfbits(k4[e]);
        }
    }
    if (t < 96) {
        uint4 z = {0,0,0,0};
        int n = t >> 1, c0 = 48 + (t & 1)*8;
        *(uint4*)&sW[n*72 + c0] = z;
    }
    __syncthreads();
    {
        int pix = pg*256 + t;
        const bf* c2p = c2 + (size_t)b*24*PL2 + pix;
        const bf* u3p = u3 + (size_t)b*24*PL2 + pix;
        ushortt* row = &sA[t*72];
        #pragma unroll
        for (int g = 0; g < 6; ++g) {
            unsigned pr[4];
            #pragma unroll
            for (int hc = 0; hc < 4; ++hc) {
                int c0 = g*8 + hc*2;
                float r0 = (c0 < 24) ? tof(c2p[(size_t)c0*PL2]) : tof(u3p[(size_t)(c0-24)*PL2]);
                float r1 = (c0+1 < 24) ? tof(c2p[(size_t)(c0+1)*PL2]) : tof(u3p[(size_t)(c0+1-24)*PL2]);
                float v0 = r0 * ssl[2*c0]   + ssl[2*c0+1];
                float v1 = r1 * ssl[2*c0+2] + ssl[2*c0+3];
                pr[hc] = bfbits(v0) | (bfbits(v1) << 16);
            }
            uint4 pk; pk.x = pr[0]; pk.y = pr[1]; pk.z = pr[2]; pk.w = pr[3];
            *(uint4*)&row[g*8] = pk;
        }
        uint4 z = {0,0,0,0};
        *(uint4*)&row[48] = z;
        *(uint4*)&row[56] = z;
    }
    __syncthreads();
    int m = lane & 15, kq = (lane >> 4)*8;
    b8v bfr[3][2];
    #pragma unroll
    for (int nt = 0; nt < 3; ++nt)
      #pragma unroll
      for (int ks = 0; ks < 2; ++ks)
        bfr[nt][ks] = *(const b8v*)&sW[(nt*16 + m)*72 + ks*32 + kq];
    f4v acc[4][3] = {};
    #pragma unroll
    for (int mt = 0; mt < 4; ++mt) {
        const ushortt* ab = &sA[(wid*64 + mt*16 + m)*72 + kq];
        b8v a0 = *(const b8v*)(ab);
        b8v a1 = *(const b8v*)(ab + 32);
        #pragma unroll
        for (int nt = 0; nt < 3; ++nt) {
            acc[mt][nt] = __builtin_amdgcn_mfma_f32_16x16x32_bf16(a0, bfr[nt][0], acc[mt][nt], 0, 0, 0);
            acc[mt][nt] = __builtin_amdgcn_mfma_f32_16x16x32_bf16(a1, bfr[nt][1], acc[mt][nt], 0, 0, 0);
        }
    }
    __syncthreads();
    ushortt* sC = sA;
    int q4 = lane >> 4;
    #pragma unroll
    for (int mt = 0; mt < 4; ++mt) {
        int pxb = wid*64 + mt*16 + q4*4;
        #pragma unroll
        for (int nt = 0; nt < 3; ++nt) {
            int n = nt*16 + m;
            int o = n >> 2, d = (n >> 1) & 1, qq = n & 1;
            float bo = bias4[o];
            #pragma unroll
            for (int r = 0; r < 4; ++r) {
                int px = pxb + r;
                int yl = ((px >> 7) << 1) + d;
                int xx = ((px & 127) << 1) + qq;
                sC[o*1024 + yl*256 + xx] = (ushortt)bfbits(acc[mt][nt][r] + bo);
            }
        }
    }
    __syncthreads();
    {
        bf* outb = u4 + (size_t)b*12*HP;
        #pragma unroll
        for (int j = 0; j < 6; ++j) {
            int idx16 = j*256 + t;
            int el = idx16*8;
            int o = el >> 10, rem = el & 1023, yl = rem >> 8, x0 = rem & 255;
            uint4 v = *(const uint4*)&sC[el];
            *(uint4*)(outb + ((size_t)o*HH + pg*4 + yl)*EE + x0) = v;
            float v0 = b2f(v.x & 0xffff), v1 = b2f(v.x >> 16);
            float v2 = b2f(v.y & 0xffff), v3 = b2f(v.y >> 16);
            float v4 = b2f(v.z & 0xffff), v5 = b2f(v.z >> 16);
            float v6 = b2f(v.w & 0xffff), v7 = b2f(v.w >> 16);
            float s = v0+v1+v2+v3+v4+v5+v6+v7;
            float qv = v0*v0+v1*v1+v2*v2+v3*v3+v4*v4+v5*v5+v6*v6+v7*v7;
            wred2(s, qv);
            if (lane == 0) { atomicAdd(&redS[o], s); atomicAdd(&redQ[o], qv); }
        }
    }
    __syncthreads();
    if (t < 12) {
        atomicAdd(&mu4[((size_t)b*12 + t)*2],     redS[t]);
        atomicAdd(&mu4[((size_t)b*12 + t)*2 + 1], redQ[t]);
    }
}

// ---------------------------------------------------------------------------
// K12: gn4-fused 1x1 conv 18->6. gn4 prologue from mc1+mu4. 4 px/thread.
// Fused u5 stats. 2048 blocks.
__global__ __launch_bounds__(256) void k_conv1x1_u5(
    const bf* __restrict__ c1, const bf* __restrict__ u4,
    const float* __restrict__ mc1, const float* __restrict__ mu4,
    const float* __restrict__ g4, const float* __restrict__ be4,
    const float* __restrict__ k, const float* __restrict__ bias,
    bf* __restrict__ u5, float* __restrict__ mu5)
{
    __shared__ float red[4][6][2];
    __shared__ float ssl[36];
    int t = threadIdx.x;
    int b  = blockIdx.x >> 5;
    int pg = blockIdx.x & 31;
    int pix = pg*1024 + t*4;
    int lane = t & 63, wid = t >> 6;
    if (t < 6) {
        float s = 0.f, q = 0.f;
        #pragma unroll
        for (int cl = 0; cl < 3; ++cl) {
            int gc = t*3 + cl;
            const float* p = (gc < 6) ? mc1 + ((size_t)b*6 + gc)*2
                                      : mu4 + ((size_t)b*12 + gc - 6)*2;
            s += p[0]; q += p[1];
        }
        float inv_n = 1.f/((float)HP*3.f);
        float mean = s*inv_n;
        float var  = q*inv_n - mean*mean;
        float rstd = rsqrtf(var + 1e-5f);
        #pragma unroll
        for (int cl = 0; cl < 3; ++cl) {
            int gc = t*3 + cl;
            float sc = g4[gc]*rstd;
            ssl[gc*2] = sc; ssl[gc*2+1] = be4[gc] - mean*sc;
        }
    }
    __syncthreads();
    const bf* c1p = c1 + ((size_t)b*6)*HP + pix;
    const bf* u4p = u4 + ((size_t)b*12)*HP + pix;
    float acc[6][4];
    #pragma unroll
    for (int o = 0; o < 6; ++o) {
        float bv = bias[o];
        #pragma unroll
        for (int j = 0; j < 4; ++j) acc[o][j] = bv;
    }
    #pragma unroll
    for (int c = 0; c < 18; ++c) {
        uint2 r = (c < 6) ? *(const uint2*)(c1p + (size_t)c*HP)
                          : *(const uint2*)(u4p + (size_t)(c-6)*HP);
        float sc = ssl[2*c], sh = ssl[2*c+1];
        float v0 = b2f(r.x & 0xffff)*sc + sh;
        float v1 = b2f(r.x >> 16)   *sc + sh;
        float v2 = b2f(r.y & 0xffff)*sc + sh;
        float v3 = b2f(r.y >> 16)   *sc + sh;
        #pragma unroll
        for (int o = 0; o < 6; ++o) {
            float wv = k[o*18 + c];
            acc[o][0] += v0*wv; acc[o][1] += v1*wv;
            acc[o][2] += v2*wv; acc[o][3] += v3*wv;
        }
    }
    #pragma unroll
    for (int o = 0; o < 6; ++o) {
        uint2 pk;
        pk.x = bfbits(acc[o][0]) | (bfbits(acc[o][1]) << 16);
        pk.y = bfbits(acc[o][2]) | (bfbits(acc[o][3]) << 16);
        *(uint2*)(u5 + ((size_t)(b*6+o))*HP + pix) = pk;
        float s = acc[o][0]+acc[o][1]+acc[o][2]+acc[o][3];
        float q = acc[o][0]*acc[o][0]+acc[o][1]*acc[o][1]
                + acc[o][2]*acc[o][2]+acc[o][3]*acc[o][3];
        wred2(s, q);
        if (lane == 0) { red[wid][o][0] = s; red[wid][o][1] = q; }
    }
    __syncthreads();
    if (t < 6) {
        float S = 0.f, Q = 0.f;
        #pragma unroll
        for (int wv = 0; wv < 4; ++wv) { S += red[wv][t][0]; Q += red[wv][t][1]; }
        atomicAdd(&mu5[((size_t)b*6 + t)*2],     S);
        atomicAdd(&mu5[((size_t)b*6 + t)*2 + 1], Q);
    }
}

// ---------------------------------------------------------------------------
// K14: gn5-fused final 1x1 conv (6->1) + divide by std(t). gn5 in prologue.
__global__ __launch_bounds__(256) void k_final(
    const bf* __restrict__ u5, const float* __restrict__ mu5,
    const float* __restrict__ g5, const float* __restrict__ be5,
    const float* __restrict__ k, const float* __restrict__ bias,
    const float* __restrict__ t, float* __restrict__ out)
{
    __shared__ float ssl[12];
    int tt = threadIdx.x;
    int b = blockIdx.x >> 5;
    int pix = ((blockIdx.x & 31)*256 + tt)*4;
    if (tt < 6) {
        float s = mu5[((size_t)b*6 + tt)*2], q = mu5[((size_t)b*6 + tt)*2 + 1];
        float mean = s * (1.f/HP);
        float var  = q * (1.f/HP) - mean*mean;
        float rstd = rsqrtf(var + 1e-5f);
        float sc = g5[tt]*rstd;
        ssl[tt*2] = sc; ssl[tt*2+1] = be5[tt] - mean*sc;
    }
    __syncthreads();
    const bf* up = u5 + (size_t)b*6*HP + pix;
    float a0 = bias[0], a1 = a0, a2 = a0, a3 = a0;
    #pragma unroll
    for (int c = 0; c < 6; ++c) {
        uint2 r = *(const uint2*)(up + (size_t)c*HP);
        float sc = ssl[2*c], sh = ssl[2*c+1];
        float wv = k[c];
        a0 += (b2f(r.x & 0xffff)*sc + sh) * wv;
        a1 += (b2f(r.x >> 16)   *sc + sh) * wv;
        a2 += (b2f(r.y & 0xffff)*sc + sh) * wv;
        a3 += (b2f(r.y >> 16)   *sc + sh) * wv;
    }
    float tb = t[b];
    const float lns = 3.2188758248682007492f;
    float var = (expf(2.f*tb*lns) - 1.f) / (2.f*lns);
    float rs = rsqrtf(var);
    float4 ov; ov.x = a0*rs; ov.y = a1*rs; ov.z = a2*rs; ov.w = a3*rs;
    *(float4*)(out + (size_t)b*HP + pix) = ov;
}

// ---------------------------------------------------------------------------
extern "C" void kernel_launch(void* const* d_in, const int* in_sizes, int n_in,
                              void* d_out, int out_size, void* d_ws, size_t ws_size,
                              hipStream_t stream)
{
    const float* x       = (const float*)d_in[0];
    const float* t       = (const float*)d_in[1];
    const float* Wf      = (const float*)d_in[2];
    const float* fc1_w   = (const float*)d_in[3];
    const float* fc1_b   = (const float*)d_in[4];
    const float* conv1_k = (const float*)d_in[5];
    const float* conv1_b = (const float*)d_in[6];
    const float* gn1_g   = (const float*)d_in[7];
    const float* gn1_b   = (const float*)d_in[8];
    const float* conv2_k = (const float*)d_in[9];
    const float* conv2_b = (const float*)d_in[10];
    const float* gn2_g   = (const float*)d_in[11];
    const float* gn2_b   = (const float*)d_in[12];
    const float* t3_k    = (const float*)d_in[13];
    const float* t3_b    = (const float*)d_in[14];
    const float* gn3_g   = (const float*)d_in[15];
    const float* gn3_b   = (const float*)d_in[16];
    const float* t4_k    = (const float*)d_in[17];
    const float* t4_b    = (const float*)d_in[18];
    const float* gn4_g   = (const float*)d_in[19];
    const float* gn4_b   = (const float*)d_in[20];
    const float* t5_k    = (const float*)d_in[21];
    const float* t5_b    = (const float*)d_in[22];
    const float* gn5_g   = (const float*)d_in[23];
    const float* gn5_b   = (const float*)d_in[24];
    const float* fin_k   = (const float*)d_in[25];
    const float* fin_b   = (const float*)d_in[26];

    bf* wsb = (bf*)d_ws;
    bf* c1 = wsb;                          // conv1..conv1x1
    bf* c2 = wsb + 12582912;               // conv2..tconv4
    bf* u3 = wsb + 25165824;               // tconv3..tconv4
    bf* u4 = wsb + 37748736;               // tconv4..conv1x1
    bf* xf = wsb + 39845888;               // fc1..conv1 (in u4 region)
    bf* u5 = wsb + 12582912;               // reuses c2, conv1x1..final
    float* mb = (float*)(wsb + 62914560);  // raw channel sums
    float* mc1 = mb;            // 768
    float* mc2 = mb + 768;      // 3072
    float* mu3 = mb + 3840;     // 3072
    float* mu4 = mb + 6912;     // 1536
    float* mu5 = mb + 8448;     // 768

    k_fourier_fc1<<<512, 256, 0, stream>>>(x, Wf, fc1_w, fc1_b, xf, mb);
    k_conv1<<<2048, 256, 0, stream>>>(xf, conv1_k, conv1_b, c1, mc1);
    k_conv2<<<2048, 256, 0, stream>>>(c1, mc1, gn1_g, gn1_b,
                                      conv2_k, conv2_b, c2, mc2);
    k_tconv3<<<512, 256, 0, stream>>>(c2, mc2, gn2_g, gn2_b,
                                      t3_k, t3_b, u3, mu3);
    k_tconv4<<<2048, 256, 0, stream>>>(c2, u3, mc2, mu3, gn3_g, gn3_b,
                                       t4_k, t4_b, u4, mu4);
    k_conv1x1_u5<<<2048, 256, 0, stream>>>(c1, u4, mc1, mu4, gn4_g, gn4_b,
                                           t5_k, t5_b, u5, mu5);
    k_final<<<2048, 256, 0, stream>>>(u5, mu5, gn5_g, gn5_b,
                                      fin_k, fin_b, t, (float*)d_out);
}

// Round 11
// 248.715 us; speedup vs baseline: 5.0224x; 1.0338x over previous
//
#include <hip/hip_runtime.h>
#include <hip/hip_bf16.h>
#include <math.h>

#define BB 64
#define HH 128
#define WW 128
#define EE 256
#define HP (HH*EE)        // 32768
#define H2 64
#define W2 128
#define PL2 (H2*W2)       // 8192
#define H4 32
#define W4 64
#define PL4 (H4*W4)       // 2048

typedef __hip_bfloat16 bf;
typedef unsigned short ushortt;
typedef __attribute__((ext_vector_type(8))) __bf16 b8v;
typedef __attribute__((ext_vector_type(4))) float f4v;

__device__ __forceinline__ float tof(bf v)    { return __bfloat162float(v); }
__device__ __forceinline__ bf    tob(float v) { return __float2bfloat16(v); }
__device__ __forceinline__ unsigned int bfbits(float v) {
    return (unsigned int)__builtin_bit_cast(ushortt, __float2bfloat16(v));
}
__device__ __forceinline__ float b2f(unsigned int u16) {
    unsigned int x = u16 << 16;
    return __builtin_bit_cast(float, x);
}
__device__ __forceinline__ void wred2(float& s, float& q) {
    #pragma unroll
    for (int m = 32; m; m >>= 1) {
        s += __shfl_xor(s, m);
        q += __shfl_xor(q, m);
    }
}
__device__ __forceinline__ void wred2_32(float& s, float& q) {
    #pragma unroll
    for (int m = 16; m; m >>= 1) {
        s += __shfl_xor(s, m);
        q += __shfl_xor(q, m);
    }
}

// ---------------------------------------------------------------------------
// K1: fused Fourier features + fc1 GEMM via MFMA. 512 blocks.
// Prologue grid-stride zeroes the stats buffer (mb, 9216 floats).
__global__ __launch_bounds__(256) void k_fourier_fc1(
    const float* __restrict__ x, const float* __restrict__ Wf,
    const float* __restrict__ fc1_w, const float* __restrict__ fc1_b,
    bf* __restrict__ xf, float* __restrict__ mb)
{
    __shared__ ushortt sA[64*264];
    __shared__ ushortt sB[64*264];
    int t = threadIdx.x;
    for (int i = blockIdx.x*256 + t; i < 9216; i += 512*256) mb[i] = 0.f;
    int rb = blockIdx.x >> 2, cb = blockIdx.x & 3;
    int row0 = rb*64, col0 = cb*64;
    const float TP = 6.2831853071795864769f;
    for (int it = 0; it < 32; ++it) {       // 8192 = 64 rows x 128 w
        int i = it*256 + t;
        int r = i >> 7, w = i & 127;
        int rg = row0 + r;
        float p = x[(size_t)rg*WW + w] * Wf[(size_t)(rg & (HH-1))*WW + w] * TP;
        sA[r*264 + w]       = (ushortt)bfbits(__sinf(p));
        sA[r*264 + 128 + w] = (ushortt)bfbits(__cosf(p));
    }
    #pragma unroll
    for (int it = 0; it < 16; ++it) {       // B: fp32 -> bf16
        int i = it*256 + t;
        int o = i >> 6, c4 = i & 63;
        float4 w4 = *(const float4*)(fc1_w + (size_t)(col0 + o)*EE + c4*4);
        uint2 pk;
        pk.x = bfbits(w4.x) | (bfbits(w4.y) << 16);
        pk.y = bfbits(w4.z) | (bfbits(w4.w) << 16);
        *(uint2*)&sB[o*264 + c4*4] = pk;
    }
    __syncthreads();
    int lane = t & 63, wid = t >> 6;
    int m = lane & 15, kq = (lane >> 4) * 8;
    f4v acc[4] = {};
    const ushortt* aBase = &sA[(wid*16 + m)*264 + kq];
    #pragma unroll
    for (int k0 = 0; k0 < 8; ++k0) {
        b8v av = *(const b8v*)(aBase + k0*32);
        #pragma unroll
        for (int t4 = 0; t4 < 4; ++t4) {
            b8v bv = *(const b8v*)&sB[(t4*16 + m)*264 + k0*32 + kq];
            acc[t4] = __builtin_amdgcn_mfma_f32_16x16x32_bf16(av, bv, acc[t4], 0, 0, 0);
        }
    }
    int rbase = row0 + wid*16 + (lane >> 4)*4;
    #pragma unroll
    for (int t4 = 0; t4 < 4; ++t4) {
        int col = col0 + t4*16 + m;
        float bias = fc1_b[col];
        #pragma unroll
        for (int r = 0; r < 4; ++r)
            xf[(size_t)(rbase + r)*EE + col] = tob(acc[t4][r] + bias);
    }
}

// ---------------------------------------------------------------------------
// K2: conv1 3x3, 1->6, LDS-staged rows, 4 px/thread. 2048 blocks. Fused gn1 stats.
__global__ __launch_bounds__(256) void k_conv1(
    const bf* __restrict__ xf, const float* __restrict__ k,
    const float* __restrict__ bias, bf* __restrict__ c1, float* __restrict__ mc1)
{
    __shared__ ushortt sT[6*272];    // 6 rows, data at [8..263], zero halos
    __shared__ float red[4][6][2];
    int t = threadIdx.x;
    int ht = blockIdx.x & 31, b = blockIdx.x >> 5;
    int h0 = ht*4;
    const bf* src = xf + (size_t)b*HP;
    if (t < 192) {
        int r = t >> 5, i = t & 31;
        int gy = h0 - 1 + r;
        uint4 v = {0,0,0,0};
        if (gy >= 0 && gy < HH) v = *(const uint4*)(src + (size_t)gy*EE + i*8);
        *(uint4*)&sT[r*272 + 8 + i*8] = v;
    } else if (t < 204) {
        int e = t - 192;
        int r = e >> 1, s = e & 1;
        uint4 z = {0,0,0,0};
        *(uint4*)&sT[r*272 + s*264] = z;
    }
    __syncthreads();
    int wq = (t & 63)*4, hl = t >> 6;
    int lane = t & 63, wid = t >> 6;
    float v[3][6];
    #pragma unroll
    for (int ky = 0; ky < 3; ++ky)
      #pragma unroll
      for (int j = 0; j < 6; ++j)
        v[ky][j] = b2f((unsigned)sT[(hl+ky)*272 + 7 + wq + j]);
    int h = h0 + hl;
    #pragma unroll
    for (int o = 0; o < 6; ++o) {
        float bv = bias[o];
        float a0=bv, a1=bv, a2=bv, a3=bv;
        #pragma unroll
        for (int ky = 0; ky < 3; ++ky)
          #pragma unroll
          for (int kx = 0; kx < 3; ++kx) {
            float wv = k[o*9 + ky*3 + kx];
            a0 += v[ky][kx+0]*wv;
            a1 += v[ky][kx+1]*wv;
            a2 += v[ky][kx+2]*wv;
            a3 += v[ky][kx+3]*wv;
          }
        uint2 pk;
        pk.x = bfbits(a0) | (bfbits(a1) << 16);
        pk.y = bfbits(a2) | (bfbits(a3) << 16);
        *(uint2*)(c1 + ((size_t)(b*6+o)*HH + h)*EE + wq) = pk;
        float s = a0+a1+a2+a3, q = a0*a0+a1*a1+a2*a2+a3*a3;
        wred2(s, q);
        if (lane == 0) { red[wid][o][0] = s; red[wid][o][1] = q; }
    }
    __syncthreads();
    if (t < 6) {
        float S = 0.f, Q = 0.f;
        #pragma unroll
        for (int wv = 0; wv < 4; ++wv) { S += red[wv][t][0]; Q += red[wv][t][1]; }
        atomicAdd(&mc1[((size_t)b*6 + t)*2],     S);
        atomicAdd(&mc1[((size_t)b*6 + t)*2 + 1], Q);
    }
}

// ---------------------------------------------------------------------------
// K5: conv2 3x3, 6->24 via MFMA implicit GEMM, fused gn1+ReLU+pool staging.
// 2048 blocks. Fused gn2 stats -> mc2.
__global__ __launch_bounds__(256) void k_conv2(
    const bf* __restrict__ c1, const float* __restrict__ mc1,
    const float* __restrict__ g1, const float* __restrict__ be1,
    const float* __restrict__ kw, const float* __restrict__ bias,
    bf* __restrict__ c2, float* __restrict__ mc2)
{
    __shared__ ushortt sA[256*72];     // im2col A; aliased by sC after MFMA
    __shared__ ushortt sW[32*72];
    __shared__ ushortt sP[6*4*136];    // pooled halo tile
    __shared__ float ssl[12];
    __shared__ float redS[24], redQ[24];
    int t = threadIdx.x;
    int ht = blockIdx.x & 31, b = blockIdx.x >> 5;
    int h0 = ht*2;                     // output rows h0, h0+1 (of 64)
    int lane = t & 63, wid = t >> 6;
    if (t < 24) { redS[t] = 0.f; redQ[t] = 0.f; }
    if (t < 6) {
        float s = mc1[((size_t)b*6 + t)*2], q = mc1[((size_t)b*6 + t)*2 + 1];
        float mean = s * (1.f/HP);
        float var  = q * (1.f/HP) - mean*mean;
        float rstd = rsqrtf(var + 1e-5f);
        float sc = g1[t]*rstd;
        ssl[t*2] = sc; ssl[t*2+1] = be1[t] - mean*sc;
    }
    for (int i = t; i < 1152; i += 256) ((unsigned*)sW)[i] = 0;   // zero W pad
    __syncthreads();
    // stage pooled tile (gn1+ReLU+pool): 6 ch x 4 rows x 130 cols
    for (int i = t; i < 3120; i += 256) {
        int c = i / 520, rem = i % 520;
        int ry = rem / 130, rx = rem % 130;
        int gy = h0 - 1 + ry, gx = rx - 1;
        float v = 0.f;
        if (gy >= 0 && gy < H2 && gx >= 0 && gx < W2) {
            const bf* pp = c1 + ((size_t)(b*6+c)*HH + 2*gy)*EE + 2*gx;
            unsigned r0 = *(const unsigned*)pp;
            unsigned r1 = *(const unsigned*)(pp + EE);
            float sc = ssl[c*2], sh = ssl[c*2+1];
            float e0 = fmaxf(b2f(r0 & 0xffff)*sc+sh, 0.f);
            float e1 = fmaxf(b2f(r0 >> 16)   *sc+sh, 0.f);
            float e2 = fmaxf(b2f(r1 & 0xffff)*sc+sh, 0.f);
            float e3 = fmaxf(b2f(r1 >> 16)   *sc+sh, 0.f);
            v = fmaxf(fmaxf(e0,e1), fmaxf(e2,e3));
        }
        sP[c*544 + ry*136 + rx] = (ushortt)bfbits(v);
    }
    // stage W data: kw[o][c][ky][kx] -> sW[o][k=c*9+ky*3+kx]
    for (int e = t; e < 1296; e += 256) {
        int o = e / 54, kk = e % 54;
        sW[o*72 + kk] = (ushortt)bfbits(kw[e]);
    }
    __syncthreads();
    // im2col: thread t -> px (r = t>>7, xx = t&127)
    {
        int r = t >> 7, xx = t & 127;
        unsigned u[32];
        #pragma unroll
        for (int p = 0; p < 27; ++p) {
            int k0 = 2*p, k1 = 2*p + 1;
            int c0 = k0/9, y0 = (k0%9)/3, x0 = k0%3;
            int c1i = k1/9, y1 = (k1%9)/3, x1 = k1%3;
            unsigned lo = sP[c0*544 + (r+y0)*136 + xx + x0];
            unsigned hi = sP[c1i*544 + (r+y1)*136 + xx + x1];
            u[p] = lo | (hi << 16);
        }
        #pragma unroll
        for (int p = 27; p < 32; ++p) u[p] = 0;
        #pragma unroll
        for (int e = 0; e < 8; ++e) {
            uint4 pk; pk.x = u[4*e]; pk.y = u[4*e+1]; pk.z = u[4*e+2]; pk.w = u[4*e+3];
            *(uint4*)&sA[t*72 + e*8] = pk;
        }
    }
    __syncthreads();
    int m = lane & 15, kq = (lane >> 4)*8;
    b8v wv[2][2];
    #pragma unroll
    for (int nt = 0; nt < 2; ++nt)
      #pragma unroll
      for (int ks = 0; ks < 2; ++ks)
        wv[nt][ks] = *(const b8v*)&sW[(nt*16 + m)*72 + ks*32 + kq];
    f4v acc[4][2] = {};
    #pragma unroll
    for (int mt = 0; mt < 4; ++mt) {
        const ushortt* ab = &sA[(wid*64 + mt*16 + m)*72 + kq];
        b8v a0 = *(const b8v*)(ab);
        b8v a1 = *(const b8v*)(ab + 32);
        #pragma unroll
        for (int nt = 0; nt < 2; ++nt) {
            acc[mt][nt] = __builtin_amdgcn_mfma_f32_16x16x32_bf16(a0, wv[nt][0], acc[mt][nt], 0, 0, 0);
            acc[mt][nt] = __builtin_amdgcn_mfma_f32_16x16x32_bf16(a1, wv[nt][1], acc[mt][nt], 0, 0, 0);
        }
    }
    __syncthreads();
    // C staging: sC[o][r(2)][x(128)]: stride o*272 + r*136 + x
    ushortt* sC = sA;
    int q4 = lane >> 4;
    #pragma unroll
    for (int mt = 0; mt < 4; ++mt) {
        int pxb = wid*64 + mt*16 + q4*4;
        #pragma unroll
        for (int nt = 0; nt < 2; ++nt) {
            int o = nt*16 + m;
            if (o < 24) {
                float bo = bias[o];
                #pragma unroll
                for (int r = 0; r < 4; ++r) {
                    int px = pxb + r;
                    sC[o*272 + (px >> 7)*136 + (px & 127)] =
                        (ushortt)bfbits(acc[mt][nt][r] + bo);
                }
            }
        }
    }
    __syncthreads();
    // coalesced writeback + gn2 stats (o constant per 32 consecutive lanes)
    #pragma unroll
    for (int j = 0; j < 3; ++j) {
        int idx = j*256 + t;               // 768 uint4 chunks
        int o = idx >> 5;
        int rem = idx & 31;
        int r = rem >> 4, x8 = (rem & 15)*8;
        uint4 v = *(const uint4*)&sC[o*272 + r*136 + x8];
        *(uint4*)(c2 + ((size_t)(b*24+o)*H2 + h0 + r)*W2 + x8) = v;
        float v0 = b2f(v.x & 0xffff), v1 = b2f(v.x >> 16);
        float v2 = b2f(v.y & 0xffff), v3 = b2f(v.y >> 16);
        float v4 = b2f(v.z & 0xffff), v5 = b2f(v.z >> 16);
        float v6 = b2f(v.w & 0xffff), v7 = b2f(v.w >> 16);
        float s = v0+v1+v2+v3+v4+v5+v6+v7;
        float qv = v0*v0+v1*v1+v2*v2+v3*v3+v4*v4+v5*v5+v6*v6+v7*v7;
        wred2_32(s, qv);
        if ((lane & 31) == 0) { atomicAdd(&redS[o], s); atomicAdd(&redQ[o], qv); }
    }
    __syncthreads();
    if (t < 24) {
        atomicAdd(&mc2[((size_t)b*24 + t)*2],     redS[t]);
        atomicAdd(&mc2[((size_t)b*24 + t)*2 + 1], redQ[t]);
    }
}

// ---------------------------------------------------------------------------
// K8: tconv3 2x2 s2, 24->24 via MFMA, fused gn2+ReLU+pool+SiLU staging from c2.
// 512 blocks.
__global__ __launch_bounds__(256) void k_tconv3(
    const bf* __restrict__ c2, const float* __restrict__ mc2,
    const float* __restrict__ g2, const float* __restrict__ be2,
    const float* __restrict__ k3, const float* __restrict__ b3,
    bf* __restrict__ u3, float* __restrict__ mu3)
{
    __shared__ ushortt sBuf[27648];       // A[256*40] + W[96*40] aliased by C[24*1152]
    __shared__ float redS[24], redQ[24];
    __shared__ float ssl[48];
    ushortt* sA = sBuf;
    ushortt* sW = sBuf + 10240;
    int t = threadIdx.x;
    int b = blockIdx.x >> 3, pg = blockIdx.x & 7;
    int lane = t & 63, wid = t >> 6;
    if (t < 24) {
        redS[t] = 0.f; redQ[t] = 0.f;
        float s = mc2[((size_t)b*24 + t)*2], q = mc2[((size_t)b*24 + t)*2 + 1];
        float mean = s * (1.f/PL2);
        float var  = q * (1.f/PL2) - mean*mean;
        float rstd = rsqrtf(var + 1e-5f);
        float sc = g2[t]*rstd;
        ssl[t*2] = sc; ssl[t*2+1] = be2[t] - mean*sc;
    }
    // stage W: k3[c][o][dq] -> sW[n=o*4+dq][kpad=c]
    #pragma unroll
    for (int j = 0; j < 9; ++j) {
        int e = j*256 + t;
        int c = e / 96, n = e % 96;
        sW[n*40 + c] = (ushortt)bfbits(k3[e]);
    }
    if (t < 96) { uint4 z = {0,0,0,0}; *(uint4*)&sW[t*40 + 24] = z; }
    { uint4 z = {0,0,0,0}; *(uint4*)&sA[t*40 + 24] = z; }   // zero A k-pad
    __syncthreads();
    // stage A: item = (c, px-pair). 24*128 = 3072 items, uint2 loads.
    #pragma unroll
    for (int j = 0; j < 12; ++j) {
        int i = j*256 + t;
        int c = i >> 7, pr = i & 127;
        int px0 = pr*2;
        int h4 = (pg*256 + px0) >> 6, w4 = px0 & 63;     // w4 even
        const bf* pp = c2 + ((size_t)b*24 + c)*PL2 + (size_t)(2*h4)*W2 + 2*w4;
        uint2 r0 = *(const uint2*)pp;
        uint2 r1 = *(const uint2*)(pp + W2);
        float sc = ssl[c*2], sh = ssl[c*2+1];
        float e0 = fmaxf(b2f(r0.x & 0xffff)*sc+sh, 0.f);
        float e1 = fmaxf(b2f(r0.x >> 16)   *sc+sh, 0.f);
        float f0 = fmaxf(b2f(r1.x & 0xffff)*sc+sh, 0.f);
        float f1 = fmaxf(b2f(r1.x >> 16)   *sc+sh, 0.f);
        float m0 = fmaxf(fmaxf(e0,e1), fmaxf(f0,f1));
        m0 = m0 / (1.f + expf(-m0));
        float e2 = fmaxf(b2f(r0.y & 0xffff)*sc+sh, 0.f);
        float e3 = fmaxf(b2f(r0.y >> 16)   *sc+sh, 0.f);
        float f2 = fmaxf(b2f(r1.y & 0xffff)*sc+sh, 0.f);
        float f3 = fmaxf(b2f(r1.y >> 16)   *sc+sh, 0.f);
        float m1 = fmaxf(fmaxf(e2,e3), fmaxf(f2,f3));
        m1 = m1 / (1.f + expf(-m1));
        sA[px0*40 + c]     = (ushortt)bfbits(m0);
        sA[(px0+1)*40 + c] = (ushortt)bfbits(m1);
    }
    __syncthreads();
    int m = lane & 15, kq = (lane >> 4)*8;
    b8v wv[6];
    #pragma unroll
    for (int nt = 0; nt < 6; ++nt)
        wv[nt] = *(const b8v*)&sW[(nt*16 + m)*40 + kq];
    f4v acc[4][6] = {};
    #pragma unroll
    for (int mt = 0; mt < 4; ++mt) {
        b8v av = *(const b8v*)&sA[(wid*64 + mt*16 + m)*40 + kq];
        #pragma unroll
        for (int nt = 0; nt < 6; ++nt)
            acc[mt][nt] = __builtin_amdgcn_mfma_f32_16x16x32_bf16(av, wv[nt], acc[mt][nt], 0, 0, 0);
    }
    __syncthreads();
    // C staging: sC[o][yl(8)][x(128)] row stride 144, o stride 1152
    ushortt* sC = sBuf;
    int q4 = lane >> 4;
    #pragma unroll
    for (int mt = 0; mt < 4; ++mt) {
        int pxb = wid*64 + mt*16 + q4*4;
        #pragma unroll
        for (int nt = 0; nt < 6; ++nt) {
            int n = nt*16 + m;
            int o = n >> 2, d = (n >> 1) & 1, qq = n & 1;
            float bo = b3[o];
            #pragma unroll
            for (int r = 0; r < 4; ++r) {
                int px = pxb + r;
                int yl = ((px >> 6) << 1) + d;
                int xx = ((px & 63) << 1) + qq;
                sC[o*1152 + yl*144 + xx] = (ushortt)bfbits(acc[mt][nt][r] + bo);
            }
        }
    }
    __syncthreads();
    bf* outb = u3 + (size_t)b*24*PL2;
    #pragma unroll
    for (int j = 0; j < 12; ++j) {
        int idx = j*256 + t;
        int o = idx >> 7;
        int rem = idx & 127;
        int yl = rem >> 4, xc = (rem & 15)*8;
        uint4 v = *(const uint4*)&sC[o*1152 + yl*144 + xc];
        *(uint4*)(outb + ((size_t)o*H2 + pg*8 + yl)*W2 + xc) = v;
        float v0 = b2f(v.x & 0xffff), v1 = b2f(v.x >> 16);
        float v2 = b2f(v.y & 0xffff), v3 = b2f(v.y >> 16);
        float v4 = b2f(v.z & 0xffff), v5 = b2f(v.z >> 16);
        float v6 = b2f(v.w & 0xffff), v7 = b2f(v.w >> 16);
        float s = v0+v1+v2+v3+v4+v5+v6+v7;
        float qv = v0*v0+v1*v1+v2*v2+v3*v3+v4*v4+v5*v5+v6*v6+v7*v7;
        wred2(s, qv);
        if (lane == 0) { atomicAdd(&redS[o], s); atomicAdd(&redQ[o], qv); }
    }
    __syncthreads();
    if (t < 24) {
        atomicAdd(&mu3[((size_t)b*24 + t)*2],     redS[t]);
        atomicAdd(&mu3[((size_t)b*24 + t)*2 + 1], redQ[t]);
    }
}

// ---------------------------------------------------------------------------
// K10: gn3-fused tconv4 2x2 s2, 48->12 via MFMA. gn3 prologue from mc2+mu3.
// 2048 blocks.
__global__ __launch_bounds__(256) void k_tconv4(
    const bf* __restrict__ c2, const bf* __restrict__ u3,
    const float* __restrict__ mc2, const float* __restrict__ mu3,
    const float* __restrict__ g3, const float* __restrict__ be3,
    const float* __restrict__ k4, const float* __restrict__ bias4,
    bf* __restrict__ u4, float* __restrict__ mu4)
{
    __shared__ ushortt sA[256*72];
    __shared__ ushortt sW[48*72];
    __shared__ float redS[12], redQ[12];
    __shared__ float ssl[96];
    int t = threadIdx.x;
    int b = blockIdx.x >> 5, pg = blockIdx.x & 31;
    int lane = t & 63, wid = t >> 6;
    if (t < 12) { redS[t] = 0.f; redQ[t] = 0.f; }
    if (t < 6) {
        float s = 0.f, q = 0.f;
        #pragma unroll
        for (int cl = 0; cl < 8; ++cl) {
            int gc = t*8 + cl;
            const float* p = (gc < 24) ? mc2 + ((size_t)b*24 + gc)*2
                                       : mu3 + ((size_t)b*24 + gc - 24)*2;
            s += p[0]; q += p[1];
        }
        float inv_n = 1.f/((float)PL2*8.f);
        float mean = s*inv_n;
        float var  = q*inv_n - mean*mean;
        float rstd = rsqrtf(var + 1e-5f);
        #pragma unroll
        for (int cl = 0; cl < 8; ++cl) {
            int gc = t*8 + cl;
            float sc = g3[gc]*rstd;
            ssl[gc*2] = sc; ssl[gc*2+1] = be3[gc] - mean*sc;
        }
    }
    #pragma unroll
    for (int j = 0; j < 9; ++j) {
        int e = j*256 + t;
        if (e < 2304) {
            int c = e / 48, n = e % 48;
            sW[n*72 + c] = (ushortt)bfbits(k4[e]);
        }
    }
    if (t < 96) {
        uint4 z = {0,0,0,0};
        int n = t >> 1, c0 = 48 + (t & 1)*8;
        *(uint4*)&sW[n*72 + c0] = z;
    }
    __syncthreads();
    {
        int pix = pg*256 + t;
        const bf* c2p = c2 + (size_t)b*24*PL2 + pix;
        const bf* u3p = u3 + (size_t)b*24*PL2 + pix;
        ushortt* row = &sA[t*72];
        #pragma unroll
        for (int g = 0; g < 6; ++g) {
            unsigned pr[4];
            #pragma unroll
            for (int hc = 0; hc < 4; ++hc) {
                int c0 = g*8 + hc*2;
                float r0 = (c0 < 24) ? tof(c2p[(size_t)c0*PL2]) : tof(u3p[(size_t)(c0-24)*PL2]);
                float r1 = (c0+1 < 24) ? tof(c2p[(size_t)(c0+1)*PL2]) : tof(u3p[(size_t)(c0+1-24)*PL2]);
                float v0 = r0 * ssl[2*c0]   + ssl[2*c0+1];
                float v1 = r1 * ssl[2*c0+2] + ssl[2*c0+3];
                pr[hc] = bfbits(v0) | (bfbits(v1) << 16);
            }
            uint4 pk; pk.x = pr[0]; pk.y = pr[1]; pk.z = pr[2]; pk.w = pr[3];
            *(uint4*)&row[g*8] = pk;
        }
        uint4 z = {0,0,0,0};
        *(uint4*)&row[48] = z;
        *(uint4*)&row[56] = z;
    }
    __syncthreads();
    int m = lane & 15, kq = (lane >> 4)*8;
    b8v bfr[3][2];
    #pragma unroll
    for (int nt = 0; nt < 3; ++nt)
      #pragma unroll
      for (int ks = 0; ks < 2; ++ks)
        bfr[nt][ks] = *(const b8v*)&sW[(nt*16 + m)*72 + ks*32 + kq];
    f4v acc[4][3] = {};
    #pragma unroll
    for (int mt = 0; mt < 4; ++mt) {
        const ushortt* ab = &sA[(wid*64 + mt*16 + m)*72 + kq];
        b8v a0 = *(const b8v*)(ab);
        b8v a1 = *(const b8v*)(ab + 32);
        #pragma unroll
        for (int nt = 0; nt < 3; ++nt) {
            acc[mt][nt] = __builtin_amdgcn_mfma_f32_16x16x32_bf16(a0, bfr[nt][0], acc[mt][nt], 0, 0, 0);
            acc[mt][nt] = __builtin_amdgcn_mfma_f32_16x16x32_bf16(a1, bfr[nt][1], acc[mt][nt], 0, 0, 0);
        }
    }
    __syncthreads();
    ushortt* sC = sA;
    int q4 = lane >> 4;
    #pragma unroll
    for (int mt = 0; mt < 4; ++mt) {
        int pxb = wid*64 + mt*16 + q4*4;
        #pragma unroll
        for (int nt = 0; nt < 3; ++nt) {
            int n = nt*16 + m;
            int o = n >> 2, d = (n >> 1) & 1, qq = n & 1;
            float bo = bias4[o];
            #pragma unroll
            for (int r = 0; r < 4; ++r) {
                int px = pxb + r;
                int yl = ((px >> 7) << 1) + d;
                int xx = ((px & 127) << 1) + qq;
                sC[o*1024 + yl*256 + xx] = (ushortt)bfbits(acc[mt][nt][r] + bo);
            }
        }
    }
    __syncthreads();
    {
        bf* outb = u4 + (size_t)b*12*HP;
        #pragma unroll
        for (int j = 0; j < 6; ++j) {
            int idx16 = j*256 + t;
            int el = idx16*8;
            int o = el >> 10, rem = el & 1023, yl = rem >> 8, x0 = rem & 255;
            uint4 v = *(const uint4*)&sC[el];
            *(uint4*)(outb + ((size_t)o*HH + pg*4 + yl)*EE + x0) = v;
            float v0 = b2f(v.x & 0xffff), v1 = b2f(v.x >> 16);
            float v2 = b2f(v.y & 0xffff), v3 = b2f(v.y >> 16);
            float v4 = b2f(v.z & 0xffff), v5 = b2f(v.z >> 16);
            float v6 = b2f(v.w & 0xffff), v7 = b2f(v.w >> 16);
            float s = v0+v1+v2+v3+v4+v5+v6+v7;
            float qv = v0*v0+v1*v1+v2*v2+v3*v3+v4*v4+v5*v5+v6*v6+v7*v7;
            wred2(s, qv);
            if (lane == 0) { atomicAdd(&redS[o], s); atomicAdd(&redQ[o], qv); }
        }
    }
    __syncthreads();
    if (t < 12) {
        atomicAdd(&mu4[((size_t)b*12 + t)*2],     redS[t]);
        atomicAdd(&mu4[((size_t)b*12 + t)*2 + 1], redQ[t]);
    }
}

// ---------------------------------------------------------------------------
// K12: gn4-fused 1x1 conv 18->6. gn4 prologue from mc1+mu4. 8 px/thread,
// uint4 loads/stores. Fused u5 stats. 1024 blocks.
__global__ __launch_bounds__(256) void k_conv1x1_u5(
    const bf* __restrict__ c1, const bf* __restrict__ u4,
    const float* __restrict__ mc1, const float* __restrict__ mu4,
    const float* __restrict__ g4, const float* __restrict__ be4,
    const float* __restrict__ k, const float* __restrict__ bias,
    bf* __restrict__ u5, float* __restrict__ mu5)
{
    __shared__ float red[4][6][2];
    __shared__ float ssl[36];
    int t = threadIdx.x;
    int b  = blockIdx.x >> 4;
    int pg = blockIdx.x & 15;
    int pix = pg*2048 + t*8;
    int lane = t & 63, wid = t >> 6;
    if (t < 6) {
        float s = 0.f, q = 0.f;
        #pragma unroll
        for (int cl = 0; cl < 3; ++cl) {
            int gc = t*3 + cl;
            const float* p = (gc < 6) ? mc1 + ((size_t)b*6 + gc)*2
                                      : mu4 + ((size_t)b*12 + gc - 6)*2;
            s += p[0]; q += p[1];
        }
        float inv_n = 1.f/((float)HP*3.f);
        float mean = s*inv_n;
        float var  = q*inv_n - mean*mean;
        float rstd = rsqrtf(var + 1e-5f);
        #pragma unroll
        for (int cl = 0; cl < 3; ++cl) {
            int gc = t*3 + cl;
            float sc = g4[gc]*rstd;
            ssl[gc*2] = sc; ssl[gc*2+1] = be4[gc] - mean*sc;
        }
    }
    __syncthreads();
    const bf* c1p = c1 + ((size_t)b*6)*HP + pix;
    const bf* u4p = u4 + ((size_t)b*12)*HP + pix;
    float acc[6][8];
    #pragma unroll
    for (int o = 0; o < 6; ++o) {
        float bv = bias[o];
        #pragma unroll
        for (int j = 0; j < 8; ++j) acc[o][j] = bv;
    }
    #pragma unroll
    for (int c = 0; c < 18; ++c) {
        uint4 r = (c < 6) ? *(const uint4*)(c1p + (size_t)c*HP)
                          : *(const uint4*)(u4p + (size_t)(c-6)*HP);
        float sc = ssl[2*c], sh = ssl[2*c+1];
        float v[8];
        v[0] = b2f(r.x & 0xffff)*sc + sh;  v[1] = b2f(r.x >> 16)*sc + sh;
        v[2] = b2f(r.y & 0xffff)*sc + sh;  v[3] = b2f(r.y >> 16)*sc + sh;
        v[4] = b2f(r.z & 0xffff)*sc + sh;  v[5] = b2f(r.z >> 16)*sc + sh;
        v[6] = b2f(r.w & 0xffff)*sc + sh;  v[7] = b2f(r.w >> 16)*sc + sh;
        #pragma unroll
        for (int o = 0; o < 6; ++o) {
            float wv = k[o*18 + c];
            #pragma unroll
            for (int j = 0; j < 8; ++j) acc[o][j] += v[j]*wv;
        }
    }
    #pragma unroll
    for (int o = 0; o < 6; ++o) {
        uint4 pk;
        pk.x = bfbits(acc[o][0]) | (bfbits(acc[o][1]) << 16);
        pk.y = bfbits(acc[o][2]) | (bfbits(acc[o][3]) << 16);
        pk.z = bfbits(acc[o][4]) | (bfbits(acc[o][5]) << 16);
        pk.w = bfbits(acc[o][6]) | (bfbits(acc[o][7]) << 16);
        *(uint4*)(u5 + ((size_t)(b*6+o))*HP + pix) = pk;
        float s = 0.f, q = 0.f;
        #pragma unroll
        for (int j = 0; j < 8; ++j) { s += acc[o][j]; q += acc[o][j]*acc[o][j]; }
        wred2(s, q);
        if (lane == 0) { red[wid][o][0] = s; red[wid][o][1] = q; }
    }
    __syncthreads();
    if (t < 6) {
        float S = 0.f, Q = 0.f;
        #pragma unroll
        for (int wv = 0; wv < 4; ++wv) { S += red[wv][t][0]; Q += red[wv][t][1]; }
        atomicAdd(&mu5[((size_t)b*6 + t)*2],     S);
        atomicAdd(&mu5[((size_t)b*6 + t)*2 + 1], Q);
    }
}

// ---------------------------------------------------------------------------
// K14: gn5-fused final 1x1 conv (6->1) + divide by std(t). gn5 in prologue.
// 8 px/thread, uint4 loads, 2x float4 stores. 1024 blocks.
__global__ __launch_bounds__(256) void k_final(
    const bf* __restrict__ u5, const float* __restrict__ mu5,
    const float* __restrict__ g5, const float* __restrict__ be5,
    const float* __restrict__ k, const float* __restrict__ bias,
    const float* __restrict__ t, float* __restrict__ out)
{
    __shared__ float ssl[12];
    int tt = threadIdx.x;
    int b = blockIdx.x >> 4;
    int pix = ((blockIdx.x & 15)*256 + tt)*8;
    if (tt < 6) {
        float s = mu5[((size_t)b*6 + tt)*2], q = mu5[((size_t)b*6 + tt)*2 + 1];
        float mean = s * (1.f/HP);
        float var  = q * (1.f/HP) - mean*mean;
        float rstd = rsqrtf(var + 1e-5f);
        float sc = g5[tt]*rstd;
        ssl[tt*2] = sc; ssl[tt*2+1] = be5[tt] - mean*sc;
    }
    __syncthreads();
    const bf* up = u5 + (size_t)b*6*HP + pix;
    float bv = bias[0];
    float a[8];
    #pragma unroll
    for (int j = 0; j < 8; ++j) a[j] = bv;
    #pragma unroll
    for (int c = 0; c < 6; ++c) {
        uint4 r = *(const uint4*)(up + (size_t)c*HP);
        float sc = ssl[2*c], sh = ssl[2*c+1];
        float wv = k[c];
        a[0] += (b2f(r.x & 0xffff)*sc + sh) * wv;
        a[1] += (b2f(r.x >> 16)   *sc + sh) * wv;
        a[2] += (b2f(r.y & 0xffff)*sc + sh) * wv;
        a[3] += (b2f(r.y >> 16)   *sc + sh) * wv;
        a[4] += (b2f(r.z & 0xffff)*sc + sh) * wv;
        a[5] += (b2f(r.z >> 16)   *sc + sh) * wv;
        a[6] += (b2f(r.w & 0xffff)*sc + sh) * wv;
        a[7] += (b2f(r.w >> 16)   *sc + sh) * wv;
    }
    float tb = t[b];
    const float lns = 3.2188758248682007492f;
    float var = (expf(2.f*tb*lns) - 1.f) / (2.f*lns);
    float rs = rsqrtf(var);
    float4 o0; o0.x = a[0]*rs; o0.y = a[1]*rs; o0.z = a[2]*rs; o0.w = a[3]*rs;
    float4 o1; o1.x = a[4]*rs; o1.y = a[5]*rs; o1.z = a[6]*rs; o1.w = a[7]*rs;
    float* op = out + (size_t)b*HP + pix;
    *(float4*)op       = o0;
    *(float4*)(op + 4) = o1;
}

// ---------------------------------------------------------------------------
extern "C" void kernel_launch(void* const* d_in, const int* in_sizes, int n_in,
                              void* d_out, int out_size, void* d_ws, size_t ws_size,
                              hipStream_t stream)
{
    const float* x       = (const float*)d_in[0];
    const float* t       = (const float*)d_in[1];
    const float* Wf      = (const float*)d_in[2];
    const float* fc1_w   = (const float*)d_in[3];
    const float* fc1_b   = (const float*)d_in[4];
    const float* conv1_k = (const float*)d_in[5];
    const float* conv1_b = (const float*)d_in[6];
    const float* gn1_g   = (const float*)d_in[7];
    const float* gn1_b   = (const float*)d_in[8];
    const float* conv2_k = (const float*)d_in[9];
    const float* conv2_b = (const float*)d_in[10];
    const float* gn2_g   = (const float*)d_in[11];
    const float* gn2_b   = (const float*)d_in[12];
    const float* t3_k    = (const float*)d_in[13];
    const float* t3_b    = (const float*)d_in[14];
    const float* gn3_g   = (const float*)d_in[15];
    const float* gn3_b   = (const float*)d_in[16];
    const float* t4_k    = (const float*)d_in[17];
    const float* t4_b    = (const float*)d_in[18];
    const float* gn4_g   = (const float*)d_in[19];
    const float* gn4_b   = (const float*)d_in[20];
    const float* t5_k    = (const float*)d_in[21];
    const float* t5_b    = (const float*)d_in[22];
    const float* gn5_g   = (const float*)d_in[23];
    const float* gn5_b   = (const float*)d_in[24];
    const float* fin_k   = (const float*)d_in[25];
    const float* fin_b   = (const float*)d_in[26];

    bf* wsb = (bf*)d_ws;
    bf* c1 = wsb;                          // conv1..conv1x1
    bf* c2 = wsb + 12582912;               // conv2..tconv4
    bf* u3 = wsb + 25165824;               // tconv3..tconv4
    bf* u4 = wsb + 37748736;               // tconv4..conv1x1
    bf* xf = wsb + 39845888;               // fc1..conv1 (in u4 region)
    bf* u5 = wsb + 12582912;               // reuses c2, conv1x1..final
    float* mb = (float*)(wsb + 62914560);  // raw channel sums
    float* mc1 = mb;            // 768
    float* mc2 = mb + 768;      // 3072
    float* mu3 = mb + 3840;     // 3072
    float* mu4 = mb + 6912;     // 1536
    float* mu5 = mb + 8448;     // 768

    k_fourier_fc1<<<512, 256, 0, stream>>>(x, Wf, fc1_w, fc1_b, xf, mb);
    k_conv1<<<2048, 256, 0, stream>>>(xf, conv1_k, conv1_b, c1, mc1);
    k_conv2<<<2048, 256, 0, stream>>>(c1, mc1, gn1_g, gn1_b,
                                      conv2_k, conv2_b, c2, mc2);
    k_tconv3<<<512, 256, 0, stream>>>(c2, mc2, gn2_g, gn2_b,
                                      t3_k, t3_b, u3, mu3);
    k_tconv4<<<2048, 256, 0, stream>>>(c2, u3, mc2, mu3, gn3_g, gn3_b,
                                       t4_k, t4_b, u4, mu4);
    k_conv1x1_u5<<<1024, 256, 0, stream>>>(c1, u4, mc1, mu4, gn4_g, gn4_b,
                                           t5_k, t5_b, u5, mu5);
    k_final<<<1024, 256, 0, stream>>>(u5, mu5, gn5_g, gn5_b,
                                      fin_k, fin_b, t, (float*)d_out);
}

// Round 12
// 236.561 us; speedup vs baseline: 5.2804x; 1.0514x over previous
//
#include <hip/hip_runtime.h>
#include <hip/hip_bf16.h>
#include <math.h>

#define BB 64
#define HH 128
#define WW 128
#define EE 256
#define HP (HH*EE)        // 32768
#define H2 64
#define W2 128
#define PL2 (H2*W2)       // 8192
#define H4 32
#define W4 64
#define PL4 (H4*W4)       // 2048

typedef __hip_bfloat16 bf;
typedef unsigned short ushortt;
typedef __attribute__((ext_vector_type(8))) __bf16 b8v;
typedef __attribute__((ext_vector_type(4))) float f4v;

__device__ __forceinline__ float tof(bf v)    { return __bfloat162float(v); }
__device__ __forceinline__ bf    tob(float v) { return __float2bfloat16(v); }
__device__ __forceinline__ unsigned int bfbits(float v) {
    return (unsigned int)__builtin_bit_cast(ushortt, __float2bfloat16(v));
}
__device__ __forceinline__ float b2f(unsigned int u16) {
    unsigned int x = u16 << 16;
    return __builtin_bit_cast(float, x);
}
__device__ __forceinline__ void wred2(float& s, float& q) {
    #pragma unroll
    for (int m = 32; m; m >>= 1) {
        s += __shfl_xor(s, m);
        q += __shfl_xor(q, m);
    }
}
__device__ __forceinline__ void wred2_32(float& s, float& q) {
    #pragma unroll
    for (int m = 16; m; m >>= 1) {
        s += __shfl_xor(s, m);
        q += __shfl_xor(q, m);
    }
}

// ---------------------------------------------------------------------------
// K1: fused Fourier features + fc1 GEMM via MFMA. 512 blocks.
// Prologue grid-stride zeroes the stats buffer (mb, 9216 floats).
__global__ __launch_bounds__(256) void k_fourier_fc1(
    const float* __restrict__ x, const float* __restrict__ Wf,
    const float* __restrict__ fc1_w, const float* __restrict__ fc1_b,
    bf* __restrict__ xf, float* __restrict__ mb)
{
    __shared__ ushortt sA[64*264];
    __shared__ ushortt sB[64*264];
    int t = threadIdx.x;
    for (int i = blockIdx.x*256 + t; i < 9216; i += 512*256) mb[i] = 0.f;
    int rb = blockIdx.x >> 2, cb = blockIdx.x & 3;
    int row0 = rb*64, col0 = cb*64;
    const float TP = 6.2831853071795864769f;
    for (int it = 0; it < 32; ++it) {       // 8192 = 64 rows x 128 w
        int i = it*256 + t;
        int r = i >> 7, w = i & 127;
        int rg = row0 + r;
        float p = x[(size_t)rg*WW + w] * Wf[(size_t)(rg & (HH-1))*WW + w] * TP;
        sA[r*264 + w]       = (ushortt)bfbits(__sinf(p));
        sA[r*264 + 128 + w] = (ushortt)bfbits(__cosf(p));
    }
    #pragma unroll
    for (int it = 0; it < 16; ++it) {       // B: fp32 -> bf16
        int i = it*256 + t;
        int o = i >> 6, c4 = i & 63;
        float4 w4 = *(const float4*)(fc1_w + (size_t)(col0 + o)*EE + c4*4);
        uint2 pk;
        pk.x = bfbits(w4.x) | (bfbits(w4.y) << 16);
        pk.y = bfbits(w4.z) | (bfbits(w4.w) << 16);
        *(uint2*)&sB[o*264 + c4*4] = pk;
    }
    __syncthreads();
    int lane = t & 63, wid = t >> 6;
    int m = lane & 15, kq = (lane >> 4) * 8;
    f4v acc[4] = {};
    const ushortt* aBase = &sA[(wid*16 + m)*264 + kq];
    #pragma unroll
    for (int k0 = 0; k0 < 8; ++k0) {
        b8v av = *(const b8v*)(aBase + k0*32);
        #pragma unroll
        for (int t4 = 0; t4 < 4; ++t4) {
            b8v bv = *(const b8v*)&sB[(t4*16 + m)*264 + k0*32 + kq];
            acc[t4] = __builtin_amdgcn_mfma_f32_16x16x32_bf16(av, bv, acc[t4], 0, 0, 0);
        }
    }
    int rbase = row0 + wid*16 + (lane >> 4)*4;
    #pragma unroll
    for (int t4 = 0; t4 < 4; ++t4) {
        int col = col0 + t4*16 + m;
        float bias = fc1_b[col];
        #pragma unroll
        for (int r = 0; r < 4; ++r)
            xf[(size_t)(rbase + r)*EE + col] = tob(acc[t4][r] + bias);
    }
}

// ---------------------------------------------------------------------------
// K2: conv1 3x3, 1->6, LDS-staged rows, 4 px/thread. 2048 blocks. Fused gn1 stats.
__global__ __launch_bounds__(256) void k_conv1(
    const bf* __restrict__ xf, const float* __restrict__ k,
    const float* __restrict__ bias, bf* __restrict__ c1, float* __restrict__ mc1)
{
    __shared__ ushortt sT[6*272];    // 6 rows, data at [8..263], zero halos
    __shared__ float red[4][6][2];
    int t = threadIdx.x;
    int ht = blockIdx.x & 31, b = blockIdx.x >> 5;
    int h0 = ht*4;
    const bf* src = xf + (size_t)b*HP;
    if (t < 192) {
        int r = t >> 5, i = t & 31;
        int gy = h0 - 1 + r;
        uint4 v = {0,0,0,0};
        if (gy >= 0 && gy < HH) v = *(const uint4*)(src + (size_t)gy*EE + i*8);
        *(uint4*)&sT[r*272 + 8 + i*8] = v;
    } else if (t < 204) {
        int e = t - 192;
        int r = e >> 1, s = e & 1;
        uint4 z = {0,0,0,0};
        *(uint4*)&sT[r*272 + s*264] = z;
    }
    __syncthreads();
    int wq = (t & 63)*4, hl = t >> 6;
    int lane = t & 63, wid = t >> 6;
    float v[3][6];
    #pragma unroll
    for (int ky = 0; ky < 3; ++ky)
      #pragma unroll
      for (int j = 0; j < 6; ++j)
        v[ky][j] = b2f((unsigned)sT[(hl+ky)*272 + 7 + wq + j]);
    int h = h0 + hl;
    #pragma unroll
    for (int o = 0; o < 6; ++o) {
        float bv = bias[o];
        float a0=bv, a1=bv, a2=bv, a3=bv;
        #pragma unroll
        for (int ky = 0; ky < 3; ++ky)
          #pragma unroll
          for (int kx = 0; kx < 3; ++kx) {
            float wv = k[o*9 + ky*3 + kx];
            a0 += v[ky][kx+0]*wv;
            a1 += v[ky][kx+1]*wv;
            a2 += v[ky][kx+2]*wv;
            a3 += v[ky][kx+3]*wv;
          }
        uint2 pk;
        pk.x = bfbits(a0) | (bfbits(a1) << 16);
        pk.y = bfbits(a2) | (bfbits(a3) << 16);
        *(uint2*)(c1 + ((size_t)(b*6+o)*HH + h)*EE + wq) = pk;
        float s = a0+a1+a2+a3, q = a0*a0+a1*a1+a2*a2+a3*a3;
        wred2(s, q);
        if (lane == 0) { red[wid][o][0] = s; red[wid][o][1] = q; }
    }
    __syncthreads();
    if (t < 6) {
        float S = 0.f, Q = 0.f;
        #pragma unroll
        for (int wv = 0; wv < 4; ++wv) { S += red[wv][t][0]; Q += red[wv][t][1]; }
        atomicAdd(&mc1[((size_t)b*6 + t)*2],     S);
        atomicAdd(&mc1[((size_t)b*6 + t)*2 + 1], Q);
    }
}

// ---------------------------------------------------------------------------
// K5: conv2 3x3, 6->24 via MFMA implicit GEMM, fused gn1+ReLU+pool staging.
// 2048 blocks. Fused gn2 stats -> mc2.
__global__ __launch_bounds__(256) void k_conv2(
    const bf* __restrict__ c1, const float* __restrict__ mc1,
    const float* __restrict__ g1, const float* __restrict__ be1,
    const float* __restrict__ kw, const float* __restrict__ bias,
    bf* __restrict__ c2, float* __restrict__ mc2)
{
    __shared__ ushortt sA[256*72];     // im2col A; aliased by sC after MFMA
    __shared__ ushortt sW[32*72];
    __shared__ ushortt sP[6*4*136];    // pooled halo tile
    __shared__ float ssl[12];
    __shared__ float redS[24], redQ[24];
    int t = threadIdx.x;
    int ht = blockIdx.x & 31, b = blockIdx.x >> 5;
    int h0 = ht*2;                     // output rows h0, h0+1 (of 64)
    int lane = t & 63, wid = t >> 6;
    if (t < 24) { redS[t] = 0.f; redQ[t] = 0.f; }
    if (t < 6) {
        float s = mc1[((size_t)b*6 + t)*2], q = mc1[((size_t)b*6 + t)*2 + 1];
        float mean = s * (1.f/HP);
        float var  = q * (1.f/HP) - mean*mean;
        float rstd = rsqrtf(var + 1e-5f);
        float sc = g1[t]*rstd;
        ssl[t*2] = sc; ssl[t*2+1] = be1[t] - mean*sc;
    }
    for (int i = t; i < 1152; i += 256) ((unsigned*)sW)[i] = 0;   // zero W pad
    __syncthreads();
    // stage pooled tile (gn1+ReLU+pool): 6 ch x 4 rows x 130 cols
    for (int i = t; i < 3120; i += 256) {
        int c = i / 520, rem = i % 520;
        int ry = rem / 130, rx = rem % 130;
        int gy = h0 - 1 + ry, gx = rx - 1;
        float v = 0.f;
        if (gy >= 0 && gy < H2 && gx >= 0 && gx < W2) {
            const bf* pp = c1 + ((size_t)(b*6+c)*HH + 2*gy)*EE + 2*gx;
            unsigned r0 = *(const unsigned*)pp;
            unsigned r1 = *(const unsigned*)(pp + EE);
            float sc = ssl[c*2], sh = ssl[c*2+1];
            float e0 = fmaxf(b2f(r0 & 0xffff)*sc+sh, 0.f);
            float e1 = fmaxf(b2f(r0 >> 16)   *sc+sh, 0.f);
            float e2 = fmaxf(b2f(r1 & 0xffff)*sc+sh, 0.f);
            float e3 = fmaxf(b2f(r1 >> 16)   *sc+sh, 0.f);
            v = fmaxf(fmaxf(e0,e1), fmaxf(e2,e3));
        }
        sP[c*544 + ry*136 + rx] = (ushortt)bfbits(v);
    }
    // stage W data: kw[o][c][ky][kx] -> sW[o][k=c*9+ky*3+kx]
    for (int e = t; e < 1296; e += 256) {
        int o = e / 54, kk = e % 54;
        sW[o*72 + kk] = (ushortt)bfbits(kw[e]);
    }
    __syncthreads();
    // im2col: thread t -> px (r = t>>7, xx = t&127)
    {
        int r = t >> 7, xx = t & 127;
        unsigned u[32];
        #pragma unroll
        for (int p = 0; p < 27; ++p) {
            int k0 = 2*p, k1 = 2*p + 1;
            int c0 = k0/9, y0 = (k0%9)/3, x0 = k0%3;
            int c1i = k1/9, y1 = (k1%9)/3, x1 = k1%3;
            unsigned lo = sP[c0*544 + (r+y0)*136 + xx + x0];
            unsigned hi = sP[c1i*544 + (r+y1)*136 + xx + x1];
            u[p] = lo | (hi << 16);
        }
        #pragma unroll
        for (int p = 27; p < 32; ++p) u[p] = 0;
        #pragma unroll
        for (int e = 0; e < 8; ++e) {
            uint4 pk; pk.x = u[4*e]; pk.y = u[4*e+1]; pk.z = u[4*e+2]; pk.w = u[4*e+3];
            *(uint4*)&sA[t*72 + e*8] = pk;
        }
    }
    __syncthreads();
    int m = lane & 15, kq = (lane >> 4)*8;
    b8v wv[2][2];
    #pragma unroll
    for (int nt = 0; nt < 2; ++nt)
      #pragma unroll
      for (int ks = 0; ks < 2; ++ks)
        wv[nt][ks] = *(const b8v*)&sW[(nt*16 + m)*72 + ks*32 + kq];
    f4v acc[4][2] = {};
    #pragma unroll
    for (int mt = 0; mt < 4; ++mt) {
        const ushortt* ab = &sA[(wid*64 + mt*16 + m)*72 + kq];
        b8v a0 = *(const b8v*)(ab);
        b8v a1 = *(const b8v*)(ab + 32);
        #pragma unroll
        for (int nt = 0; nt < 2; ++nt) {
            acc[mt][nt] = __builtin_amdgcn_mfma_f32_16x16x32_bf16(a0, wv[nt][0], acc[mt][nt], 0, 0, 0);
            acc[mt][nt] = __builtin_amdgcn_mfma_f32_16x16x32_bf16(a1, wv[nt][1], acc[mt][nt], 0, 0, 0);
        }
    }
    __syncthreads();
    // C staging: sC[o][r(2)][x(128)]: stride o*272 + r*136 + x
    ushortt* sC = sA;
    int q4 = lane >> 4;
    #pragma unroll
    for (int mt = 0; mt < 4; ++mt) {
        int pxb = wid*64 + mt*16 + q4*4;
        #pragma unroll
        for (int nt = 0; nt < 2; ++nt) {
            int o = nt*16 + m;
            if (o < 24) {
                float bo = bias[o];
                #pragma unroll
                for (int r = 0; r < 4; ++r) {
                    int px = pxb + r;
                    sC[o*272 + (px >> 7)*136 + (px & 127)] =
                        (ushortt)bfbits(acc[mt][nt][r] + bo);
                }
            }
        }
    }
    __syncthreads();
    // coalesced writeback + gn2 stats (o constant per 32 consecutive lanes)
    #pragma unroll
    for (int j = 0; j < 3; ++j) {
        int idx = j*256 + t;               // 768 uint4 chunks
        int o = idx >> 5;
        int rem = idx & 31;
        int r = rem >> 4, x8 = (rem & 15)*8;
        uint4 v = *(const uint4*)&sC[o*272 + r*136 + x8];
        *(uint4*)(c2 + ((size_t)(b*24+o)*H2 + h0 + r)*W2 + x8) = v;
        float v0 = b2f(v.x & 0xffff), v1 = b2f(v.x >> 16);
        float v2 = b2f(v.y & 0xffff), v3 = b2f(v.y >> 16);
        float v4 = b2f(v.z & 0xffff), v5 = b2f(v.z >> 16);
        float v6 = b2f(v.w & 0xffff), v7 = b2f(v.w >> 16);
        float s = v0+v1+v2+v3+v4+v5+v6+v7;
        float qv = v0*v0+v1*v1+v2*v2+v3*v3+v4*v4+v5*v5+v6*v6+v7*v7;
        wred2_32(s, qv);
        if ((lane & 31) == 0) { atomicAdd(&redS[o], s); atomicAdd(&redQ[o], qv); }
    }
    __syncthreads();
    if (t < 24) {
        atomicAdd(&mc2[((size_t)b*24 + t)*2],     redS[t]);
        atomicAdd(&mc2[((size_t)b*24 + t)*2 + 1], redQ[t]);
    }
}

// ---------------------------------------------------------------------------
// K8: tconv3 2x2 s2, 24->24 via MFMA, fused gn2+ReLU+pool+SiLU staging from c2.
// 512 blocks.
__global__ __launch_bounds__(256) void k_tconv3(
    const bf* __restrict__ c2, const float* __restrict__ mc2,
    const float* __restrict__ g2, const float* __restrict__ be2,
    const float* __restrict__ k3, const float* __restrict__ b3,
    bf* __restrict__ u3, float* __restrict__ mu3)
{
    __shared__ ushortt sBuf[27648];       // A[256*40] + W[96*40] aliased by C[24*1152]
    __shared__ float redS[24], redQ[24];
    __shared__ float ssl[48];
    ushortt* sA = sBuf;
    ushortt* sW = sBuf + 10240;
    int t = threadIdx.x;
    int b = blockIdx.x >> 3, pg = blockIdx.x & 7;
    int lane = t & 63, wid = t >> 6;
    if (t < 24) {
        redS[t] = 0.f; redQ[t] = 0.f;
        float s = mc2[((size_t)b*24 + t)*2], q = mc2[((size_t)b*24 + t)*2 + 1];
        float mean = s * (1.f/PL2);
        float var  = q * (1.f/PL2) - mean*mean;
        float rstd = rsqrtf(var + 1e-5f);
        float sc = g2[t]*rstd;
        ssl[t*2] = sc; ssl[t*2+1] = be2[t] - mean*sc;
    }
    // stage W: k3[c][o][dq] -> sW[n=o*4+dq][kpad=c]
    #pragma unroll
    for (int j = 0; j < 9; ++j) {
        int e = j*256 + t;
        int c = e / 96, n = e % 96;
        sW[n*40 + c] = (ushortt)bfbits(k3[e]);
    }
    if (t < 96) { uint4 z = {0,0,0,0}; *(uint4*)&sW[t*40 + 24] = z; }
    { uint4 z = {0,0,0,0}; *(uint4*)&sA[t*40 + 24] = z; }   // zero A k-pad
    __syncthreads();
    // stage A: item = (c, px-pair). 24*128 = 3072 items, uint2 loads.
    #pragma unroll
    for (int j = 0; j < 12; ++j) {
        int i = j*256 + t;
        int c = i >> 7, pr = i & 127;
        int px0 = pr*2;
        int h4 = (pg*256 + px0) >> 6, w4 = px0 & 63;     // w4 even
        const bf* pp = c2 + ((size_t)b*24 + c)*PL2 + (size_t)(2*h4)*W2 + 2*w4;
        uint2 r0 = *(const uint2*)pp;
        uint2 r1 = *(const uint2*)(pp + W2);
        float sc = ssl[c*2], sh = ssl[c*2+1];
        float e0 = fmaxf(b2f(r0.x & 0xffff)*sc+sh, 0.f);
        float e1 = fmaxf(b2f(r0.x >> 16)   *sc+sh, 0.f);
        float f0 = fmaxf(b2f(r1.x & 0xffff)*sc+sh, 0.f);
        float f1 = fmaxf(b2f(r1.x >> 16)   *sc+sh, 0.f);
        float m0 = fmaxf(fmaxf(e0,e1), fmaxf(f0,f1));
        m0 = m0 / (1.f + expf(-m0));
        float e2 = fmaxf(b2f(r0.y & 0xffff)*sc+sh, 0.f);
        float e3 = fmaxf(b2f(r0.y >> 16)   *sc+sh, 0.f);
        float f2 = fmaxf(b2f(r1.y & 0xffff)*sc+sh, 0.f);
        float f3 = fmaxf(b2f(r1.y >> 16)   *sc+sh, 0.f);
        float m1 = fmaxf(fmaxf(e2,e3), fmaxf(f2,f3));
        m1 = m1 / (1.f + expf(-m1));
        sA[px0*40 + c]     = (ushortt)bfbits(m0);
        sA[(px0+1)*40 + c] = (ushortt)bfbits(m1);
    }
    __syncthreads();
    int m = lane & 15, kq = (lane >> 4)*8;
    b8v wv[6];
    #pragma unroll
    for (int nt = 0; nt < 6; ++nt)
        wv[nt] = *(const b8v*)&sW[(nt*16 + m)*40 + kq];
    f4v acc[4][6] = {};
    #pragma unroll
    for (int mt = 0; mt < 4; ++mt) {
        b8v av = *(const b8v*)&sA[(wid*64 + mt*16 + m)*40 + kq];
        #pragma unroll
        for (int nt = 0; nt < 6; ++nt)
            acc[mt][nt] = __builtin_amdgcn_mfma_f32_16x16x32_bf16(av, wv[nt], acc[mt][nt], 0, 0, 0);
    }
    __syncthreads();
    // C staging: sC[o][yl(8)][x(128)] row stride 144, o stride 1152
    ushortt* sC = sBuf;
    int q4 = lane >> 4;
    #pragma unroll
    for (int mt = 0; mt < 4; ++mt) {
        int pxb = wid*64 + mt*16 + q4*4;
        #pragma unroll
        for (int nt = 0; nt < 6; ++nt) {
            int n = nt*16 + m;
            int o = n >> 2, d = (n >> 1) & 1, qq = n & 1;
            float bo = b3[o];
            #pragma unroll
            for (int r = 0; r < 4; ++r) {
                int px = pxb + r;
                int yl = ((px >> 6) << 1) + d;
                int xx = ((px & 63) << 1) + qq;
                sC[o*1152 + yl*144 + xx] = (ushortt)bfbits(acc[mt][nt][r] + bo);
            }
        }
    }
    __syncthreads();
    bf* outb = u3 + (size_t)b*24*PL2;
    #pragma unroll
    for (int j = 0; j < 12; ++j) {
        int idx = j*256 + t;
        int o = idx >> 7;
        int rem = idx & 127;
        int yl = rem >> 4, xc = (rem & 15)*8;
        uint4 v = *(const uint4*)&sC[o*1152 + yl*144 + xc];
        *(uint4*)(outb + ((size_t)o*H2 + pg*8 + yl)*W2 + xc) = v;
        float v0 = b2f(v.x & 0xffff), v1 = b2f(v.x >> 16);
        float v2 = b2f(v.y & 0xffff), v3 = b2f(v.y >> 16);
        float v4 = b2f(v.z & 0xffff), v5 = b2f(v.z >> 16);
        float v6 = b2f(v.w & 0xffff), v7 = b2f(v.w >> 16);
        float s = v0+v1+v2+v3+v4+v5+v6+v7;
        float qv = v0*v0+v1*v1+v2*v2+v3*v3+v4*v4+v5*v5+v6*v6+v7*v7;
        wred2(s, qv);
        if (lane == 0) { atomicAdd(&redS[o], s); atomicAdd(&redQ[o], qv); }
    }
    __syncthreads();
    if (t < 24) {
        atomicAdd(&mu3[((size_t)b*24 + t)*2],     redS[t]);
        atomicAdd(&mu3[((size_t)b*24 + t)*2 + 1], redQ[t]);
    }
}

// ---------------------------------------------------------------------------
// K10: gn3-fused tconv4 2x2 s2, 48->12 via MFMA. gn3 prologue from mc2+mu3.
// XOR-swizzled A/W staging (stride 64, block = kb ^ (row&7)) — zero LDS bank
// conflicts on b128 ops. C written directly to global via lane-pairing
// (shfl_xor(1)) as coalesced uint4; stats reduced in registers. 2048 blocks.
__global__ __launch_bounds__(256) void k_tconv4(
    const bf* __restrict__ c2, const bf* __restrict__ u3,
    const float* __restrict__ mc2, const float* __restrict__ mu3,
    const float* __restrict__ g3, const float* __restrict__ be3,
    const float* __restrict__ k4, const float* __restrict__ bias4,
    bf* __restrict__ u4, float* __restrict__ mu4)
{
    __shared__ ushortt sA[256*64];   // [px][kb^(px&7) blocks of 8]
    __shared__ ushortt sW[48*64];    // [n][kb^(n&7) blocks of 8]
    __shared__ float redS[12], redQ[12];
    __shared__ float ssl[96];
    int t = threadIdx.x;
    int b = blockIdx.x >> 5, pg = blockIdx.x & 31;
    int lane = t & 63, wid = t >> 6;
    int m = lane & 15, q4 = lane >> 4;
    if (t < 12) { redS[t] = 0.f; redQ[t] = 0.f; }
    if (t < 6) {
        float s = 0.f, q = 0.f;
        #pragma unroll
        for (int cl = 0; cl < 8; ++cl) {
            int gc = t*8 + cl;
            const float* p = (gc < 24) ? mc2 + ((size_t)b*24 + gc)*2
                                       : mu3 + ((size_t)b*24 + gc - 24)*2;
            s += p[0]; q += p[1];
        }
        float inv_n = 1.f/((float)PL2*8.f);
        float mean = s*inv_n;
        float var  = q*inv_n - mean*mean;
        float rstd = rsqrtf(var + 1e-5f);
        #pragma unroll
        for (int cl = 0; cl < 8; ++cl) {
            int gc = t*8 + cl;
            float sc = g3[gc]*rstd;
            ssl[gc*2] = sc; ssl[gc*2+1] = be3[gc] - mean*sc;
        }
    }
    // stage W: k4[c][n] -> sW[n][swizzled block (c>>3)^(n&7), elem c&7]
    #pragma unroll
    for (int j = 0; j < 9; ++j) {
        int e = j*256 + t;                 // 2304 exactly
        int c = e / 48, n = e % 48;
        sW[n*64 + ((((c >> 3) ^ (n & 7)) << 3) | (c & 7))] = (ushortt)bfbits(k4[e]);
    }
    if (t < 96) {                          // zero pad blocks kb=6,7
        uint4 z = {0,0,0,0};
        int n = t >> 1, kb = 6 + (t & 1);
        *(uint4*)&sW[n*64 + ((kb ^ (n & 7)) << 3)] = z;
    }
    // stage A: gn3-affine of concat(c2,u3), swizzled blocks
    {
        int px = t;
        int pix = pg*256 + px;
        const bf* c2p = c2 + (size_t)b*24*PL2 + pix;
        const bf* u3p = u3 + (size_t)b*24*PL2 + pix;
        #pragma unroll
        for (int g = 0; g < 6; ++g) {
            unsigned pr[4];
            #pragma unroll
            for (int hc = 0; hc < 4; ++hc) {
                int c0 = g*8 + hc*2;
                float r0 = (c0 < 24) ? tof(c2p[(size_t)c0*PL2]) : tof(u3p[(size_t)(c0-24)*PL2]);
                float r1 = (c0+1 < 24) ? tof(c2p[(size_t)(c0+1)*PL2]) : tof(u3p[(size_t)(c0+1-24)*PL2]);
                float v0 = r0 * ssl[2*c0]   + ssl[2*c0+1];
                float v1 = r1 * ssl[2*c0+2] + ssl[2*c0+3];
                pr[hc] = bfbits(v0) | (bfbits(v1) << 16);
            }
            uint4 pk; pk.x = pr[0]; pk.y = pr[1]; pk.z = pr[2]; pk.w = pr[3];
            *(uint4*)&sA[px*64 + ((g ^ (px & 7)) << 3)] = pk;
        }
        uint4 z = {0,0,0,0};
        *(uint4*)&sA[px*64 + ((6 ^ (px & 7)) << 3)] = z;
        *(uint4*)&sA[px*64 + ((7 ^ (px & 7)) << 3)] = z;
    }
    __syncthreads();
    // MFMA: wave = 64 px x 48 n, K=64 (2 swizzled reads)
    b8v bfr[3][2];
    #pragma unroll
    for (int nt = 0; nt < 3; ++nt) {
        int n = nt*16 + m;
        #pragma unroll
        for (int ks = 0; ks < 2; ++ks)
            bfr[nt][ks] = *(const b8v*)&sW[n*64 + (((ks*4 + q4) ^ (n & 7)) << 3)];
    }
    f4v acc[4][3] = {};
    #pragma unroll
    for (int mt = 0; mt < 4; ++mt) {
        int px = wid*64 + mt*16 + m;
        b8v a0 = *(const b8v*)&sA[px*64 + (((q4)     ^ (px & 7)) << 3)];
        b8v a1 = *(const b8v*)&sA[px*64 + (((4 + q4) ^ (px & 7)) << 3)];
        #pragma unroll
        for (int nt = 0; nt < 3; ++nt) {
            acc[mt][nt] = __builtin_amdgcn_mfma_f32_16x16x32_bf16(a0, bfr[nt][0], acc[mt][nt], 0, 0, 0);
            acc[mt][nt] = __builtin_amdgcn_mfma_f32_16x16x32_bf16(a1, bfr[nt][1], acc[mt][nt], 0, 0, 0);
        }
    }
    // Epilogue: lane-paired direct global uint4 stores + register stats.
    // Lanes m, m^1 share (o,d); qq = m&1 selects low/high short.
    float sAcc[3] = {0.f, 0.f, 0.f}, qAcc[3] = {0.f, 0.f, 0.f};
    int qq = m & 1;
    #pragma unroll
    for (int nt = 0; nt < 3; ++nt) {
        int n = nt*16 + m;
        int o = n >> 2, d = (n >> 1) & 1;
        float bo = bias4[o];
        #pragma unroll
        for (int mt = 0; mt < 4; ++mt) {
            int pxb = wid*64 + mt*16 + q4*4;
            unsigned wds[4];
            float s = 0.f, q = 0.f;
            #pragma unroll
            for (int r = 0; r < 4; ++r) {
                float v = acc[mt][nt][r] + bo;
                float vp = __shfl_xor(v, 1);
                unsigned lo = bfbits(v), hi = bfbits(vp);
                wds[r] = lo | (hi << 16);
                float f0 = b2f(lo), f1 = b2f(hi);
                s += f0 + f1;
                q += f0*f0 + f1*f1;
            }
            if (qq == 0) {
                int h2 = (pg*256 + pxb) >> 7;      // global up-h base / 2
                int w0 = pxb & 127;
                uint4 pk; pk.x = wds[0]; pk.y = wds[1]; pk.z = wds[2]; pk.w = wds[3];
                *(uint4*)(u4 + (((size_t)(b*12 + o))*HH + 2*h2 + d)*EE + 2*w0) = pk;
                sAcc[nt] += s; qAcc[nt] += q;
            }
        }
    }
    #pragma unroll
    for (int nt = 0; nt < 3; ++nt) {
        float s = sAcc[nt], q = qAcc[nt];
        s += __shfl_xor(s, 2);  q += __shfl_xor(q, 2);
        s += __shfl_xor(s, 16); q += __shfl_xor(q, 16);
        s += __shfl_xor(s, 32); q += __shfl_xor(q, 32);
        if ((lane & 51) == 0) {            // m&3==0 && q4==0
            int o = nt*4 + (m >> 2);
            atomicAdd(&redS[o], s);
            atomicAdd(&redQ[o], q);
        }
    }
    __syncthreads();
    if (t < 12) {
        atomicAdd(&mu4[((size_t)b*12 + t)*2],     redS[t]);
        atomicAdd(&mu4[((size_t)b*12 + t)*2 + 1], redQ[t]);
    }
}

// ---------------------------------------------------------------------------
// K12: gn4-fused 1x1 conv 18->6. gn4 prologue from mc1+mu4. 8 px/thread,
// uint4 loads/stores. Fused u5 stats. 1024 blocks.
__global__ __launch_bounds__(256) void k_conv1x1_u5(
    const bf* __restrict__ c1, const bf* __restrict__ u4,
    const float* __restrict__ mc1, const float* __restrict__ mu4,
    const float* __restrict__ g4, const float* __restrict__ be4,
    const float* __restrict__ k, const float* __restrict__ bias,
    bf* __restrict__ u5, float* __restrict__ mu5)
{
    __shared__ float red[4][6][2];
    __shared__ float ssl[36];
    int t = threadIdx.x;
    int b  = blockIdx.x >> 4;
    int pg = blockIdx.x & 15;
    int pix = pg*2048 + t*8;
    int lane = t & 63, wid = t >> 6;
    if (t < 6) {
        float s = 0.f, q = 0.f;
        #pragma unroll
        for (int cl = 0; cl < 3; ++cl) {
            int gc = t*3 + cl;
            const float* p = (gc < 6) ? mc1 + ((size_t)b*6 + gc)*2
                                      : mu4 + ((size_t)b*12 + gc - 6)*2;
            s += p[0]; q += p[1];
        }
        float inv_n = 1.f/((float)HP*3.f);
        float mean = s*inv_n;
        float var  = q*inv_n - mean*mean;
        float rstd = rsqrtf(var + 1e-5f);
        #pragma unroll
        for (int cl = 0; cl < 3; ++cl) {
            int gc = t*3 + cl;
            float sc = g4[gc]*rstd;
            ssl[gc*2] = sc; ssl[gc*2+1] = be4[gc] - mean*sc;
        }
    }
    __syncthreads();
    const bf* c1p = c1 + ((size_t)b*6)*HP + pix;
    const bf* u4p = u4 + ((size_t)b*12)*HP + pix;
    float acc[6][8];
    #pragma unroll
    for (int o = 0; o < 6; ++o) {
        float bv = bias[o];
        #pragma unroll
        for (int j = 0; j < 8; ++j) acc[o][j] = bv;
    }
    #pragma unroll
    for (int c = 0; c < 18; ++c) {
        uint4 r = (c < 6) ? *(const uint4*)(c1p + (size_t)c*HP)
                          : *(const uint4*)(u4p + (size_t)(c-6)*HP);
        float sc = ssl[2*c], sh = ssl[2*c+1];
        float v[8];
        v[0] = b2f(r.x & 0xffff)*sc + sh;  v[1] = b2f(r.x >> 16)*sc + sh;
        v[2] = b2f(r.y & 0xffff)*sc + sh;  v[3] = b2f(r.y >> 16)*sc + sh;
        v[4] = b2f(r.z & 0xffff)*sc + sh;  v[5] = b2f(r.z >> 16)*sc + sh;
        v[6] = b2f(r.w & 0xffff)*sc + sh;  v[7] = b2f(r.w >> 16)*sc + sh;
        #pragma unroll
        for (int o = 0; o < 6; ++o) {
            float wv = k[o*18 + c];
            #pragma unroll
            for (int j = 0; j < 8; ++j) acc[o][j] += v[j]*wv;
        }
    }
    #pragma unroll
    for (int o = 0; o < 6; ++o) {
        uint4 pk;
        pk.x = bfbits(acc[o][0]) | (bfbits(acc[o][1]) << 16);
        pk.y = bfbits(acc[o][2]) | (bfbits(acc[o][3]) << 16);
        pk.z = bfbits(acc[o][4]) | (bfbits(acc[o][5]) << 16);
        pk.w = bfbits(acc[o][6]) | (bfbits(acc[o][7]) << 16);
        *(uint4*)(u5 + ((size_t)(b*6+o))*HP + pix) = pk;
        float s = 0.f, q = 0.f;
        #pragma unroll
        for (int j = 0; j < 8; ++j) { s += acc[o][j]; q += acc[o][j]*acc[o][j]; }
        wred2(s, q);
        if (lane == 0) { red[wid][o][0] = s; red[wid][o][1] = q; }
    }
    __syncthreads();
    if (t < 6) {
        float S = 0.f, Q = 0.f;
        #pragma unroll
        for (int wv = 0; wv < 4; ++wv) { S += red[wv][t][0]; Q += red[wv][t][1]; }
        atomicAdd(&mu5[((size_t)b*6 + t)*2],     S);
        atomicAdd(&mu5[((size_t)b*6 + t)*2 + 1], Q);
    }
}

// ---------------------------------------------------------------------------
// K14: gn5-fused final 1x1 conv (6->1) + divide by std(t). gn5 in prologue.
// 8 px/thread, uint4 loads, 2x float4 stores. 1024 blocks.
__global__ __launch_bounds__(256) void k_final(
    const bf* __restrict__ u5, const float* __restrict__ mu5,
    const float* __restrict__ g5, const float* __restrict__ be5,
    const float* __restrict__ k, const float* __restrict__ bias,
    const float* __restrict__ t, float* __restrict__ out)
{
    __shared__ float ssl[12];
    int tt = threadIdx.x;
    int b = blockIdx.x >> 4;
    int pix = ((blockIdx.x & 15)*256 + tt)*8;
    if (tt < 6) {
        float s = mu5[((size_t)b*6 + tt)*2], q = mu5[((size_t)b*6 + tt)*2 + 1];
        float mean = s * (1.f/HP);
        float var  = q * (1.f/HP) - mean*mean;
        float rstd = rsqrtf(var + 1e-5f);
        float sc = g5[tt]*rstd;
        ssl[tt*2] = sc; ssl[tt*2+1] = be5[tt] - mean*sc;
    }
    __syncthreads();
    const bf* up = u5 + (size_t)b*6*HP + pix;
    float bv = bias[0];
    float a[8];
    #pragma unroll
    for (int j = 0; j < 8; ++j) a[j] = bv;
    #pragma unroll
    for (int c = 0; c < 6; ++c) {
        uint4 r = *(const uint4*)(up + (size_t)c*HP);
        float sc = ssl[2*c], sh = ssl[2*c+1];
        float wv = k[c];
        a[0] += (b2f(r.x & 0xffff)*sc + sh) * wv;
        a[1] += (b2f(r.x >> 16)   *sc + sh) * wv;
        a[2] += (b2f(r.y & 0xffff)*sc + sh) * wv;
        a[3] += (b2f(r.y >> 16)   *sc + sh) * wv;
        a[4] += (b2f(r.z & 0xffff)*sc + sh) * wv;
        a[5] += (b2f(r.z >> 16)   *sc + sh) * wv;
        a[6] += (b2f(r.w & 0xffff)*sc + sh) * wv;
        a[7] += (b2f(r.w >> 16)   *sc + sh) * wv;
    }
    float tb = t[b];
    const float lns = 3.2188758248682007492f;
    float var = (expf(2.f*tb*lns) - 1.f) / (2.f*lns);
    float rs = rsqrtf(var);
    float4 o0; o0.x = a[0]*rs; o0.y = a[1]*rs; o0.z = a[2]*rs; o0.w = a[3]*rs;
    float4 o1; o1.x = a[4]*rs; o1.y = a[5]*rs; o1.z = a[6]*rs; o1.w = a[7]*rs;
    float* op = out + (size_t)b*HP + pix;
    *(float4*)op       = o0;
    *(float4*)(op + 4) = o1;
}

// ---------------------------------------------------------------------------
extern "C" void kernel_launch(void* const* d_in, const int* in_sizes, int n_in,
                              void* d_out, int out_size, void* d_ws, size_t ws_size,
                              hipStream_t stream)
{
    const float* x       = (const float*)d_in[0];
    const float* t       = (const float*)d_in[1];
    const float* Wf      = (const float*)d_in[2];
    const float* fc1_w   = (const float*)d_in[3];
    const float* fc1_b   = (const float*)d_in[4];
    const float* conv1_k = (const float*)d_in[5];
    const float* conv1_b = (const float*)d_in[6];
    const float* gn1_g   = (const float*)d_in[7];
    const float* gn1_b   = (const float*)d_in[8];
    const float* conv2_k = (const float*)d_in[9];
    const float* conv2_b = (const float*)d_in[10];
    const float* gn2_g   = (const float*)d_in[11];
    const float* gn2_b   = (const float*)d_in[12];
    const float* t3_k    = (const float*)d_in[13];
    const float* t3_b    = (const float*)d_in[14];
    const float* gn3_g   = (const float*)d_in[15];
    const float* gn3_b   = (const float*)d_in[16];
    const float* t4_k    = (const float*)d_in[17];
    const float* t4_b    = (const float*)d_in[18];
    const float* gn4_g   = (const float*)d_in[19];
    const float* gn4_b   = (const float*)d_in[20];
    const float* t5_k    = (const float*)d_in[21];
    const float* t5_b    = (const float*)d_in[22];
    const float* gn5_g   = (const float*)d_in[23];
    const float* gn5_b   = (const float*)d_in[24];
    const float* fin_k   = (const float*)d_in[25];
    const float* fin_b   = (const float*)d_in[26];

    bf* wsb = (bf*)d_ws;
    bf* c1 = wsb;                          // conv1..conv1x1
    bf* c2 = wsb + 12582912;               // conv2..tconv4
    bf* u3 = wsb + 25165824;               // tconv3..tconv4
    bf* u4 = wsb + 37748736;               // tconv4..conv1x1
    bf* xf = wsb + 39845888;               // fc1..conv1 (in u4 region)
    bf* u5 = wsb + 12582912;               // reuses c2, conv1x1..final
    float* mb = (float*)(wsb + 62914560);  // raw channel sums
    float* mc1 = mb;            // 768
    float* mc2 = mb + 768;      // 3072
    float* mu3 = mb + 3840;     // 3072
    float* mu4 = mb + 6912;     // 1536
    float* mu5 = mb + 8448;     // 768

    k_fourier_fc1<<<512, 256, 0, stream>>>(x, Wf, fc1_w, fc1_b, xf, mb);
    k_conv1<<<2048, 256, 0, stream>>>(xf, conv1_k, conv1_b, c1, mc1);
    k_conv2<<<2048, 256, 0, stream>>>(c1, mc1, gn1_g, gn1_b,
                                      conv2_k, conv2_b, c2, mc2);
    k_tconv3<<<512, 256, 0, stream>>>(c2, mc2, gn2_g, gn2_b,
                                      t3_k, t3_b, u3, mu3);
    k_tconv4<<<2048, 256, 0, stream>>>(c2, u3, mc2, mu3, gn3_g, gn3_b,
                                       t4_k, t4_b, u4, mu4);
    k_conv1x1_u5<<<1024, 256, 0, stream>>>(c1, u4, mc1, mu4, gn4_g, gn4_b,
                                           t5_k, t5_b, u5, mu5);
    k_final<<<1024, 256, 0, stream>>>(u5, mu5, gn5_g, gn5_b,
                                      fin_k, fin_b, t, (float*)d_out);
}

// Round 13
// 233.838 us; speedup vs baseline: 5.3419x; 1.0116x over previous
//
#include <hip/hip_runtime.h>
#include <hip/hip_bf16.h>
#include <math.h>

#define BB 64
#define HH 128
#define WW 128
#define EE 256
#define HP (HH*EE)        // 32768
#define H2 64
#define W2 128
#define PL2 (H2*W2)       // 8192
#define H4 32
#define W4 64
#define PL4 (H4*W4)       // 2048

typedef __hip_bfloat16 bf;
typedef unsigned short ushortt;
typedef __attribute__((ext_vector_type(8))) __bf16 b8v;
typedef __attribute__((ext_vector_type(4))) float f4v;

__device__ __forceinline__ float tof(bf v)    { return __bfloat162float(v); }
__device__ __forceinline__ bf    tob(float v) { return __float2bfloat16(v); }
__device__ __forceinline__ unsigned int bfbits(float v) {
    return (unsigned int)__builtin_bit_cast(ushortt, __float2bfloat16(v));
}
__device__ __forceinline__ float b2f(unsigned int u16) {
    unsigned int x = u16 << 16;
    return __builtin_bit_cast(float, x);
}
__device__ __forceinline__ void wred2(float& s, float& q) {
    #pragma unroll
    for (int m = 32; m; m >>= 1) {
        s += __shfl_xor(s, m);
        q += __shfl_xor(q, m);
    }
}

// ---------------------------------------------------------------------------
// K1: fused Fourier features + fc1 GEMM via MFMA. 512 blocks.
// Prologue grid-stride zeroes the stats buffer (mb, 9216 floats).
__global__ __launch_bounds__(256) void k_fourier_fc1(
    const float* __restrict__ x, const float* __restrict__ Wf,
    const float* __restrict__ fc1_w, const float* __restrict__ fc1_b,
    bf* __restrict__ xf, float* __restrict__ mb)
{
    __shared__ ushortt sA[64*264];
    __shared__ ushortt sB[64*264];
    int t = threadIdx.x;
    for (int i = blockIdx.x*256 + t; i < 9216; i += 512*256) mb[i] = 0.f;
    int rb = blockIdx.x >> 2, cb = blockIdx.x & 3;
    int row0 = rb*64, col0 = cb*64;
    const float TP = 6.2831853071795864769f;
    for (int it = 0; it < 32; ++it) {       // 8192 = 64 rows x 128 w
        int i = it*256 + t;
        int r = i >> 7, w = i & 127;
        int rg = row0 + r;
        float p = x[(size_t)rg*WW + w] * Wf[(size_t)(rg & (HH-1))*WW + w] * TP;
        sA[r*264 + w]       = (ushortt)bfbits(__sinf(p));
        sA[r*264 + 128 + w] = (ushortt)bfbits(__cosf(p));
    }
    #pragma unroll
    for (int it = 0; it < 16; ++it) {       // B: fp32 -> bf16
        int i = it*256 + t;
        int o = i >> 6, c4 = i & 63;
        float4 w4 = *(const float4*)(fc1_w + (size_t)(col0 + o)*EE + c4*4);
        uint2 pk;
        pk.x = bfbits(w4.x) | (bfbits(w4.y) << 16);
        pk.y = bfbits(w4.z) | (bfbits(w4.w) << 16);
        *(uint2*)&sB[o*264 + c4*4] = pk;
    }
    __syncthreads();
    int lane = t & 63, wid = t >> 6;
    int m = lane & 15, kq = (lane >> 4) * 8;
    f4v acc[4] = {};
    const ushortt* aBase = &sA[(wid*16 + m)*264 + kq];
    #pragma unroll
    for (int k0 = 0; k0 < 8; ++k0) {
        b8v av = *(const b8v*)(aBase + k0*32);
        #pragma unroll
        for (int t4 = 0; t4 < 4; ++t4) {
            b8v bv = *(const b8v*)&sB[(t4*16 + m)*264 + k0*32 + kq];
            acc[t4] = __builtin_amdgcn_mfma_f32_16x16x32_bf16(av, bv, acc[t4], 0, 0, 0);
        }
    }
    int rbase = row0 + wid*16 + (lane >> 4)*4;
    #pragma unroll
    for (int t4 = 0; t4 < 4; ++t4) {
        int col = col0 + t4*16 + m;
        float bias = fc1_b[col];
        #pragma unroll
        for (int r = 0; r < 4; ++r)
            xf[(size_t)(rbase + r)*EE + col] = tob(acc[t4][r] + bias);
    }
}

// ---------------------------------------------------------------------------
// K2: conv1 3x3, 1->6, LDS-staged rows, 4 px/thread. 2048 blocks. Fused gn1 stats.
__global__ __launch_bounds__(256) void k_conv1(
    const bf* __restrict__ xf, const float* __restrict__ k,
    const float* __restrict__ bias, bf* __restrict__ c1, float* __restrict__ mc1)
{
    __shared__ ushortt sT[6*272];    // 6 rows, data at [8..263], zero halos
    __shared__ float red[4][6][2];
    int t = threadIdx.x;
    int ht = blockIdx.x & 31, b = blockIdx.x >> 5;
    int h0 = ht*4;
    const bf* src = xf + (size_t)b*HP;
    if (t < 192) {
        int r = t >> 5, i = t & 31;
        int gy = h0 - 1 + r;
        uint4 v = {0,0,0,0};
        if (gy >= 0 && gy < HH) v = *(const uint4*)(src + (size_t)gy*EE + i*8);
        *(uint4*)&sT[r*272 + 8 + i*8] = v;
    } else if (t < 204) {
        int e = t - 192;
        int r = e >> 1, s = e & 1;
        uint4 z = {0,0,0,0};
        *(uint4*)&sT[r*272 + s*264] = z;
    }
    __syncthreads();
    int wq = (t & 63)*4, hl = t >> 6;
    int lane = t & 63, wid = t >> 6;
    float v[3][6];
    #pragma unroll
    for (int ky = 0; ky < 3; ++ky)
      #pragma unroll
      for (int j = 0; j < 6; ++j)
        v[ky][j] = b2f((unsigned)sT[(hl+ky)*272 + 7 + wq + j]);
    int h = h0 + hl;
    #pragma unroll
    for (int o = 0; o < 6; ++o) {
        float bv = bias[o];
        float a0=bv, a1=bv, a2=bv, a3=bv;
        #pragma unroll
        for (int ky = 0; ky < 3; ++ky)
          #pragma unroll
          for (int kx = 0; kx < 3; ++kx) {
            float wv = k[o*9 + ky*3 + kx];
            a0 += v[ky][kx+0]*wv;
            a1 += v[ky][kx+1]*wv;
            a2 += v[ky][kx+2]*wv;
            a3 += v[ky][kx+3]*wv;
          }
        uint2 pk;
        pk.x = bfbits(a0) | (bfbits(a1) << 16);
        pk.y = bfbits(a2) | (bfbits(a3) << 16);
        *(uint2*)(c1 + ((size_t)(b*6+o)*HH + h)*EE + wq) = pk;
        float s = a0+a1+a2+a3, q = a0*a0+a1*a1+a2*a2+a3*a3;
        wred2(s, q);
        if (lane == 0) { red[wid][o][0] = s; red[wid][o][1] = q; }
    }
    __syncthreads();
    if (t < 6) {
        float S = 0.f, Q = 0.f;
        #pragma unroll
        for (int wv = 0; wv < 4; ++wv) { S += red[wv][t][0]; Q += red[wv][t][1]; }
        atomicAdd(&mc1[((size_t)b*6 + t)*2],     S);
        atomicAdd(&mc1[((size_t)b*6 + t)*2 + 1], Q);
    }
}

// ---------------------------------------------------------------------------
// K5: conv2 3x3, 6->24 via MFMA implicit GEMM, fused gn1+ReLU+pool staging.
// XOR-swizzled stride-64 A/W (zero bank conflicts); direct-global uint2
// epilogue + register stats. 2048 blocks. Fused gn2 stats -> mc2.
__global__ __launch_bounds__(256) void k_conv2(
    const bf* __restrict__ c1, const float* __restrict__ mc1,
    const float* __restrict__ g1, const float* __restrict__ be1,
    const float* __restrict__ kw, const float* __restrict__ bias,
    bf* __restrict__ c2, float* __restrict__ mc2)
{
    __shared__ ushortt sA[256*64];     // im2col A, swizzled blocks
    __shared__ ushortt sW[32*64];
    __shared__ ushortt sP[6*4*136];    // pooled halo tile
    __shared__ float ssl[12];
    __shared__ float redS[24], redQ[24];
    int t = threadIdx.x;
    int ht = blockIdx.x & 31, b = blockIdx.x >> 5;
    int h0 = ht*2;                     // output rows h0, h0+1 (of 64)
    int lane = t & 63, wid = t >> 6;
    int m = lane & 15, q4 = lane >> 4;
    if (t < 24) { redS[t] = 0.f; redQ[t] = 0.f; }
    if (t < 6) {
        float s = mc1[((size_t)b*6 + t)*2], q = mc1[((size_t)b*6 + t)*2 + 1];
        float mean = s * (1.f/HP);
        float var  = q * (1.f/HP) - mean*mean;
        float rstd = rsqrtf(var + 1e-5f);
        float sc = g1[t]*rstd;
        ssl[t*2] = sc; ssl[t*2+1] = be1[t] - mean*sc;
    }
    for (int i = t; i < 1024; i += 256) ((unsigned*)sW)[i] = 0;   // zero W
    __syncthreads();
    // stage pooled tile (gn1+ReLU+pool): 6 ch x 4 rows x 130 cols
    for (int i = t; i < 3120; i += 256) {
        int c = i / 520, rem = i % 520;
        int ry = rem / 130, rx = rem % 130;
        int gy = h0 - 1 + ry, gx = rx - 1;
        float v = 0.f;
        if (gy >= 0 && gy < H2 && gx >= 0 && gx < W2) {
            const bf* pp = c1 + ((size_t)(b*6+c)*HH + 2*gy)*EE + 2*gx;
            unsigned r0 = *(const unsigned*)pp;
            unsigned r1 = *(const unsigned*)(pp + EE);
            float sc = ssl[c*2], sh = ssl[c*2+1];
            float e0 = fmaxf(b2f(r0 & 0xffff)*sc+sh, 0.f);
            float e1 = fmaxf(b2f(r0 >> 16)   *sc+sh, 0.f);
            float e2 = fmaxf(b2f(r1 & 0xffff)*sc+sh, 0.f);
            float e3 = fmaxf(b2f(r1 >> 16)   *sc+sh, 0.f);
            v = fmaxf(fmaxf(e0,e1), fmaxf(e2,e3));
        }
        sP[c*544 + ry*136 + rx] = (ushortt)bfbits(v);
    }
    // stage W: kw[o][k] -> sW[o][swizzled block (k>>3)^(o&7), elem k&7]
    for (int e = t; e < 1296; e += 256) {
        int o = e / 54, kk = e % 54;
        sW[o*64 + ((((kk >> 3) ^ (o & 7)) << 3) | (kk & 7))] = (ushortt)bfbits(kw[e]);
    }
    __syncthreads();
    // im2col: thread t -> px; 8 swizzled b128 writes
    {
        int r = t >> 7, xx = t & 127;
        unsigned u[32];
        #pragma unroll
        for (int p = 0; p < 27; ++p) {
            int k0 = 2*p, k1 = 2*p + 1;
            int c0 = k0/9, y0 = (k0%9)/3, x0 = k0%3;
            int c1i = k1/9, y1 = (k1%9)/3, x1 = k1%3;
            unsigned lo = sP[c0*544 + (r+y0)*136 + xx + x0];
            unsigned hi = sP[c1i*544 + (r+y1)*136 + xx + x1];
            u[p] = lo | (hi << 16);
        }
        #pragma unroll
        for (int p = 27; p < 32; ++p) u[p] = 0;
        #pragma unroll
        for (int e = 0; e < 8; ++e) {
            uint4 pk; pk.x = u[4*e]; pk.y = u[4*e+1]; pk.z = u[4*e+2]; pk.w = u[4*e+3];
            *(uint4*)&sA[t*64 + ((e ^ (t & 7)) << 3)] = pk;
        }
    }
    __syncthreads();
    b8v wv[2][2];
    #pragma unroll
    for (int nt = 0; nt < 2; ++nt) {
        int o = nt*16 + m;
        #pragma unroll
        for (int ks = 0; ks < 2; ++ks)
            wv[nt][ks] = *(const b8v*)&sW[o*64 + (((ks*4 + q4) ^ (o & 7)) << 3)];
    }
    f4v acc[4][2] = {};
    #pragma unroll
    for (int mt = 0; mt < 4; ++mt) {
        int px = wid*64 + mt*16 + m;
        b8v a0 = *(const b8v*)&sA[px*64 + (((q4)     ^ (px & 7)) << 3)];
        b8v a1 = *(const b8v*)&sA[px*64 + (((4 + q4) ^ (px & 7)) << 3)];
        #pragma unroll
        for (int nt = 0; nt < 2; ++nt) {
            acc[mt][nt] = __builtin_amdgcn_mfma_f32_16x16x32_bf16(a0, wv[nt][0], acc[mt][nt], 0, 0, 0);
            acc[mt][nt] = __builtin_amdgcn_mfma_f32_16x16x32_bf16(a1, wv[nt][1], acc[mt][nt], 0, 0, 0);
        }
    }
    // Epilogue: each lane holds 4 consecutive px for output channel o.
    float sAcc[2] = {0.f, 0.f}, qAcc[2] = {0.f, 0.f};
    #pragma unroll
    for (int nt = 0; nt < 2; ++nt) {
        int o = nt*16 + m;
        bool valid = (o < 24);
        float bo = valid ? bias[o] : 0.f;
        #pragma unroll
        for (int mt = 0; mt < 4; ++mt) {
            int pxb = wid*64 + mt*16 + q4*4;
            unsigned l0 = bfbits(acc[mt][nt][0] + bo);
            unsigned l1 = bfbits(acc[mt][nt][1] + bo);
            unsigned l2 = bfbits(acc[mt][nt][2] + bo);
            unsigned l3 = bfbits(acc[mt][nt][3] + bo);
            if (valid) {
                uint2 pk; pk.x = l0 | (l1 << 16); pk.y = l2 | (l3 << 16);
                int r = pxb >> 7, xx = pxb & 127;
                *(uint2*)(c2 + ((size_t)(b*24+o))*PL2 + (size_t)(h0 + r)*W2 + xx) = pk;
                float f0 = b2f(l0), f1 = b2f(l1), f2 = b2f(l2), f3 = b2f(l3);
                sAcc[nt] += f0+f1+f2+f3;
                qAcc[nt] += f0*f0+f1*f1+f2*f2+f3*f3;
            }
        }
    }
    #pragma unroll
    for (int nt = 0; nt < 2; ++nt) {
        int o = nt*16 + m;
        float s = sAcc[nt], q = qAcc[nt];
        s += __shfl_xor(s, 16); q += __shfl_xor(q, 16);
        s += __shfl_xor(s, 32); q += __shfl_xor(q, 32);
        if (q4 == 0 && o < 24) { atomicAdd(&redS[o], s); atomicAdd(&redQ[o], q); }
    }
    __syncthreads();
    if (t < 24) {
        atomicAdd(&mc2[((size_t)b*24 + t)*2],     redS[t]);
        atomicAdd(&mc2[((size_t)b*24 + t)*2 + 1], redQ[t]);
    }
}

// ---------------------------------------------------------------------------
// K8: tconv3 2x2 s2, 24->24 via MFMA, fused gn2+ReLU+pool+SiLU staging from c2.
// Stride-64 rows, 4 logical K-blocks swizzled (g^(px&3))+(px&4); row-per-thread
// A staging; direct-global lane-paired uint4 epilogue + register stats.
// 512 blocks.
__global__ __launch_bounds__(256) void k_tconv3(
    const bf* __restrict__ c2, const float* __restrict__ mc2,
    const float* __restrict__ g2, const float* __restrict__ be2,
    const float* __restrict__ k3, const float* __restrict__ b3,
    bf* __restrict__ u3, float* __restrict__ mu3)
{
    __shared__ ushortt sA[256*64];
    __shared__ ushortt sW[96*64];
    __shared__ float redS[24], redQ[24];
    __shared__ float ssl[48];
    int t = threadIdx.x;
    int b = blockIdx.x >> 3, pg = blockIdx.x & 7;
    int lane = t & 63, wid = t >> 6;
    int m = lane & 15, q4 = lane >> 4;
    if (t < 24) {
        redS[t] = 0.f; redQ[t] = 0.f;
        float s = mc2[((size_t)b*24 + t)*2], q = mc2[((size_t)b*24 + t)*2 + 1];
        float mean = s * (1.f/PL2);
        float var  = q * (1.f/PL2) - mean*mean;
        float rstd = rsqrtf(var + 1e-5f);
        float sc = g2[t]*rstd;
        ssl[t*2] = sc; ssl[t*2+1] = be2[t] - mean*sc;
    }
    // zero W pad block (logical g=3) per row; data goes to logical 0..2.
    if (t < 96) {
        uint4 z = {0,0,0,0};
        *(uint4*)&sW[t*64 + (((3 ^ (t & 3)) + (t & 4)) << 3)] = z;
    }
    // stage W: k3[c][n] -> sW[n][logical block c>>3 swizzled, elem c&7]
    #pragma unroll
    for (int j = 0; j < 9; ++j) {
        int e = j*256 + t;                  // 2304 exactly
        int c = e / 96, n = e % 96;
        sW[n*64 + (((((c >> 3) ^ (n & 3)) + (n & 4)) << 3) | (c & 7))] =
            (ushortt)bfbits(k3[e]);
    }
    // stage A: thread t = px; pooled+SiLU of its 24 channels, swizzled blocks.
    {
        int pix = pg*256 + t;
        int h4 = pix >> 6, w4 = pix & 63;
        const bf* base = c2 + (size_t)b*24*PL2 + (size_t)(2*h4)*W2 + 2*w4;
        #pragma unroll
        for (int g = 0; g < 3; ++g) {
            unsigned pr[4];
            #pragma unroll
            for (int hc = 0; hc < 4; ++hc) {
                unsigned two[2];
                #pragma unroll
                for (int cc = 0; cc < 2; ++cc) {
                    int c = g*8 + hc*2 + cc;
                    const bf* pp = base + (size_t)c*PL2;
                    unsigned r0 = *(const unsigned*)pp;
                    unsigned r1 = *(const unsigned*)(pp + W2);
                    float sc = ssl[c*2], sh = ssl[c*2+1];
                    float e0 = fmaxf(b2f(r0 & 0xffff)*sc+sh, 0.f);
                    float e1 = fmaxf(b2f(r0 >> 16)   *sc+sh, 0.f);
                    float e2 = fmaxf(b2f(r1 & 0xffff)*sc+sh, 0.f);
                    float e3 = fmaxf(b2f(r1 >> 16)   *sc+sh, 0.f);
                    float mm = fmaxf(fmaxf(e0,e1), fmaxf(e2,e3));
                    mm = mm / (1.f + expf(-mm));
                    two[cc] = bfbits(mm);
                }
                pr[hc] = two[0] | (two[1] << 16);
            }
            uint4 pk; pk.x = pr[0]; pk.y = pr[1]; pk.z = pr[2]; pk.w = pr[3];
            *(uint4*)&sA[t*64 + (((g ^ (t & 3)) + (t & 4)) << 3)] = pk;
        }
        uint4 z = {0,0,0,0};
        *(uint4*)&sA[t*64 + (((3 ^ (t & 3)) + (t & 4)) << 3)] = z;
    }
    __syncthreads();
    // MFMA: wave = 64 px x 96 n, single K=32 step.
    b8v wv[6];
    #pragma unroll
    for (int nt = 0; nt < 6; ++nt) {
        int n = nt*16 + m;
        wv[nt] = *(const b8v*)&sW[n*64 + (((q4 ^ (n & 3)) + (n & 4)) << 3)];
    }
    f4v acc[4][6] = {};
    #pragma unroll
    for (int mt = 0; mt < 4; ++mt) {
        int px = wid*64 + mt*16 + m;
        b8v av = *(const b8v*)&sA[px*64 + (((q4 ^ (px & 3)) + (px & 4)) << 3)];
        #pragma unroll
        for (int nt = 0; nt < 6; ++nt)
            acc[mt][nt] = __builtin_amdgcn_mfma_f32_16x16x32_bf16(av, wv[nt], acc[mt][nt], 0, 0, 0);
    }
    // Epilogue: lane-paired direct global uint4 stores + register stats.
    float sAcc[6] = {}, qAcc[6] = {};
    int qq = m & 1;
    #pragma unroll
    for (int nt = 0; nt < 6; ++nt) {
        int n = nt*16 + m;
        int o = n >> 2, d = (n >> 1) & 1;
        float bo = b3[o];
        #pragma unroll
        for (int mt = 0; mt < 4; ++mt) {
            int pxb = wid*64 + mt*16 + q4*4;
            unsigned wds[4];
            float s = 0.f, q = 0.f;
            #pragma unroll
            for (int r = 0; r < 4; ++r) {
                float v = acc[mt][nt][r] + bo;
                float vp = __shfl_xor(v, 1);
                unsigned lo = bfbits(v), hi = bfbits(vp);
                wds[r] = lo | (hi << 16);
                float f0 = b2f(lo), f1 = b2f(hi);
                s += f0 + f1;
                q += f0*f0 + f1*f1;
            }
            if (qq == 0) {
                int h4 = (pg*256 + pxb) >> 6;
                int w4 = pxb & 63;
                uint4 pk; pk.x = wds[0]; pk.y = wds[1]; pk.z = wds[2]; pk.w = wds[3];
                *(uint4*)(u3 + ((size_t)(b*24 + o))*PL2 + (size_t)(2*h4 + d)*W2 + 2*w4) = pk;
                sAcc[nt] += s; qAcc[nt] += q;
            }
        }
    }
    #pragma unroll
    for (int nt = 0; nt < 6; ++nt) {
        float s = sAcc[nt], q = qAcc[nt];
        s += __shfl_xor(s, 2);  q += __shfl_xor(q, 2);
        s += __shfl_xor(s, 16); q += __shfl_xor(q, 16);
        s += __shfl_xor(s, 32); q += __shfl_xor(q, 32);
        if ((lane & 51) == 0) {            // m&3==0 && q4==0
            int o = nt*4 + (m >> 2);
            atomicAdd(&redS[o], s);
            atomicAdd(&redQ[o], q);
        }
    }
    __syncthreads();
    if (t < 24) {
        atomicAdd(&mu3[((size_t)b*24 + t)*2],     redS[t]);
        atomicAdd(&mu3[((size_t)b*24 + t)*2 + 1], redQ[t]);
    }
}

// ---------------------------------------------------------------------------
// K10: gn3-fused tconv4 2x2 s2, 48->12 via MFMA. gn3 prologue from mc2+mu3.
// XOR-swizzled A/W staging; direct-global lane-paired epilogue. 2048 blocks.
__global__ __launch_bounds__(256) void k_tconv4(
    const bf* __restrict__ c2, const bf* __restrict__ u3,
    const float* __restrict__ mc2, const float* __restrict__ mu3,
    const float* __restrict__ g3, const float* __restrict__ be3,
    const float* __restrict__ k4, const float* __restrict__ bias4,
    bf* __restrict__ u4, float* __restrict__ mu4)
{
    __shared__ ushortt sA[256*64];   // [px][kb^(px&7) blocks of 8]
    __shared__ ushortt sW[48*64];    // [n][kb^(n&7) blocks of 8]
    __shared__ float redS[12], redQ[12];
    __shared__ float ssl[96];
    int t = threadIdx.x;
    int b = blockIdx.x >> 5, pg = blockIdx.x & 31;
    int lane = t & 63, wid = t >> 6;
    int m = lane & 15, q4 = lane >> 4;
    if (t < 12) { redS[t] = 0.f; redQ[t] = 0.f; }
    if (t < 6) {
        float s = 0.f, q = 0.f;
        #pragma unroll
        for (int cl = 0; cl < 8; ++cl) {
            int gc = t*8 + cl;
            const float* p = (gc < 24) ? mc2 + ((size_t)b*24 + gc)*2
                                       : mu3 + ((size_t)b*24 + gc - 24)*2;
            s += p[0]; q += p[1];
        }
        float inv_n = 1.f/((float)PL2*8.f);
        float mean = s*inv_n;
        float var  = q*inv_n - mean*mean;
        float rstd = rsqrtf(var + 1e-5f);
        #pragma unroll
        for (int cl = 0; cl < 8; ++cl) {
            int gc = t*8 + cl;
            float sc = g3[gc]*rstd;
            ssl[gc*2] = sc; ssl[gc*2+1] = be3[gc] - mean*sc;
        }
    }
    // stage W: k4[c][n] -> sW[n][swizzled block (c>>3)^(n&7), elem c&7]
    #pragma unroll
    for (int j = 0; j < 9; ++j) {
        int e = j*256 + t;                 // 2304 exactly
        int c = e / 48, n = e % 48;
        sW[n*64 + ((((c >> 3) ^ (n & 7)) << 3) | (c & 7))] = (ushortt)bfbits(k4[e]);
    }
    if (t < 96) {                          // zero pad blocks kb=6,7
        uint4 z = {0,0,0,0};
        int n = t >> 1, kb = 6 + (t & 1);
        *(uint4*)&sW[n*64 + ((kb ^ (n & 7)) << 3)] = z;
    }
    // stage A: gn3-affine of concat(c2,u3), swizzled blocks
    {
        int px = t;
        int pix = pg*256 + px;
        const bf* c2p = c2 + (size_t)b*24*PL2 + pix;
        const bf* u3p = u3 + (size_t)b*24*PL2 + pix;
        #pragma unroll
        for (int g = 0; g < 6; ++g) {
            unsigned pr[4];
            #pragma unroll
            for (int hc = 0; hc < 4; ++hc) {
                int c0 = g*8 + hc*2;
                float r0 = (c0 < 24) ? tof(c2p[(size_t)c0*PL2]) : tof(u3p[(size_t)(c0-24)*PL2]);
                float r1 = (c0+1 < 24) ? tof(c2p[(size_t)(c0+1)*PL2]) : tof(u3p[(size_t)(c0+1-24)*PL2]);
                float v0 = r0 * ssl[2*c0]   + ssl[2*c0+1];
                float v1 = r1 * ssl[2*c0+2] + ssl[2*c0+3];
                pr[hc] = bfbits(v0) | (bfbits(v1) << 16);
            }
            uint4 pk; pk.x = pr[0]; pk.y = pr[1]; pk.z = pr[2]; pk.w = pr[3];
            *(uint4*)&sA[px*64 + ((g ^ (px & 7)) << 3)] = pk;
        }
        uint4 z = {0,0,0,0};
        *(uint4*)&sA[px*64 + ((6 ^ (px & 7)) << 3)] = z;
        *(uint4*)&sA[px*64 + ((7 ^ (px & 7)) << 3)] = z;
    }
    __syncthreads();
    // MFMA: wave = 64 px x 48 n, K=64 (2 swizzled reads)
    b8v bfr[3][2];
    #pragma unroll
    for (int nt = 0; nt < 3; ++nt) {
        int n = nt*16 + m;
        #pragma unroll
        for (int ks = 0; ks < 2; ++ks)
            bfr[nt][ks] = *(const b8v*)&sW[n*64 + (((ks*4 + q4) ^ (n & 7)) << 3)];
    }
    f4v acc[4][3] = {};
    #pragma unroll
    for (int mt = 0; mt < 4; ++mt) {
        int px = wid*64 + mt*16 + m;
        b8v a0 = *(const b8v*)&sA[px*64 + (((q4)     ^ (px & 7)) << 3)];
        b8v a1 = *(const b8v*)&sA[px*64 + (((4 + q4) ^ (px & 7)) << 3)];
        #pragma unroll
        for (int nt = 0; nt < 3; ++nt) {
            acc[mt][nt] = __builtin_amdgcn_mfma_f32_16x16x32_bf16(a0, bfr[nt][0], acc[mt][nt], 0, 0, 0);
            acc[mt][nt] = __builtin_amdgcn_mfma_f32_16x16x32_bf16(a1, bfr[nt][1], acc[mt][nt], 0, 0, 0);
        }
    }
    // Epilogue: lane-paired direct global uint4 stores + register stats.
    float sAcc[3] = {0.f, 0.f, 0.f}, qAcc[3] = {0.f, 0.f, 0.f};
    int qq = m & 1;
    #pragma unroll
    for (int nt = 0; nt < 3; ++nt) {
        int n = nt*16 + m;
        int o = n >> 2, d = (n >> 1) & 1;
        float bo = bias4[o];
        #pragma unroll
        for (int mt = 0; mt < 4; ++mt) {
            int pxb = wid*64 + mt*16 + q4*4;
            unsigned wds[4];
            float s = 0.f, q = 0.f;
            #pragma unroll
            for (int r = 0; r < 4; ++r) {
                float v = acc[mt][nt][r] + bo;
                float vp = __shfl_xor(v, 1);
                unsigned lo = bfbits(v), hi = bfbits(vp);
                wds[r] = lo | (hi << 16);
                float f0 = b2f(lo), f1 = b2f(hi);
                s += f0 + f1;
                q += f0*f0 + f1*f1;
            }
            if (qq == 0) {
                int h2 = (pg*256 + pxb) >> 7;
                int w0 = pxb & 127;
                uint4 pk; pk.x = wds[0]; pk.y = wds[1]; pk.z = wds[2]; pk.w = wds[3];
                *(uint4*)(u4 + (((size_t)(b*12 + o))*HH + 2*h2 + d)*EE + 2*w0) = pk;
                sAcc[nt] += s; qAcc[nt] += q;
            }
        }
    }
    #pragma unroll
    for (int nt = 0; nt < 3; ++nt) {
        float s = sAcc[nt], q = qAcc[nt];
        s += __shfl_xor(s, 2);  q += __shfl_xor(q, 2);
        s += __shfl_xor(s, 16); q += __shfl_xor(q, 16);
        s += __shfl_xor(s, 32); q += __shfl_xor(q, 32);
        if ((lane & 51) == 0) {
            int o = nt*4 + (m >> 2);
            atomicAdd(&redS[o], s);
            atomicAdd(&redQ[o], q);
        }
    }
    __syncthreads();
    if (t < 12) {
        atomicAdd(&mu4[((size_t)b*12 + t)*2],     redS[t]);
        atomicAdd(&mu4[((size_t)b*12 + t)*2 + 1], redQ[t]);
    }
}

// ---------------------------------------------------------------------------
// K12: gn4-fused 1x1 conv 18->6. gn4 prologue from mc1+mu4. 8 px/thread,
// uint4 loads/stores. Fused u5 stats. 1024 blocks.
__global__ __launch_bounds__(256) void k_conv1x1_u5(
    const bf* __restrict__ c1, const bf* __restrict__ u4,
    const float* __restrict__ mc1, const float* __restrict__ mu4,
    const float* __restrict__ g4, const float* __restrict__ be4,
    const float* __restrict__ k, const float* __restrict__ bias,
    bf* __restrict__ u5, float* __restrict__ mu5)
{
    __shared__ float red[4][6][2];
    __shared__ float ssl[36];
    int t = threadIdx.x;
    int b  = blockIdx.x >> 4;
    int pg = blockIdx.x & 15;
    int pix = pg*2048 + t*8;
    int lane = t & 63, wid = t >> 6;
    if (t < 6) {
        float s = 0.f, q = 0.f;
        #pragma unroll
        for (int cl = 0; cl < 3; ++cl) {
            int gc = t*3 + cl;
            const float* p = (gc < 6) ? mc1 + ((size_t)b*6 + gc)*2
                                      : mu4 + ((size_t)b*12 + gc - 6)*2;
            s += p[0]; q += p[1];
        }
        float inv_n = 1.f/((float)HP*3.f);
        float mean = s*inv_n;
        float var  = q*inv_n - mean*mean;
        float rstd = rsqrtf(var + 1e-5f);
        #pragma unroll
        for (int cl = 0; cl < 3; ++cl) {
            int gc = t*3 + cl;
            float sc = g4[gc]*rstd;
            ssl[gc*2] = sc; ssl[gc*2+1] = be4[gc] - mean*sc;
        }
    }
    __syncthreads();
    const bf* c1p = c1 + ((size_t)b*6)*HP + pix;
    const bf* u4p = u4 + ((size_t)b*12)*HP + pix;
    float acc[6][8];
    #pragma unroll
    for (int o = 0; o < 6; ++o) {
        float bv = bias[o];
        #pragma unroll
        for (int j = 0; j < 8; ++j) acc[o][j] = bv;
    }
    #pragma unroll
    for (int c = 0; c < 18; ++c) {
        uint4 r = (c < 6) ? *(const uint4*)(c1p + (size_t)c*HP)
                          : *(const uint4*)(u4p + (size_t)(c-6)*HP);
        float sc = ssl[2*c], sh = ssl[2*c+1];
        float v[8];
        v[0] = b2f(r.x & 0xffff)*sc + sh;  v[1] = b2f(r.x >> 16)*sc + sh;
        v[2] = b2f(r.y & 0xffff)*sc + sh;  v[3] = b2f(r.y >> 16)*sc + sh;
        v[4] = b2f(r.z & 0xffff)*sc + sh;  v[5] = b2f(r.z >> 16)*sc + sh;
        v[6] = b2f(r.w & 0xffff)*sc + sh;  v[7] = b2f(r.w >> 16)*sc + sh;
        #pragma unroll
        for (int o = 0; o < 6; ++o) {
            float wv = k[o*18 + c];
            #pragma unroll
            for (int j = 0; j < 8; ++j) acc[o][j] += v[j]*wv;
        }
    }
    #pragma unroll
    for (int o = 0; o < 6; ++o) {
        uint4 pk;
        pk.x = bfbits(acc[o][0]) | (bfbits(acc[o][1]) << 16);
        pk.y = bfbits(acc[o][2]) | (bfbits(acc[o][3]) << 16);
        pk.z = bfbits(acc[o][4]) | (bfbits(acc[o][5]) << 16);
        pk.w = bfbits(acc[o][6]) | (bfbits(acc[o][7]) << 16);
        *(uint4*)(u5 + ((size_t)(b*6+o))*HP + pix) = pk;
        float s = 0.f, q = 0.f;
        #pragma unroll
        for (int j = 0; j < 8; ++j) { s += acc[o][j]; q += acc[o][j]*acc[o][j]; }
        wred2(s, q);
        if (lane == 0) { red[wid][o][0] = s; red[wid][o][1] = q; }
    }
    __syncthreads();
    if (t < 6) {
        float S = 0.f, Q = 0.f;
        #pragma unroll
        for (int wv = 0; wv < 4; ++wv) { S += red[wv][t][0]; Q += red[wv][t][1]; }
        atomicAdd(&mu5[((size_t)b*6 + t)*2],     S);
        atomicAdd(&mu5[((size_t)b*6 + t)*2 + 1], Q);
    }
}

// ---------------------------------------------------------------------------
// K14: gn5-fused final 1x1 conv (6->1) + divide by std(t). gn5 in prologue.
// 8 px/thread, uint4 loads, 2x float4 stores. 1024 blocks.
__global__ __launch_bounds__(256) void k_final(
    const bf* __restrict__ u5, const float* __restrict__ mu5,
    const float* __restrict__ g5, const float* __restrict__ be5,
    const float* __restrict__ k, const float* __restrict__ bias,
    const float* __restrict__ t, float* __restrict__ out)
{
    __shared__ float ssl[12];
    int tt = threadIdx.x;
    int b = blockIdx.x >> 4;
    int pix = ((blockIdx.x & 15)*256 + tt)*8;
    if (tt < 6) {
        float s = mu5[((size_t)b*6 + tt)*2], q = mu5[((size_t)b*6 + tt)*2 + 1];
        float mean = s * (1.f/HP);
        float var  = q * (1.f/HP) - mean*mean;
        float rstd = rsqrtf(var + 1e-5f);
        float sc = g5[tt]*rstd;
        ssl[tt*2] = sc; ssl[tt*2+1] = be5[tt] - mean*sc;
    }
    __syncthreads();
    const bf* up = u5 + (size_t)b*6*HP + pix;
    float bv = bias[0];
    float a[8];
    #pragma unroll
    for (int j = 0; j < 8; ++j) a[j] = bv;
    #pragma unroll
    for (int c = 0; c < 6; ++c) {
        uint4 r = *(const uint4*)(up + (size_t)c*HP);
        float sc = ssl[2*c], sh = ssl[2*c+1];
        float wv = k[c];
        a[0] += (b2f(r.x & 0xffff)*sc + sh) * wv;
        a[1] += (b2f(r.x >> 16)   *sc + sh) * wv;
        a[2] += (b2f(r.y & 0xffff)*sc + sh) * wv;
        a[3] += (b2f(r.y >> 16)   *sc + sh) * wv;
        a[4] += (b2f(r.z & 0xffff)*sc + sh) * wv;
        a[5] += (b2f(r.z >> 16)   *sc + sh) * wv;
        a[6] += (b2f(r.w & 0xffff)*sc + sh) * wv;
        a[7] += (b2f(r.w >> 16)   *sc + sh) * wv;
    }
    float tb = t[b];
    const float lns = 3.2188758248682007492f;
    float var = (expf(2.f*tb*lns) - 1.f) / (2.f*lns);
    float rs = rsqrtf(var);
    float4 o0; o0.x = a[0]*rs; o0.y = a[1]*rs; o0.z = a[2]*rs; o0.w = a[3]*rs;
    float4 o1; o1.x = a[4]*rs; o1.y = a[5]*rs; o1.z = a[6]*rs; o1.w = a[7]*rs;
    float* op = out + (size_t)b*HP + pix;
    *(float4*)op       = o0;
    *(float4*)(op + 4) = o1;
}

// ---------------------------------------------------------------------------
extern "C" void kernel_launch(void* const* d_in, const int* in_sizes, int n_in,
                              void* d_out, int out_size, void* d_ws, size_t ws_size,
                              hipStream_t stream)
{
    const float* x       = (const float*)d_in[0];
    const float* t       = (const float*)d_in[1];
    const float* Wf      = (const float*)d_in[2];
    const float* fc1_w   = (const float*)d_in[3];
    const float* fc1_b   = (const float*)d_in[4];
    const float* conv1_k = (const float*)d_in[5];
    const float* conv1_b = (const float*)d_in[6];
    const float* gn1_g   = (const float*)d_in[7];
    const float* gn1_b   = (const float*)d_in[8];
    const float* conv2_k = (const float*)d_in[9];
    const float* conv2_b = (const float*)d_in[10];
    const float* gn2_g   = (const float*)d_in[11];
    const float* gn2_b   = (const float*)d_in[12];
    const float* t3_k    = (const float*)d_in[13];
    const float* t3_b    = (const float*)d_in[14];
    const float* gn3_g   = (const float*)d_in[15];
    const float* gn3_b   = (const float*)d_in[16];
    const float* t4_k    = (const float*)d_in[17];
    const float* t4_b    = (const float*)d_in[18];
    const float* gn4_g   = (const float*)d_in[19];
    const float* gn4_b   = (const float*)d_in[20];
    const float* t5_k    = (const float*)d_in[21];
    const float* t5_b    = (const float*)d_in[22];
    const float* gn5_g   = (const float*)d_in[23];
    const float* gn5_b   = (const float*)d_in[24];
    const float* fin_k   = (const float*)d_in[25];
    const float* fin_b   = (const float*)d_in[26];

    bf* wsb = (bf*)d_ws;
    bf* c1 = wsb;                          // conv1..conv1x1
    bf* c2 = wsb + 12582912;               // conv2..tconv4
    bf* u3 = wsb + 25165824;               // tconv3..tconv4
    bf* u4 = wsb + 37748736;               // tconv4..conv1x1
    bf* xf = wsb + 39845888;               // fc1..conv1 (in u4 region)
    bf* u5 = wsb + 12582912;               // reuses c2, conv1x1..final
    float* mb = (float*)(wsb + 62914560);  // raw channel sums
    float* mc1 = mb;            // 768
    float* mc2 = mb + 768;      // 3072
    float* mu3 = mb + 3840;     // 3072
    float* mu4 = mb + 6912;     // 1536
    float* mu5 = mb + 8448;     // 768

    k_fourier_fc1<<<512, 256, 0, stream>>>(x, Wf, fc1_w, fc1_b, xf, mb);
    k_conv1<<<2048, 256, 0, stream>>>(xf, conv1_k, conv1_b, c1, mc1);
    k_conv2<<<2048, 256, 0, stream>>>(c1, mc1, gn1_g, gn1_b,
                                      conv2_k, conv2_b, c2, mc2);
    k_tconv3<<<512, 256, 0, stream>>>(c2, mc2, gn2_g, gn2_b,
                                      t3_k, t3_b, u3, mu3);
    k_tconv4<<<2048, 256, 0, stream>>>(c2, u3, mc2, mu3, gn3_g, gn3_b,
                                       t4_k, t4_b, u4, mu4);
    k_conv1x1_u5<<<1024, 256, 0, stream>>>(c1, u4, mc1, mu4, gn4_g, gn4_b,
                                           t5_k, t5_b, u5, mu5);
    k_final<<<1024, 256, 0, stream>>>(u5, mu5, gn5_g, gn5_b,
                                      fin_k, fin_b, t, (float*)d_out);
}